// Round 9
// baseline (424.456 us; speedup 1.0000x reference)
//
#include <hip/hip_runtime.h>
#include <hip/hip_bf16.h>
#include <math.h>

typedef __hip_bfloat16 bf16;
typedef __attribute__((ext_vector_type(8))) short short8;
typedef __attribute__((ext_vector_type(4))) short short4v;
typedef __attribute__((ext_vector_type(4))) float f32x4;

#define SEQ 3072
#define HID 1152
#define NHEAD 16
#define HD 72
#define HDP 96
#define MLPD 4304
#define MLPP 4352

__device__ __forceinline__ void async_lds16(void* lds, const void* g) {
  __builtin_amdgcn_global_load_lds((const __attribute__((address_space(1))) void*)g,
                                   (__attribute__((address_space(3))) void*)lds,
                                   16, 0, 0);
}

// one v_cvt_pk_bf16_f32: a -> low16, b -> high16 (RNE)
__device__ __forceinline__ unsigned cvt_pk2(float a, float b) {
  unsigned r;
  asm("v_cvt_pk_bf16_f32 %0, %1, %2" : "=v"(r) : "v"(a), "v"(b));
  return r;
}

// raw v_exp_f32: 2^x
__device__ __forceinline__ float exp2a(float x) {
  float r;
  asm("v_exp_f32 %0, %1" : "=v"(r) : "v"(x));
  return r;
}

// ---------------- weight cast kernels ----------------
__global__ __launch_bounds__(256) void cast_bf16_k(const float* __restrict__ in,
                                                   unsigned* __restrict__ out2, int n4) {
  int stride = gridDim.x * blockDim.x;
  for (int i = blockIdx.x * blockDim.x + threadIdx.x; i < n4; i += stride) {
    float4 u = ((const float4*)in)[i];
    uint2 w = make_uint2(cvt_pk2(u.x, u.y), cvt_pk2(u.z, u.w));
    ((uint2*)out2)[i] = w;
  }
}

__global__ __launch_bounds__(256) void cast_pad_rows_k(const float* __restrict__ in,
                                                       unsigned* __restrict__ out2,
                                                       int R, int C4, int n4) {
  int stride = gridDim.x * blockDim.x;
  for (int i = blockIdx.x * blockDim.x + threadIdx.x; i < n4; i += stride) {
    int r = i / C4;
    uint2 w = make_uint2(0u, 0u);
    if (r < R) {
      float4 u = ((const float4*)in)[i];
      w = make_uint2(cvt_pk2(u.x, u.y), cvt_pk2(u.z, u.w));
    }
    ((uint2*)out2)[i] = w;
  }
}

__global__ __launch_bounds__(256) void cast_pad_cols_k(const float* __restrict__ in,
                                                       unsigned* __restrict__ out2,
                                                       int C4, int Cp4, int n4) {
  int stride = gridDim.x * blockDim.x;
  for (int i = blockIdx.x * blockDim.x + threadIdx.x; i < n4; i += stride) {
    int r = i / Cp4, c4 = i - r * Cp4;
    uint2 w = make_uint2(0u, 0u);
    if (c4 < C4) {
      float4 u = ((const float4*)in)[r * C4 + c4];
      w = make_uint2(cvt_pk2(u.x, u.y), cvt_pk2(u.z, u.w));
    }
    ((uint2*)out2)[i] = w;
  }
}

// ---------------- layernorm (fp32 in -> bf16 out) ----------------
__global__ __launch_bounds__(256) void ln_k(const float* __restrict__ x,
                                            const float* __restrict__ g,
                                            const float* __restrict__ b,
                                            bf16* __restrict__ o) {
  int row = blockIdx.x;
  const float4* xr = (const float4*)(x + (size_t)row * HID);
  float sum = 0.f, sq = 0.f;
  for (int c = threadIdx.x; c < HID / 4; c += 256) {
    float4 u = xr[c];
    sum += u.x + u.y + u.z + u.w;
    sq += u.x * u.x + u.y * u.y + u.z * u.z + u.w * u.w;
  }
#pragma unroll
  for (int off = 32; off > 0; off >>= 1) {
    sum += __shfl_down(sum, off, 64);
    sq += __shfl_down(sq, off, 64);
  }
  __shared__ float red[8];
  int wv = threadIdx.x >> 6;
  if ((threadIdx.x & 63) == 0) { red[wv] = sum; red[4 + wv] = sq; }
  __syncthreads();
  if (threadIdx.x == 0) {
    red[0] = red[0] + red[1] + red[2] + red[3];
    red[4] = red[4] + red[5] + red[6] + red[7];
  }
  __syncthreads();
  float mu = red[0] * (1.f / HID);
  float var = red[4] * (1.f / HID) - mu * mu;
  float inv = rsqrtf(var + 1e-5f);
  uint2* o4 = (uint2*)(o + (size_t)row * HID);
  const float4* g4 = (const float4*)g;
  const float4* b4 = (const float4*)b;
  for (int c = threadIdx.x; c < HID / 4; c += 256) {
    float4 u = xr[c], gg = g4[c], bb = b4[c];
    uint2 w = make_uint2(cvt_pk2((u.x - mu) * inv * gg.x + bb.x, (u.y - mu) * inv * gg.y + bb.y),
                         cvt_pk2((u.z - mu) * inv * gg.z + bb.z, (u.w - mu) * inv * gg.w + bb.w));
    o4[c] = w;
  }
}

// ---------------- GEMM: C[M][N] = A[M][K] @ Bt[N][K]^T  (+ epilogue) ----------------
// 3 LDS buffers (48KB -> 3 blocks/CU), depth-2 prefetch, counted vmcnt,
// bijective XCD swizzle (x-major per XCD -> B-panel L2-resident).
// EPI 0: +bias -> fp32   1: +bias+res -> fp32   2: +bias, gelu -> bf16
template <int EPI>
__global__ __launch_bounds__(256) void gemm_bf16(const bf16* __restrict__ A,
                                                 const bf16* __restrict__ Bt,
                                                 const float* __restrict__ bias, int nbias,
                                                 const float* __restrict__ res,
                                                 float* __restrict__ outf,
                                                 bf16* __restrict__ outb,
                                                 int M, int N, int K) {
  __shared__ bf16 As[3][128 * 32];
  __shared__ bf16 Bs[3][128 * 32];
  const int t = threadIdx.x;
  const int l = t & 63;
  const int w = t >> 6;
  const int wr = w >> 1, wc = w & 1;
  const int lrow = l & 15;
  const int lk = (l >> 4) * 8;
  const int wg = (blockIdx.x & 7) * (gridDim.x >> 3) + (blockIdx.x >> 3);
  const int gyt = M >> 7;
  const int xt = wg / gyt;
  const int yt = wg - xt * gyt;
  const int m0 = yt * 128;
  const int n0 = xt * 128;
  const int arow = t >> 2;
  const int ach = (t & 3) * 8;

  const bf16* pa0 = &A[(size_t)(m0 + arow) * K + ach];
  const bf16* pa1 = &A[(size_t)(m0 + arow + 64) * K + ach];
  const bf16* pb0 = &Bt[(size_t)(n0 + arow) * K + ach];
  const bf16* pb1 = &Bt[(size_t)(n0 + arow + 64) * K + ach];
  auto STAGE = [&](int buf, int kt) {
    size_t off = (size_t)kt * 32;
    async_lds16(&As[buf][t * 8], pa0 + off);
    async_lds16(&As[buf][(256 + t) * 8], pa1 + off);
    async_lds16(&Bs[buf][t * 8], pb0 + off);
    async_lds16(&Bs[buf][(256 + t) * 8], pb1 + off);
  };

  f32x4 acc[4][4] = {};
  const int nkt = K >> 5;
  STAGE(0, 0);
  STAGE(1, 1);
  int bcur = 0;
  for (int kt = 0; kt < nkt; ++kt) {
    if (kt + 1 < nkt) {
      asm volatile("s_waitcnt vmcnt(4)" ::: "memory");  // stage kt landed; kt+1 in flight
    } else {
      asm volatile("s_waitcnt vmcnt(0)" ::: "memory");
    }
    __builtin_amdgcn_s_barrier();
    int bn2 = bcur + 2;
    if (bn2 >= 3) bn2 -= 3;
    if (kt + 2 < nkt) STAGE(bn2, kt + 2);

    short8 af[4], bfr[4];
#pragma unroll
    for (int i = 0; i < 4; ++i)
      af[i] = *(const short8*)&As[bcur][(wr * 64 + i * 16 + lrow) * 32 + lk];
#pragma unroll
    for (int i = 0; i < 4; ++i)
      bfr[i] = *(const short8*)&Bs[bcur][(wc * 64 + i * 16 + lrow) * 32 + lk];
    __builtin_amdgcn_s_setprio(1);
#pragma unroll
    for (int i = 0; i < 4; ++i)
#pragma unroll
      for (int j = 0; j < 4; ++j)
        acc[i][j] = __builtin_amdgcn_mfma_f32_16x16x32_bf16(af[i], bfr[j], acc[i][j], 0, 0, 0);
    __builtin_amdgcn_s_setprio(0);
    ++bcur;
    if (bcur == 3) bcur = 0;
  }

#pragma unroll
  for (int i = 0; i < 4; ++i) {
    int rowb = m0 + wr * 64 + i * 16 + (l >> 4) * 4;
#pragma unroll
    for (int j = 0; j < 4; ++j) {
      int col = n0 + wc * 64 + j * 16 + lrow;
      float bv = (col < nbias) ? bias[col] : 0.f;
#pragma unroll
      for (int r2 = 0; r2 < 4; ++r2) {
        size_t idx = (size_t)(rowb + r2) * N + col;
        float v = acc[i][j][r2] + bv;
        if (EPI == 0) {
          outf[idx] = v;
        } else if (EPI == 1) {
          outf[idx] = v + res[idx];
        } else {
          float u = 0.7978845608028654f * (v + 0.044715f * v * v * v);
          u = fminf(fmaxf(u, -15.f), 15.f);
          float tt = __expf(2.f * u);
          outb[idx] = __float2bfloat16(v * tt / (tt + 1.f));
        }
      }
    }
  }
}

// ---------------- rope + qkv split ----------------
// q scale folds log2(e) so flash softmax runs in exp2 domain.
__global__ __launch_bounds__(256) void rope_split(const float* __restrict__ xqkv,
                                                  const float* __restrict__ cosb,
                                                  const float* __restrict__ sinb,
                                                  bf16* __restrict__ qp,
                                                  bf16* __restrict__ kp,
                                                  bf16* __restrict__ vt) {
  __shared__ bf16 vl[64][72];
  const int t = threadIdx.x;
  const int h = blockIdx.y;
  const int s0 = blockIdx.x * 64;
  const float scale = 0.17002445f;  // (1/sqrt(72)) * log2(e)
  for (int idx = t; idx < 64 * 48; idx += 256) {
    int sl = idx / 48, pi = idx - sl * 48;
    int srow = s0 + sl;
    size_t obase = ((size_t)h * SEQ + srow) * HDP + 2 * pi;
    if (pi < 36) {
      const float* xr = xqkv + (size_t)srow * (3 * HID) + h * HD + 2 * pi;
      float qr = xr[0], qi = xr[1];
      float kr = xr[HID], ki = xr[HID + 1];
      float c = cosb[srow * 36 + pi], sn = sinb[srow * 36 + pi];
      *(unsigned*)&qp[obase] = cvt_pk2((qr * c - qi * sn) * scale, (qr * sn + qi * c) * scale);
      *(unsigned*)&kp[obase] = cvt_pk2(kr * c - ki * sn, kr * sn + ki * c);
    } else {
      *(unsigned*)&qp[obase] = 0u;
      *(unsigned*)&kp[obase] = 0u;
    }
  }
  for (int idx = t; idx < 64 * 72; idx += 256) {
    int sl = idx / 72, d = idx - sl * 72;
    vl[sl][d] = __float2bfloat16(xqkv[(size_t)(s0 + sl) * (3 * HID) + 2 * HID + h * HD + d]);
  }
  __syncthreads();
  bf16 z = __float2bfloat16(0.f);
  for (int idx = t; idx < HDP * 64; idx += 256) {
    int d = idx / 64, sl = idx - d * 64;
    vt[((size_t)h * HDP + d) * SEQ + s0 + sl] = (d < 72) ? vl[sl][d] : z;
  }
}

// ---------------- flash attention ----------------
// KVBLK=64, NT=48. 6 waves x 16 q-rows (QBLK=96), grid 512 = exactly 2 blocks/CU.
// K triple-buffered, V double-buffered; K staged before V so vmcnt(2) at loop
// top completes K(t+1)+V(t) and leaves V(t+1) in flight. QK(t+1)-ahead pipeline,
// swapped operands (lane-local softmax), exp2-domain, defer-max THR=11.54.
// LDS: Ks 3x12KB + Vs 2x12KB + Pl 12KB = 72KB -> 2 blocks/CU.
// K buf [64 kv][96 d] chunk-major: elem = cb*512 + kv*8 + e (cb = d/8, 0..11)
// V buf [96 d][64 kv] chunk-major: elem = cb*768 + d*8 + e  (cb = kv/8, 0..7)
// P per wave [16 q][64 kv] chunk-major: elem = cb*128 + q*8 + e (cb = kv/8)
__global__ __launch_bounds__(384) void flash_attn(const bf16* __restrict__ q,
                                                  const bf16* __restrict__ kk,
                                                  const bf16* __restrict__ vT,
                                                  bf16* __restrict__ o) {
  __shared__ alignas(16) bf16 Ks[3][6144];
  __shared__ alignas(16) bf16 Vs[2][6144];
  __shared__ alignas(16) bf16 Pl[6][1024];
  const int t = threadIdx.x;
  const int l = t & 63;
  const int w = t >> 6;  // 0..5
  const int g = l >> 4;
  const int lrow = l & 15;
  const int bid = blockIdx.x;
  const int kq = bid >> 3;
  const int h = (bid & 7) * 2 + (kq & 1);
  const int q0 = (kq >> 1) * 96 + w * 16;
  const int NT = SEQ / 64;  // 48

  // staging: K slots s = t, t+384 (0..767); V slots vs = t, t+384 (0..767)
  const bf16* kbase[2];
  const bf16* vbase[2];
#pragma unroll
  for (int i = 0; i < 2; ++i) {
    int s = t + i * 384;
    int cb = s >> 6, kv = s & 63;
    kbase[i] = kk + ((size_t)h * SEQ + kv) * HDP + cb * 8;
    int vs = t + i * 384;
    int vcb = vs / 96, d = vs - vcb * 96;
    vbase[i] = vT + ((size_t)h * HDP + d) * SEQ + vcb * 8;
  }
  auto STAGE_K = [&](int tile, int kb) {
    size_t off = (size_t)tile * 64 * HDP;
    async_lds16(&Ks[kb][t * 8], kbase[0] + off);
    async_lds16(&Ks[kb][(t + 384) * 8], kbase[1] + off);
  };
  auto STAGE_V = [&](int tile, int vb) {
    size_t off = (size_t)tile * 64;
    async_lds16(&Vs[vb][t * 8], vbase[0] + off);
    async_lds16(&Vs[vb][(t + 384) * 8], vbase[1] + off);
  };

  short8 qf[3];
#pragma unroll
  for (int f = 0; f < 3; ++f)
    qf[f] = *(const short8*)&q[((size_t)h * SEQ + q0 + lrow) * HDP + f * 32 + g * 8];

  float m_r = -1e30f, l_r = 0.f;
  f32x4 oa[5] = {};

  STAGE_K(0, 0);
  STAGE_V(0, 0);
  STAGE_K(1, 1);
  STAGE_V(1, 1);
  asm volatile("s_waitcnt vmcnt(6)" ::: "memory");  // K(0) landed
  __builtin_amdgcn_s_barrier();

  f32x4 stA[4] = {}, stB[4];
#pragma unroll
  for (int nf = 0; nf < 4; ++nf)
#pragma unroll
    for (int f = 0; f < 3; ++f) {
      short8 kfrag = *(const short8*)&Ks[0][(f * 4 + g) * 512 + (nf * 16 + lrow) * 8];
      stA[nf] = __builtin_amdgcn_mfma_f32_16x16x32_bf16(kfrag, qf[f], stA[nf], 0, 0, 0);
    }

  // softmax: defer-max (exp2 domain), lane-local partial l, P write (4 uint2)
  auto SOFTMAX = [&](f32x4* st) {
    float pmax = -1e30f;
#pragma unroll
    for (int nf = 0; nf < 4; ++nf)
      pmax = fmaxf(pmax, fmaxf(fmaxf(st[nf][0], st[nf][1]), fmaxf(st[nf][2], st[nf][3])));
    if (!__all(pmax - m_r <= 11.54f)) {
      float rm = pmax;
      rm = fmaxf(rm, __shfl_xor(rm, 16, 64));
      rm = fmaxf(rm, __shfl_xor(rm, 32, 64));
      float mn = fmaxf(m_r, rm);
      float alpha = exp2a(m_r - mn);
      l_r *= alpha;
#pragma unroll
      for (int nf = 0; nf < 5; ++nf)
#pragma unroll
        for (int r = 0; r < 4; ++r) oa[nf][r] *= alpha;
      m_r = mn;
    }
#pragma unroll
    for (int nf = 0; nf < 4; ++nf) {
#pragma unroll
      for (int r = 0; r < 4; ++r) st[nf][r] = exp2a(st[nf][r] - m_r);
      l_r += (st[nf][0] + st[nf][1]) + (st[nf][2] + st[nf][3]);
    }
#pragma unroll
    for (int nf = 0; nf < 4; ++nf) {
      uint2* dst = (uint2*)&Pl[w][(2 * nf + (g >> 1)) * 128 + lrow * 8 + (g & 1) * 4];
      *dst = make_uint2(cvt_pk2(st[nf][0], st[nf][1]), cvt_pk2(st[nf][2], st[nf][3]));
    }
  };

  auto PV = [&](int vb) {
    short8 pa0 = *(const short8*)&Pl[w][g * 128 + lrow * 8];
    short8 pa1 = *(const short8*)&Pl[w][(4 + g) * 128 + lrow * 8];
    __builtin_amdgcn_s_setprio(1);
#pragma unroll
    for (int nf = 0; nf < 5; ++nf) {
      short8 bv0 = *(const short8*)&Vs[vb][g * 768 + (nf * 16 + lrow) * 8];
      oa[nf] = __builtin_amdgcn_mfma_f32_16x16x32_bf16(bv0, pa0, oa[nf], 0, 0, 0);
      short8 bv1 = *(const short8*)&Vs[vb][(4 + g) * 768 + (nf * 16 + lrow) * 8];
      oa[nf] = __builtin_amdgcn_mfma_f32_16x16x32_bf16(bv1, pa1, oa[nf], 0, 0, 0);
    }
    __builtin_amdgcn_s_setprio(0);
  };

  for (int kt = 0; kt < NT - 1; ++kt) {
    asm volatile("s_waitcnt vmcnt(2)" ::: "memory");  // K(kt+1)+V(kt) landed; V(kt+1) flying
    __builtin_amdgcn_s_barrier();

    // QK(kt+1) from Ks[(kt+1)%3] (independent of softmax(kt) below)
    const int kb1 = (kt + 1) % 3;
#pragma unroll
    for (int nf = 0; nf < 4; ++nf) stB[nf] = (f32x4){0.f, 0.f, 0.f, 0.f};
    __builtin_amdgcn_s_setprio(1);
#pragma unroll
    for (int nf = 0; nf < 4; ++nf)
#pragma unroll
      for (int f = 0; f < 3; ++f) {
        short8 kfrag = *(const short8*)&Ks[kb1][(f * 4 + g) * 512 + (nf * 16 + lrow) * 8];
        stB[nf] = __builtin_amdgcn_mfma_f32_16x16x32_bf16(kfrag, qf[f], stB[nf], 0, 0, 0);
      }
    __builtin_amdgcn_s_setprio(0);

    SOFTMAX(stA);
    PV(kt & 1);

    asm volatile("s_waitcnt lgkmcnt(0)" ::: "memory");
    __builtin_amdgcn_s_barrier();
    int s = kt + 2;
    if (s >= NT) s -= NT;  // stale wrapped stages land in never-again-read buffers
    STAGE_K(s, (kt + 2) % 3);
    STAGE_V(s, kt & 1);
#pragma unroll
    for (int nf = 0; nf < 4; ++nf) stA[nf] = stB[nf];
  }

  // epilogue tile NT-1: V(NT-1) is the oldest outstanding pair
  asm volatile("s_waitcnt vmcnt(4)" ::: "memory");
  __builtin_amdgcn_s_barrier();
  SOFTMAX(stA);
  PV((NT - 1) & 1);

  // row-reduce partial l, store O^T (lane-local divide)
  float lt = l_r;
  lt += __shfl_xor(lt, 16, 64);
  lt += __shfl_xor(lt, 32, 64);
  float rcp = 1.f / lt;
  size_t obase = (size_t)(q0 + lrow) * HID + h * HD;
#pragma unroll
  for (int nf = 0; nf < 5; ++nf) {
    int d = nf * 16 + g * 4;
    if (d + 3 < HD) {
      uint2 pk = make_uint2(cvt_pk2(oa[nf][0] * rcp, oa[nf][1] * rcp),
                            cvt_pk2(oa[nf][2] * rcp, oa[nf][3] * rcp));
      *(uint2*)&o[obase + d] = pk;
    }
  }
}

// ---------------- launch ----------------
extern "C" void kernel_launch(void* const* d_in, const int* in_sizes, int n_in,
                              void* d_out, int out_size, void* d_ws, size_t ws_size,
                              hipStream_t stream) {
  (void)in_sizes; (void)n_in; (void)out_size;
  const float* hidden = (const float*)d_in[0];
  const float* cosb = (const float*)d_in[1];
  const float* sinb = (const float*)d_in[2];
  const float* ln0g = (const float*)d_in[3];
  const float* ln0b = (const float*)d_in[4];
  const float* ln1g = (const float*)d_in[5];
  const float* ln1b = (const float*)d_in[6];
  const float* wqkv = (const float*)d_in[7];
  const float* bqkv = (const float*)d_in[8];
  const float* wo = (const float*)d_in[9];
  const float* bo = (const float*)d_in[10];
  const float* w0 = (const float*)d_in[11];
  const float* b0 = (const float*)d_in[12];
  const float* w1 = (const float*)d_in[13];
  const float* b1 = (const float*)d_in[14];

  char* p = (char*)d_ws;
  auto alloc = [&](size_t n) {
    char* r = p;
    p += (n + 255) & ~(size_t)255;
    return r;
  };
  bf16* wqkv_bf = (bf16*)alloc((size_t)3 * HID * HID * 2);
  bf16* wo_bf = (bf16*)alloc((size_t)HID * HID * 2);
  bf16* fc0_bf = (bf16*)alloc((size_t)MLPP * HID * 2);
  bf16* fc1_bf = (bf16*)alloc((size_t)HID * MLPP * 2);
  bf16* ln0_bf = (bf16*)alloc((size_t)SEQ * HID * 2);
  float* xqkv = (float*)alloc((size_t)SEQ * 3 * HID * 4);
  bf16* qp = (bf16*)alloc((size_t)NHEAD * SEQ * HDP * 2);
  bf16* kp = (bf16*)alloc((size_t)NHEAD * SEQ * HDP * 2);
  bf16* vt = (bf16*)alloc((size_t)NHEAD * HDP * SEQ * 2);
  bf16* attn_bf = (bf16*)alloc((size_t)SEQ * HID * 2);
  float* h1 = (float*)alloc((size_t)SEQ * HID * 4);
  bf16* ln1_bf = (bf16*)alloc((size_t)SEQ * HID * 2);
  bf16* gelu_bf = (bf16*)alloc((size_t)SEQ * MLPP * 2);
  if ((size_t)(p - (char*)d_ws) > ws_size) return;

  dim3 blk(256);
  cast_bf16_k<<<2048, blk, 0, stream>>>(wqkv, (unsigned*)wqkv_bf, 3 * HID * HID / 4);
  cast_bf16_k<<<1024, blk, 0, stream>>>(wo, (unsigned*)wo_bf, HID * HID / 4);
  cast_pad_rows_k<<<2048, blk, 0, stream>>>(w0, (unsigned*)fc0_bf, MLPD, HID / 4, MLPP * HID / 4);
  cast_pad_cols_k<<<2048, blk, 0, stream>>>(w1, (unsigned*)fc1_bf, MLPD / 4, MLPP / 4, HID * MLPP / 4);
  ln_k<<<SEQ, blk, 0, stream>>>(hidden, ln0g, ln0b, ln0_bf);
  gemm_bf16<0><<<dim3((3 * HID / 128) * (SEQ / 128)), blk, 0, stream>>>(
      ln0_bf, wqkv_bf, bqkv, 3 * HID, nullptr, xqkv, nullptr, SEQ, 3 * HID, HID);
  rope_split<<<dim3(SEQ / 64, NHEAD), blk, 0, stream>>>(xqkv, cosb, sinb, qp, kp, vt);
  flash_attn<<<dim3(512), dim3(384), 0, stream>>>(qp, kp, vt, attn_bf);
  gemm_bf16<1><<<dim3((HID / 128) * (SEQ / 128)), blk, 0, stream>>>(
      attn_bf, wo_bf, bo, HID, hidden, h1, nullptr, SEQ, HID, HID);
  ln_k<<<SEQ, blk, 0, stream>>>(h1, ln1g, ln1b, ln1_bf);
  gemm_bf16<2><<<dim3((MLPP / 128) * (SEQ / 128)), blk, 0, stream>>>(
      ln1_bf, fc0_bf, b0, MLPD, nullptr, nullptr, gelu_bf, SEQ, MLPP, HID);
  gemm_bf16<1><<<dim3((HID / 128) * (SEQ / 128)), blk, 0, stream>>>(
      gelu_bf, fc1_bf, b1, HID, h1, (float*)d_out, nullptr, SEQ, HID, MLPP);
}

// Round 10
// 382.861 us; speedup vs baseline: 1.1086x; 1.1086x over previous
//
#include <hip/hip_runtime.h>
#include <hip/hip_bf16.h>
#include <math.h>

typedef __hip_bfloat16 bf16;
typedef __attribute__((ext_vector_type(8))) short short8;
typedef __attribute__((ext_vector_type(4))) short short4v;
typedef __attribute__((ext_vector_type(4))) float f32x4;

#define SEQ 3072
#define HID 1152
#define NHEAD 16
#define HD 72
#define HDP 96
#define MLPD 4304
#define MLPP 4352

__device__ __forceinline__ void async_lds16(void* lds, const void* g) {
  __builtin_amdgcn_global_load_lds((const __attribute__((address_space(1))) void*)g,
                                   (__attribute__((address_space(3))) void*)lds,
                                   16, 0, 0);
}

// one v_cvt_pk_bf16_f32: a -> low16, b -> high16 (RNE)
__device__ __forceinline__ unsigned cvt_pk2(float a, float b) {
  unsigned r;
  asm("v_cvt_pk_bf16_f32 %0, %1, %2" : "=v"(r) : "v"(a), "v"(b));
  return r;
}

// raw v_exp_f32: 2^x
__device__ __forceinline__ float exp2a(float x) {
  float r;
  asm("v_exp_f32 %0, %1" : "=v"(r) : "v"(x));
  return r;
}

// ---------------- weight cast kernels ----------------
__global__ __launch_bounds__(256) void cast_bf16_k(const float* __restrict__ in,
                                                   unsigned* __restrict__ out2, int n4) {
  int stride = gridDim.x * blockDim.x;
  for (int i = blockIdx.x * blockDim.x + threadIdx.x; i < n4; i += stride) {
    float4 u = ((const float4*)in)[i];
    uint2 w = make_uint2(cvt_pk2(u.x, u.y), cvt_pk2(u.z, u.w));
    ((uint2*)out2)[i] = w;
  }
}

__global__ __launch_bounds__(256) void cast_pad_rows_k(const float* __restrict__ in,
                                                       unsigned* __restrict__ out2,
                                                       int R, int C4, int n4) {
  int stride = gridDim.x * blockDim.x;
  for (int i = blockIdx.x * blockDim.x + threadIdx.x; i < n4; i += stride) {
    int r = i / C4;
    uint2 w = make_uint2(0u, 0u);
    if (r < R) {
      float4 u = ((const float4*)in)[i];
      w = make_uint2(cvt_pk2(u.x, u.y), cvt_pk2(u.z, u.w));
    }
    ((uint2*)out2)[i] = w;
  }
}

__global__ __launch_bounds__(256) void cast_pad_cols_k(const float* __restrict__ in,
                                                       unsigned* __restrict__ out2,
                                                       int C4, int Cp4, int n4) {
  int stride = gridDim.x * blockDim.x;
  for (int i = blockIdx.x * blockDim.x + threadIdx.x; i < n4; i += stride) {
    int r = i / Cp4, c4 = i - r * Cp4;
    uint2 w = make_uint2(0u, 0u);
    if (c4 < C4) {
      float4 u = ((const float4*)in)[r * C4 + c4];
      w = make_uint2(cvt_pk2(u.x, u.y), cvt_pk2(u.z, u.w));
    }
    ((uint2*)out2)[i] = w;
  }
}

// ---------------- layernorm (fp32 in -> bf16 out) ----------------
__global__ __launch_bounds__(256) void ln_k(const float* __restrict__ x,
                                            const float* __restrict__ g,
                                            const float* __restrict__ b,
                                            bf16* __restrict__ o) {
  int row = blockIdx.x;
  const float4* xr = (const float4*)(x + (size_t)row * HID);
  float sum = 0.f, sq = 0.f;
  for (int c = threadIdx.x; c < HID / 4; c += 256) {
    float4 u = xr[c];
    sum += u.x + u.y + u.z + u.w;
    sq += u.x * u.x + u.y * u.y + u.z * u.z + u.w * u.w;
  }
#pragma unroll
  for (int off = 32; off > 0; off >>= 1) {
    sum += __shfl_down(sum, off, 64);
    sq += __shfl_down(sq, off, 64);
  }
  __shared__ float red[8];
  int wv = threadIdx.x >> 6;
  if ((threadIdx.x & 63) == 0) { red[wv] = sum; red[4 + wv] = sq; }
  __syncthreads();
  if (threadIdx.x == 0) {
    red[0] = red[0] + red[1] + red[2] + red[3];
    red[4] = red[4] + red[5] + red[6] + red[7];
  }
  __syncthreads();
  float mu = red[0] * (1.f / HID);
  float var = red[4] * (1.f / HID) - mu * mu;
  float inv = rsqrtf(var + 1e-5f);
  uint2* o4 = (uint2*)(o + (size_t)row * HID);
  const float4* g4 = (const float4*)g;
  const float4* b4 = (const float4*)b;
  for (int c = threadIdx.x; c < HID / 4; c += 256) {
    float4 u = xr[c], gg = g4[c], bb = b4[c];
    uint2 w = make_uint2(cvt_pk2((u.x - mu) * inv * gg.x + bb.x, (u.y - mu) * inv * gg.y + bb.y),
                         cvt_pk2((u.z - mu) * inv * gg.z + bb.z, (u.w - mu) * inv * gg.w + bb.w));
    o4[c] = w;
  }
}

// ---------------- GEMM: C[M][N] = A[M][K] @ Bt[N][K]^T  (+ epilogue) ----------------
// 3 LDS buffers (48KB -> 3 blocks/CU), depth-2 prefetch, counted vmcnt,
// bijective XCD swizzle (x-major per XCD -> B-panel L2-resident).
// EPI 0: +bias -> fp32   1: +bias+res -> fp32   2: +bias, gelu -> bf16
template <int EPI>
__global__ __launch_bounds__(256) void gemm_bf16(const bf16* __restrict__ A,
                                                 const bf16* __restrict__ Bt,
                                                 const float* __restrict__ bias, int nbias,
                                                 const float* __restrict__ res,
                                                 float* __restrict__ outf,
                                                 bf16* __restrict__ outb,
                                                 int M, int N, int K) {
  __shared__ bf16 As[3][128 * 32];
  __shared__ bf16 Bs[3][128 * 32];
  const int t = threadIdx.x;
  const int l = t & 63;
  const int w = t >> 6;
  const int wr = w >> 1, wc = w & 1;
  const int lrow = l & 15;
  const int lk = (l >> 4) * 8;
  const int wg = (blockIdx.x & 7) * (gridDim.x >> 3) + (blockIdx.x >> 3);
  const int gyt = M >> 7;
  const int xt = wg / gyt;
  const int yt = wg - xt * gyt;
  const int m0 = yt * 128;
  const int n0 = xt * 128;
  const int arow = t >> 2;
  const int ach = (t & 3) * 8;

  const bf16* pa0 = &A[(size_t)(m0 + arow) * K + ach];
  const bf16* pa1 = &A[(size_t)(m0 + arow + 64) * K + ach];
  const bf16* pb0 = &Bt[(size_t)(n0 + arow) * K + ach];
  const bf16* pb1 = &Bt[(size_t)(n0 + arow + 64) * K + ach];
  auto STAGE = [&](int buf, int kt) {
    size_t off = (size_t)kt * 32;
    async_lds16(&As[buf][t * 8], pa0 + off);
    async_lds16(&As[buf][(256 + t) * 8], pa1 + off);
    async_lds16(&Bs[buf][t * 8], pb0 + off);
    async_lds16(&Bs[buf][(256 + t) * 8], pb1 + off);
  };

  f32x4 acc[4][4] = {};
  const int nkt = K >> 5;
  STAGE(0, 0);
  STAGE(1, 1);
  int bcur = 0;
  for (int kt = 0; kt < nkt; ++kt) {
    if (kt + 1 < nkt) {
      asm volatile("s_waitcnt vmcnt(4)" ::: "memory");  // stage kt landed; kt+1 in flight
    } else {
      asm volatile("s_waitcnt vmcnt(0)" ::: "memory");
    }
    __builtin_amdgcn_s_barrier();
    int bn2 = bcur + 2;
    if (bn2 >= 3) bn2 -= 3;
    if (kt + 2 < nkt) STAGE(bn2, kt + 2);

    short8 af[4], bfr[4];
#pragma unroll
    for (int i = 0; i < 4; ++i)
      af[i] = *(const short8*)&As[bcur][(wr * 64 + i * 16 + lrow) * 32 + lk];
#pragma unroll
    for (int i = 0; i < 4; ++i)
      bfr[i] = *(const short8*)&Bs[bcur][(wc * 64 + i * 16 + lrow) * 32 + lk];
    __builtin_amdgcn_s_setprio(1);
#pragma unroll
    for (int i = 0; i < 4; ++i)
#pragma unroll
      for (int j = 0; j < 4; ++j)
        acc[i][j] = __builtin_amdgcn_mfma_f32_16x16x32_bf16(af[i], bfr[j], acc[i][j], 0, 0, 0);
    __builtin_amdgcn_s_setprio(0);
    ++bcur;
    if (bcur == 3) bcur = 0;
  }

#pragma unroll
  for (int i = 0; i < 4; ++i) {
    int rowb = m0 + wr * 64 + i * 16 + (l >> 4) * 4;
#pragma unroll
    for (int j = 0; j < 4; ++j) {
      int col = n0 + wc * 64 + j * 16 + lrow;
      float bv = (col < nbias) ? bias[col] : 0.f;
#pragma unroll
      for (int r2 = 0; r2 < 4; ++r2) {
        size_t idx = (size_t)(rowb + r2) * N + col;
        float v = acc[i][j][r2] + bv;
        if (EPI == 0) {
          outf[idx] = v;
        } else if (EPI == 1) {
          outf[idx] = v + res[idx];
        } else {
          float u = 0.7978845608028654f * (v + 0.044715f * v * v * v);
          u = fminf(fmaxf(u, -15.f), 15.f);
          float tt = __expf(2.f * u);
          outb[idx] = __float2bfloat16(v * tt / (tt + 1.f));
        }
      }
    }
  }
}

// ---------------- rope + qkv split ----------------
// q scale folds log2(e) so flash softmax runs in exp2 domain.
__global__ __launch_bounds__(256) void rope_split(const float* __restrict__ xqkv,
                                                  const float* __restrict__ cosb,
                                                  const float* __restrict__ sinb,
                                                  bf16* __restrict__ qp,
                                                  bf16* __restrict__ kp,
                                                  bf16* __restrict__ vt) {
  __shared__ bf16 vl[64][72];
  const int t = threadIdx.x;
  const int h = blockIdx.y;
  const int s0 = blockIdx.x * 64;
  const float scale = 0.17002445f;  // (1/sqrt(72)) * log2(e)
  for (int idx = t; idx < 64 * 48; idx += 256) {
    int sl = idx / 48, pi = idx - sl * 48;
    int srow = s0 + sl;
    size_t obase = ((size_t)h * SEQ + srow) * HDP + 2 * pi;
    if (pi < 36) {
      const float* xr = xqkv + (size_t)srow * (3 * HID) + h * HD + 2 * pi;
      float qr = xr[0], qi = xr[1];
      float kr = xr[HID], ki = xr[HID + 1];
      float c = cosb[srow * 36 + pi], sn = sinb[srow * 36 + pi];
      *(unsigned*)&qp[obase] = cvt_pk2((qr * c - qi * sn) * scale, (qr * sn + qi * c) * scale);
      *(unsigned*)&kp[obase] = cvt_pk2(kr * c - ki * sn, kr * sn + ki * c);
    } else {
      *(unsigned*)&qp[obase] = 0u;
      *(unsigned*)&kp[obase] = 0u;
    }
  }
  for (int idx = t; idx < 64 * 72; idx += 256) {
    int sl = idx / 72, d = idx - sl * 72;
    vl[sl][d] = __float2bfloat16(xqkv[(size_t)(s0 + sl) * (3 * HID) + 2 * HID + h * HD + d]);
  }
  __syncthreads();
  bf16 z = __float2bfloat16(0.f);
  for (int idx = t; idx < HDP * 64; idx += 256) {
    int d = idx / 64, sl = idx - d * 64;
    vt[((size_t)h * HDP + d) * SEQ + s0 + sl] = (d < 72) ? vl[sl][d] : z;
  }
}

// ---------------- flash attention (best-known config: KVBLK=32, 4 waves, 40KB) ----------------
// Triple-buffered KV, QK(t+1)-ahead, swapped operands (lane-local softmax),
// exp2-domain (log2e folded into q scale), defer-max THR=8*log2(e)=11.54,
// lane-local partial l (row-reduced once in epilogue). Grid 768 = 3 blocks/CU.
// K buf [32 kv][96 d] chunk-major: elem = cb*256 + kv*8 + e
// V buf [96 d][32 kv] chunk-major: elem = 3072 + cb*768 + d*8 + e
__global__ __launch_bounds__(256) void flash_attn(const bf16* __restrict__ q,
                                                  const bf16* __restrict__ kk,
                                                  const bf16* __restrict__ vT,
                                                  bf16* __restrict__ o) {
  __shared__ alignas(16) bf16 KV3[3 * 6144];
  __shared__ alignas(16) bf16 Pl[4][512];
  const int t = threadIdx.x;
  const int l = t & 63;
  const int w = t >> 6;
  const int g = l >> 4;
  const int lrow = l & 15;
  const int bid = blockIdx.x;
  const int kq = bid >> 3;
  const int h = (bid & 7) * 2 + (kq & 1);
  const int q0 = (kq >> 1) * 64 + w * 16;
  const int NT = SEQ / 32;

  const bf16* sbase[3];
  int smul[3];
#pragma unroll
  for (int i = 0; i < 3; ++i) {
    int s = t + i * 256;
    if (s < 384) {
      int cb = s >> 5, kv = s & 31;
      sbase[i] = kk + ((size_t)h * SEQ + kv) * HDP + cb * 8;
      smul[i] = 32 * HDP;
    } else {
      int vs = s - 384;
      int cb = vs / 96, d = vs - cb * 96;
      sbase[i] = vT + ((size_t)h * HDP + d) * SEQ + cb * 8;
      smul[i] = 32;
    }
  }
  auto STAGE = [&](int tile, int bufOff) {
#pragma unroll
    for (int i = 0; i < 3; ++i)
      async_lds16(&KV3[bufOff + (t + i * 256) * 8], sbase[i] + (size_t)tile * smul[i]);
  };

  short8 qf[3];
#pragma unroll
  for (int f = 0; f < 3; ++f)
    qf[f] = *(const short8*)&q[((size_t)h * SEQ + q0 + lrow) * HDP + f * 32 + g * 8];

  float m_r = -1e30f, l_r = 0.f;
  f32x4 oa[5] = {};

  STAGE(0, 0);
  STAGE(1, 6144);
  STAGE(2, 12288);
  asm volatile("s_waitcnt vmcnt(6)" ::: "memory");
  __builtin_amdgcn_s_barrier();

  f32x4 stA[2] = {}, stB[2];
  int b0 = 0;
#pragma unroll
  for (int nf = 0; nf < 2; ++nf)
#pragma unroll
    for (int f = 0; f < 3; ++f) {
      short8 kfrag = *(const short8*)&KV3[0 + (f * 4 + g) * 256 + (nf * 16 + lrow) * 8];
      stA[nf] = __builtin_amdgcn_mfma_f32_16x16x32_bf16(kfrag, qf[f], stA[nf], 0, 0, 0);
    }

  for (int kt = 0; kt < NT - 1; ++kt) {
    int b1 = b0 + 6144;
    if (b1 == 18432) b1 = 0;
    asm volatile("s_waitcnt vmcnt(3)" ::: "memory");
    __builtin_amdgcn_s_barrier();

    // QK(kt+1) from b1 (independent of softmax(kt) below)
    stB[0] = (f32x4){0.f, 0.f, 0.f, 0.f};
    stB[1] = (f32x4){0.f, 0.f, 0.f, 0.f};
    __builtin_amdgcn_s_setprio(1);
#pragma unroll
    for (int nf = 0; nf < 2; ++nf)
#pragma unroll
      for (int f = 0; f < 3; ++f) {
        short8 kfrag = *(const short8*)&KV3[b1 + (f * 4 + g) * 256 + (nf * 16 + lrow) * 8];
        stB[nf] = __builtin_amdgcn_mfma_f32_16x16x32_bf16(kfrag, qf[f], stB[nf], 0, 0, 0);
      }
    __builtin_amdgcn_s_setprio(0);

    // softmax(kt): defer-max (exp2 domain), lane-local partial l
    float pmax = fmaxf(fmaxf(fmaxf(stA[0][0], stA[0][1]), fmaxf(stA[0][2], stA[0][3])),
                       fmaxf(fmaxf(stA[1][0], stA[1][1]), fmaxf(stA[1][2], stA[1][3])));
    if (!__all(pmax - m_r <= 11.54f)) {
      float rm = pmax;
      rm = fmaxf(rm, __shfl_xor(rm, 16, 64));
      rm = fmaxf(rm, __shfl_xor(rm, 32, 64));
      float mn = fmaxf(m_r, rm);
      float alpha = exp2a(m_r - mn);
      l_r *= alpha;
#pragma unroll
      for (int nf = 0; nf < 5; ++nf)
#pragma unroll
        for (int r = 0; r < 4; ++r) oa[nf][r] *= alpha;
      m_r = mn;
    }
#pragma unroll
    for (int nf = 0; nf < 2; ++nf)
#pragma unroll
      for (int r = 0; r < 4; ++r) stA[nf][r] = exp2a(stA[nf][r] - m_r);
    l_r += (stA[0][0] + stA[0][1]) + (stA[0][2] + stA[0][3]) +
           (stA[1][0] + stA[1][1]) + (stA[1][2] + stA[1][3]);

    // P write: kv = nf*16+g*4+r, q=lrow -> elem = (2nf+(g>>1))*128 + lrow*8 + (g&1)*4
#pragma unroll
    for (int nf = 0; nf < 2; ++nf) {
      uint2* dst = (uint2*)&Pl[w][(2 * nf + (g >> 1)) * 128 + lrow * 8 + (g & 1) * 4];
      *dst = make_uint2(cvt_pk2(stA[nf][0], stA[nf][1]), cvt_pk2(stA[nf][2], stA[nf][3]));
    }

    // PV(kt) from b0: O^T += V' x P'
    {
      short8 pa = *(const short8*)&Pl[w][g * 128 + lrow * 8];
      __builtin_amdgcn_s_setprio(1);
#pragma unroll
      for (int nf = 0; nf < 5; ++nf) {
        short8 bv = *(const short8*)&KV3[b0 + 3072 + g * 768 + (nf * 16 + lrow) * 8];
        oa[nf] = __builtin_amdgcn_mfma_f32_16x16x32_bf16(bv, pa, oa[nf], 0, 0, 0);
      }
      __builtin_amdgcn_s_setprio(0);
    }

    asm volatile("s_waitcnt lgkmcnt(0)" ::: "memory");
    __builtin_amdgcn_s_barrier();
    int s = kt + 3;
    if (s >= NT) s -= NT;
    STAGE(s, b0);
    stA[0] = stB[0];
    stA[1] = stB[1];
    b0 = b1;
  }

  // epilogue tile NT-1
  {
    float pmax = fmaxf(fmaxf(fmaxf(stA[0][0], stA[0][1]), fmaxf(stA[0][2], stA[0][3])),
                       fmaxf(fmaxf(stA[1][0], stA[1][1]), fmaxf(stA[1][2], stA[1][3])));
    if (!__all(pmax - m_r <= 11.54f)) {
      float rm = pmax;
      rm = fmaxf(rm, __shfl_xor(rm, 16, 64));
      rm = fmaxf(rm, __shfl_xor(rm, 32, 64));
      float mn = fmaxf(m_r, rm);
      float alpha = exp2a(m_r - mn);
      l_r *= alpha;
#pragma unroll
      for (int nf = 0; nf < 5; ++nf)
#pragma unroll
        for (int r = 0; r < 4; ++r) oa[nf][r] *= alpha;
      m_r = mn;
    }
#pragma unroll
    for (int nf = 0; nf < 2; ++nf)
#pragma unroll
      for (int r = 0; r < 4; ++r) stA[nf][r] = exp2a(stA[nf][r] - m_r);
    l_r += (stA[0][0] + stA[0][1]) + (stA[0][2] + stA[0][3]) +
           (stA[1][0] + stA[1][1]) + (stA[1][2] + stA[1][3]);
#pragma unroll
    for (int nf = 0; nf < 2; ++nf) {
      uint2* dst = (uint2*)&Pl[w][(2 * nf + (g >> 1)) * 128 + lrow * 8 + (g & 1) * 4];
      *dst = make_uint2(cvt_pk2(stA[nf][0], stA[nf][1]), cvt_pk2(stA[nf][2], stA[nf][3]));
    }
    short8 pa = *(const short8*)&Pl[w][g * 128 + lrow * 8];
#pragma unroll
    for (int nf = 0; nf < 5; ++nf) {
      short8 bv = *(const short8*)&KV3[b0 + 3072 + g * 768 + (nf * 16 + lrow) * 8];
      oa[nf] = __builtin_amdgcn_mfma_f32_16x16x32_bf16(bv, pa, oa[nf], 0, 0, 0);
    }
  }

  // row-reduce the partial l (deferred from the loop), then store
  float lt = l_r;
  lt += __shfl_xor(lt, 16, 64);
  lt += __shfl_xor(lt, 32, 64);
  float rcp = 1.f / lt;
  size_t obase = (size_t)(q0 + lrow) * HID + h * HD;
#pragma unroll
  for (int nf = 0; nf < 5; ++nf) {
    int d = nf * 16 + g * 4;
    if (d + 3 < HD) {
      uint2 pk = make_uint2(cvt_pk2(oa[nf][0] * rcp, oa[nf][1] * rcp),
                            cvt_pk2(oa[nf][2] * rcp, oa[nf][3] * rcp));
      *(uint2*)&o[obase + d] = pk;
    }
  }
}

// ---------------- launch ----------------
extern "C" void kernel_launch(void* const* d_in, const int* in_sizes, int n_in,
                              void* d_out, int out_size, void* d_ws, size_t ws_size,
                              hipStream_t stream) {
  (void)in_sizes; (void)n_in; (void)out_size;
  const float* hidden = (const float*)d_in[0];
  const float* cosb = (const float*)d_in[1];
  const float* sinb = (const float*)d_in[2];
  const float* ln0g = (const float*)d_in[3];
  const float* ln0b = (const float*)d_in[4];
  const float* ln1g = (const float*)d_in[5];
  const float* ln1b = (const float*)d_in[6];
  const float* wqkv = (const float*)d_in[7];
  const float* bqkv = (const float*)d_in[8];
  const float* wo = (const float*)d_in[9];
  const float* bo = (const float*)d_in[10];
  const float* w0 = (const float*)d_in[11];
  const float* b0 = (const float*)d_in[12];
  const float* w1 = (const float*)d_in[13];
  const float* b1 = (const float*)d_in[14];

  char* p = (char*)d_ws;
  auto alloc = [&](size_t n) {
    char* r = p;
    p += (n + 255) & ~(size_t)255;
    return r;
  };
  bf16* wqkv_bf = (bf16*)alloc((size_t)3 * HID * HID * 2);
  bf16* wo_bf = (bf16*)alloc((size_t)HID * HID * 2);
  bf16* fc0_bf = (bf16*)alloc((size_t)MLPP * HID * 2);
  bf16* fc1_bf = (bf16*)alloc((size_t)HID * MLPP * 2);
  bf16* ln0_bf = (bf16*)alloc((size_t)SEQ * HID * 2);
  float* xqkv = (float*)alloc((size_t)SEQ * 3 * HID * 4);
  bf16* qp = (bf16*)alloc((size_t)NHEAD * SEQ * HDP * 2);
  bf16* kp = (bf16*)alloc((size_t)NHEAD * SEQ * HDP * 2);
  bf16* vt = (bf16*)alloc((size_t)NHEAD * HDP * SEQ * 2);
  bf16* attn_bf = (bf16*)alloc((size_t)SEQ * HID * 2);
  float* h1 = (float*)alloc((size_t)SEQ * HID * 4);
  bf16* ln1_bf = (bf16*)alloc((size_t)SEQ * HID * 2);
  bf16* gelu_bf = (bf16*)alloc((size_t)SEQ * MLPP * 2);
  if ((size_t)(p - (char*)d_ws) > ws_size) return;

  dim3 blk(256);
  cast_bf16_k<<<2048, blk, 0, stream>>>(wqkv, (unsigned*)wqkv_bf, 3 * HID * HID / 4);
  cast_bf16_k<<<1024, blk, 0, stream>>>(wo, (unsigned*)wo_bf, HID * HID / 4);
  cast_pad_rows_k<<<2048, blk, 0, stream>>>(w0, (unsigned*)fc0_bf, MLPD, HID / 4, MLPP * HID / 4);
  cast_pad_cols_k<<<2048, blk, 0, stream>>>(w1, (unsigned*)fc1_bf, MLPD / 4, MLPP / 4, HID * MLPP / 4);
  ln_k<<<SEQ, blk, 0, stream>>>(hidden, ln0g, ln0b, ln0_bf);
  gemm_bf16<0><<<dim3((3 * HID / 128) * (SEQ / 128)), blk, 0, stream>>>(
      ln0_bf, wqkv_bf, bqkv, 3 * HID, nullptr, xqkv, nullptr, SEQ, 3 * HID, HID);
  rope_split<<<dim3(SEQ / 64, NHEAD), blk, 0, stream>>>(xqkv, cosb, sinb, qp, kp, vt);
  flash_attn<<<dim3(768), blk, 0, stream>>>(qp, kp, vt, attn_bf);
  gemm_bf16<1><<<dim3((HID / 128) * (SEQ / 128)), blk, 0, stream>>>(
      attn_bf, wo_bf, bo, HID, hidden, h1, nullptr, SEQ, HID, HID);
  ln_k<<<SEQ, blk, 0, stream>>>(h1, ln1g, ln1b, ln1_bf);
  gemm_bf16<2><<<dim3((MLPP / 128) * (SEQ / 128)), blk, 0, stream>>>(
      ln1_bf, fc0_bf, b0, MLPD, nullptr, nullptr, gelu_bf, SEQ, MLPP, HID);
  gemm_bf16<1><<<dim3((HID / 128) * (SEQ / 128)), blk, 0, stream>>>(
      gelu_bf, fc1_bf, b1, HID, h1, (float*)d_out, nullptr, SEQ, HID, MLPP);
}

// Round 11
// 378.131 us; speedup vs baseline: 1.1225x; 1.0125x over previous
//
#include <hip/hip_runtime.h>
#include <hip/hip_bf16.h>
#include <math.h>

typedef __hip_bfloat16 bf16;
typedef __attribute__((ext_vector_type(8))) short short8;
typedef __attribute__((ext_vector_type(4))) short short4v;
typedef __attribute__((ext_vector_type(4))) float f32x4;

#define SEQ 3072
#define HID 1152
#define NHEAD 16
#define HD 72
#define HDP 96
#define MLPD 4304
#define MLPP 4352

__device__ __forceinline__ void async_lds16(void* lds, const void* g) {
  __builtin_amdgcn_global_load_lds((const __attribute__((address_space(1))) void*)g,
                                   (__attribute__((address_space(3))) void*)lds,
                                   16, 0, 0);
}

// one v_cvt_pk_bf16_f32: a -> low16, b -> high16 (RNE)
__device__ __forceinline__ unsigned cvt_pk2(float a, float b) {
  unsigned r;
  asm("v_cvt_pk_bf16_f32 %0, %1, %2" : "=v"(r) : "v"(a), "v"(b));
  return r;
}

// raw v_exp_f32: 2^x
__device__ __forceinline__ float exp2a(float x) {
  float r;
  asm("v_exp_f32 %0, %1" : "=v"(r) : "v"(x));
  return r;
}

// ---------------- weight cast kernels ----------------
__global__ __launch_bounds__(256) void cast_bf16_k(const float* __restrict__ in,
                                                   unsigned* __restrict__ out2, int n4) {
  int stride = gridDim.x * blockDim.x;
  for (int i = blockIdx.x * blockDim.x + threadIdx.x; i < n4; i += stride) {
    float4 u = ((const float4*)in)[i];
    uint2 w = make_uint2(cvt_pk2(u.x, u.y), cvt_pk2(u.z, u.w));
    ((uint2*)out2)[i] = w;
  }
}

__global__ __launch_bounds__(256) void cast_pad_rows_k(const float* __restrict__ in,
                                                       unsigned* __restrict__ out2,
                                                       int R, int C4, int n4) {
  int stride = gridDim.x * blockDim.x;
  for (int i = blockIdx.x * blockDim.x + threadIdx.x; i < n4; i += stride) {
    int r = i / C4;
    uint2 w = make_uint2(0u, 0u);
    if (r < R) {
      float4 u = ((const float4*)in)[i];
      w = make_uint2(cvt_pk2(u.x, u.y), cvt_pk2(u.z, u.w));
    }
    ((uint2*)out2)[i] = w;
  }
}

__global__ __launch_bounds__(256) void cast_pad_cols_k(const float* __restrict__ in,
                                                       unsigned* __restrict__ out2,
                                                       int C4, int Cp4, int n4) {
  int stride = gridDim.x * blockDim.x;
  for (int i = blockIdx.x * blockDim.x + threadIdx.x; i < n4; i += stride) {
    int r = i / Cp4, c4 = i - r * Cp4;
    uint2 w = make_uint2(0u, 0u);
    if (c4 < C4) {
      float4 u = ((const float4*)in)[r * C4 + c4];
      w = make_uint2(cvt_pk2(u.x, u.y), cvt_pk2(u.z, u.w));
    }
    ((uint2*)out2)[i] = w;
  }
}

// ---------------- layernorm (fp32 in -> bf16 out) ----------------
__global__ __launch_bounds__(256) void ln_k(const float* __restrict__ x,
                                            const float* __restrict__ g,
                                            const float* __restrict__ b,
                                            bf16* __restrict__ o) {
  int row = blockIdx.x;
  const float4* xr = (const float4*)(x + (size_t)row * HID);
  float sum = 0.f, sq = 0.f;
  for (int c = threadIdx.x; c < HID / 4; c += 256) {
    float4 u = xr[c];
    sum += u.x + u.y + u.z + u.w;
    sq += u.x * u.x + u.y * u.y + u.z * u.z + u.w * u.w;
  }
#pragma unroll
  for (int off = 32; off > 0; off >>= 1) {
    sum += __shfl_down(sum, off, 64);
    sq += __shfl_down(sq, off, 64);
  }
  __shared__ float red[8];
  int wv = threadIdx.x >> 6;
  if ((threadIdx.x & 63) == 0) { red[wv] = sum; red[4 + wv] = sq; }
  __syncthreads();
  if (threadIdx.x == 0) {
    red[0] = red[0] + red[1] + red[2] + red[3];
    red[4] = red[4] + red[5] + red[6] + red[7];
  }
  __syncthreads();
  float mu = red[0] * (1.f / HID);
  float var = red[4] * (1.f / HID) - mu * mu;
  float inv = rsqrtf(var + 1e-5f);
  uint2* o4 = (uint2*)(o + (size_t)row * HID);
  const float4* g4 = (const float4*)g;
  const float4* b4 = (const float4*)b;
  for (int c = threadIdx.x; c < HID / 4; c += 256) {
    float4 u = xr[c], gg = g4[c], bb = b4[c];
    uint2 w = make_uint2(cvt_pk2((u.x - mu) * inv * gg.x + bb.x, (u.y - mu) * inv * gg.y + bb.y),
                         cvt_pk2((u.z - mu) * inv * gg.z + bb.z, (u.w - mu) * inv * gg.w + bb.w));
    o4[c] = w;
  }
}

// ---------------- GEMM: C[M][N] = A[M][K] @ Bt[N][K]^T  (+ epilogue) ----------------
// 3 LDS buffers (48KB -> 3 blocks/CU), depth-2 prefetch, counted vmcnt,
// bijective XCD swizzle (x-major per XCD -> B-panel L2-resident).
// EPI 0: +bias -> fp32   1: +bias+res -> fp32   2: +bias, gelu -> bf16
template <int EPI>
__global__ __launch_bounds__(256) void gemm_bf16(const bf16* __restrict__ A,
                                                 const bf16* __restrict__ Bt,
                                                 const float* __restrict__ bias, int nbias,
                                                 const float* __restrict__ res,
                                                 float* __restrict__ outf,
                                                 bf16* __restrict__ outb,
                                                 int M, int N, int K) {
  __shared__ bf16 As[3][128 * 32];
  __shared__ bf16 Bs[3][128 * 32];
  const int t = threadIdx.x;
  const int l = t & 63;
  const int w = t >> 6;
  const int wr = w >> 1, wc = w & 1;
  const int lrow = l & 15;
  const int lk = (l >> 4) * 8;
  const int wg = (blockIdx.x & 7) * (gridDim.x >> 3) + (blockIdx.x >> 3);
  const int gyt = M >> 7;
  const int xt = wg / gyt;
  const int yt = wg - xt * gyt;
  const int m0 = yt * 128;
  const int n0 = xt * 128;
  const int arow = t >> 2;
  const int ach = (t & 3) * 8;

  const bf16* pa0 = &A[(size_t)(m0 + arow) * K + ach];
  const bf16* pa1 = &A[(size_t)(m0 + arow + 64) * K + ach];
  const bf16* pb0 = &Bt[(size_t)(n0 + arow) * K + ach];
  const bf16* pb1 = &Bt[(size_t)(n0 + arow + 64) * K + ach];
  auto STAGE = [&](int buf, int kt) {
    size_t off = (size_t)kt * 32;
    async_lds16(&As[buf][t * 8], pa0 + off);
    async_lds16(&As[buf][(256 + t) * 8], pa1 + off);
    async_lds16(&Bs[buf][t * 8], pb0 + off);
    async_lds16(&Bs[buf][(256 + t) * 8], pb1 + off);
  };

  f32x4 acc[4][4] = {};
  const int nkt = K >> 5;
  STAGE(0, 0);
  STAGE(1, 1);
  int bcur = 0;
  for (int kt = 0; kt < nkt; ++kt) {
    if (kt + 1 < nkt) {
      asm volatile("s_waitcnt vmcnt(4)" ::: "memory");  // stage kt landed; kt+1 in flight
    } else {
      asm volatile("s_waitcnt vmcnt(0)" ::: "memory");
    }
    __builtin_amdgcn_s_barrier();
    int bn2 = bcur + 2;
    if (bn2 >= 3) bn2 -= 3;
    if (kt + 2 < nkt) STAGE(bn2, kt + 2);

    short8 af[4], bfr[4];
#pragma unroll
    for (int i = 0; i < 4; ++i)
      af[i] = *(const short8*)&As[bcur][(wr * 64 + i * 16 + lrow) * 32 + lk];
#pragma unroll
    for (int i = 0; i < 4; ++i)
      bfr[i] = *(const short8*)&Bs[bcur][(wc * 64 + i * 16 + lrow) * 32 + lk];
    __builtin_amdgcn_s_setprio(1);
#pragma unroll
    for (int i = 0; i < 4; ++i)
#pragma unroll
      for (int j = 0; j < 4; ++j)
        acc[i][j] = __builtin_amdgcn_mfma_f32_16x16x32_bf16(af[i], bfr[j], acc[i][j], 0, 0, 0);
    __builtin_amdgcn_s_setprio(0);
    ++bcur;
    if (bcur == 3) bcur = 0;
  }

#pragma unroll
  for (int i = 0; i < 4; ++i) {
    int rowb = m0 + wr * 64 + i * 16 + (l >> 4) * 4;
#pragma unroll
    for (int j = 0; j < 4; ++j) {
      int col = n0 + wc * 64 + j * 16 + lrow;
      float bv = (col < nbias) ? bias[col] : 0.f;
#pragma unroll
      for (int r2 = 0; r2 < 4; ++r2) {
        size_t idx = (size_t)(rowb + r2) * N + col;
        float v = acc[i][j][r2] + bv;
        if (EPI == 0) {
          outf[idx] = v;
        } else if (EPI == 1) {
          outf[idx] = v + res[idx];
        } else {
          float u = 0.7978845608028654f * (v + 0.044715f * v * v * v);
          u = fminf(fmaxf(u, -15.f), 15.f);
          float tt = __expf(2.f * u);
          outb[idx] = __float2bfloat16(v * tt / (tt + 1.f));
        }
      }
    }
  }
}

// ---------------- rope + qkv split ----------------
// q scale folds log2(e) so flash softmax runs in exp2 domain.
__global__ __launch_bounds__(256) void rope_split(const float* __restrict__ xqkv,
                                                  const float* __restrict__ cosb,
                                                  const float* __restrict__ sinb,
                                                  bf16* __restrict__ qp,
                                                  bf16* __restrict__ kp,
                                                  bf16* __restrict__ vt) {
  __shared__ bf16 vl[64][72];
  const int t = threadIdx.x;
  const int h = blockIdx.y;
  const int s0 = blockIdx.x * 64;
  const float scale = 0.17002445f;  // (1/sqrt(72)) * log2(e)
  for (int idx = t; idx < 64 * 48; idx += 256) {
    int sl = idx / 48, pi = idx - sl * 48;
    int srow = s0 + sl;
    size_t obase = ((size_t)h * SEQ + srow) * HDP + 2 * pi;
    if (pi < 36) {
      const float* xr = xqkv + (size_t)srow * (3 * HID) + h * HD + 2 * pi;
      float qr = xr[0], qi = xr[1];
      float kr = xr[HID], ki = xr[HID + 1];
      float c = cosb[srow * 36 + pi], sn = sinb[srow * 36 + pi];
      *(unsigned*)&qp[obase] = cvt_pk2((qr * c - qi * sn) * scale, (qr * sn + qi * c) * scale);
      *(unsigned*)&kp[obase] = cvt_pk2(kr * c - ki * sn, kr * sn + ki * c);
    } else {
      *(unsigned*)&qp[obase] = 0u;
      *(unsigned*)&kp[obase] = 0u;
    }
  }
  for (int idx = t; idx < 64 * 72; idx += 256) {
    int sl = idx / 72, d = idx - sl * 72;
    vl[sl][d] = __float2bfloat16(xqkv[(size_t)(s0 + sl) * (3 * HID) + 2 * HID + h * HD + d]);
  }
  __syncthreads();
  bf16 z = __float2bfloat16(0.f);
  for (int idx = t; idx < HDP * 64; idx += 256) {
    int d = idx / 64, sl = idx - d * 64;
    vt[((size_t)h * HDP + d) * SEQ + s0 + sl] = (d < 72) ? vl[sl][d] : z;
  }
}

// ---------------- flash attention (best-known config: KVBLK=32, 4 waves, 40KB) ----------------
// Triple-buffered KV, QK(t+1)-ahead, swapped operands (lane-local softmax),
// exp2-domain (log2e folded into q scale), defer-max THR=8*log2(e)=11.54,
// lane-local partial l (row-reduced once in epilogue). Grid 768 = 3 blocks/CU.
// K buf [32 kv][96 d] chunk-major: elem = cb*256 + kv*8 + e
// V buf [96 d][32 kv] chunk-major: elem = 3072 + cb*768 + d*8 + e
__global__ __launch_bounds__(256) void flash_attn(const bf16* __restrict__ q,
                                                  const bf16* __restrict__ kk,
                                                  const bf16* __restrict__ vT,
                                                  bf16* __restrict__ o) {
  __shared__ alignas(16) bf16 KV3[3 * 6144];
  __shared__ alignas(16) bf16 Pl[4][512];
  const int t = threadIdx.x;
  const int l = t & 63;
  const int w = t >> 6;
  const int g = l >> 4;
  const int lrow = l & 15;
  const int bid = blockIdx.x;
  const int kq = bid >> 3;
  const int h = (bid & 7) * 2 + (kq & 1);
  const int q0 = (kq >> 1) * 64 + w * 16;
  const int NT = SEQ / 32;

  const bf16* sbase[3];
  int smul[3];
#pragma unroll
  for (int i = 0; i < 3; ++i) {
    int s = t + i * 256;
    if (s < 384) {
      int cb = s >> 5, kv = s & 31;
      sbase[i] = kk + ((size_t)h * SEQ + kv) * HDP + cb * 8;
      smul[i] = 32 * HDP;
    } else {
      int vs = s - 384;
      int cb = vs / 96, d = vs - cb * 96;
      sbase[i] = vT + ((size_t)h * HDP + d) * SEQ + cb * 8;
      smul[i] = 32;
    }
  }
  auto STAGE = [&](int tile, int bufOff) {
#pragma unroll
    for (int i = 0; i < 3; ++i)
      async_lds16(&KV3[bufOff + (t + i * 256) * 8], sbase[i] + (size_t)tile * smul[i]);
  };

  short8 qf[3];
#pragma unroll
  for (int f = 0; f < 3; ++f)
    qf[f] = *(const short8*)&q[((size_t)h * SEQ + q0 + lrow) * HDP + f * 32 + g * 8];

  float m_r = -1e30f, l_r = 0.f;
  f32x4 oa[5] = {};

  STAGE(0, 0);
  STAGE(1, 6144);
  STAGE(2, 12288);
  asm volatile("s_waitcnt vmcnt(6)" ::: "memory");
  __builtin_amdgcn_s_barrier();

  f32x4 stA[2] = {}, stB[2];
  int b0 = 0;
#pragma unroll
  for (int nf = 0; nf < 2; ++nf)
#pragma unroll
    for (int f = 0; f < 3; ++f) {
      short8 kfrag = *(const short8*)&KV3[0 + (f * 4 + g) * 256 + (nf * 16 + lrow) * 8];
      stA[nf] = __builtin_amdgcn_mfma_f32_16x16x32_bf16(kfrag, qf[f], stA[nf], 0, 0, 0);
    }

  for (int kt = 0; kt < NT - 1; ++kt) {
    int b1 = b0 + 6144;
    if (b1 == 18432) b1 = 0;
    asm volatile("s_waitcnt vmcnt(3)" ::: "memory");
    __builtin_amdgcn_s_barrier();

    // QK(kt+1) from b1 (independent of softmax(kt) below)
    stB[0] = (f32x4){0.f, 0.f, 0.f, 0.f};
    stB[1] = (f32x4){0.f, 0.f, 0.f, 0.f};
    __builtin_amdgcn_s_setprio(1);
#pragma unroll
    for (int nf = 0; nf < 2; ++nf)
#pragma unroll
      for (int f = 0; f < 3; ++f) {
        short8 kfrag = *(const short8*)&KV3[b1 + (f * 4 + g) * 256 + (nf * 16 + lrow) * 8];
        stB[nf] = __builtin_amdgcn_mfma_f32_16x16x32_bf16(kfrag, qf[f], stB[nf], 0, 0, 0);
      }
    __builtin_amdgcn_s_setprio(0);

    // softmax(kt): defer-max (exp2 domain), lane-local partial l
    float pmax = fmaxf(fmaxf(fmaxf(stA[0][0], stA[0][1]), fmaxf(stA[0][2], stA[0][3])),
                       fmaxf(fmaxf(stA[1][0], stA[1][1]), fmaxf(stA[1][2], stA[1][3])));
    if (!__all(pmax - m_r <= 11.54f)) {
      float rm = pmax;
      rm = fmaxf(rm, __shfl_xor(rm, 16, 64));
      rm = fmaxf(rm, __shfl_xor(rm, 32, 64));
      float mn = fmaxf(m_r, rm);
      float alpha = exp2a(m_r - mn);
      l_r *= alpha;
#pragma unroll
      for (int nf = 0; nf < 5; ++nf)
#pragma unroll
        for (int r = 0; r < 4; ++r) oa[nf][r] *= alpha;
      m_r = mn;
    }
#pragma unroll
    for (int nf = 0; nf < 2; ++nf)
#pragma unroll
      for (int r = 0; r < 4; ++r) stA[nf][r] = exp2a(stA[nf][r] - m_r);
    l_r += (stA[0][0] + stA[0][1]) + (stA[0][2] + stA[0][3]) +
           (stA[1][0] + stA[1][1]) + (stA[1][2] + stA[1][3]);

    // P write: kv = nf*16+g*4+r, q=lrow -> elem = (2nf+(g>>1))*128 + lrow*8 + (g&1)*4
#pragma unroll
    for (int nf = 0; nf < 2; ++nf) {
      uint2* dst = (uint2*)&Pl[w][(2 * nf + (g >> 1)) * 128 + lrow * 8 + (g & 1) * 4];
      *dst = make_uint2(cvt_pk2(stA[nf][0], stA[nf][1]), cvt_pk2(stA[nf][2], stA[nf][3]));
    }

    // PV(kt) from b0: O^T += V' x P'
    {
      short8 pa = *(const short8*)&Pl[w][g * 128 + lrow * 8];
      __builtin_amdgcn_s_setprio(1);
#pragma unroll
      for (int nf = 0; nf < 5; ++nf) {
        short8 bv = *(const short8*)&KV3[b0 + 3072 + g * 768 + (nf * 16 + lrow) * 8];
        oa[nf] = __builtin_amdgcn_mfma_f32_16x16x32_bf16(bv, pa, oa[nf], 0, 0, 0);
      }
      __builtin_amdgcn_s_setprio(0);
    }

    asm volatile("s_waitcnt lgkmcnt(0)" ::: "memory");
    __builtin_amdgcn_s_barrier();
    int s = kt + 3;
    if (s >= NT) s -= NT;
    STAGE(s, b0);
    stA[0] = stB[0];
    stA[1] = stB[1];
    b0 = b1;
  }

  // epilogue tile NT-1
  {
    float pmax = fmaxf(fmaxf(fmaxf(stA[0][0], stA[0][1]), fmaxf(stA[0][2], stA[0][3])),
                       fmaxf(fmaxf(stA[1][0], stA[1][1]), fmaxf(stA[1][2], stA[1][3])));
    if (!__all(pmax - m_r <= 11.54f)) {
      float rm = pmax;
      rm = fmaxf(rm, __shfl_xor(rm, 16, 64));
      rm = fmaxf(rm, __shfl_xor(rm, 32, 64));
      float mn = fmaxf(m_r, rm);
      float alpha = exp2a(m_r - mn);
      l_r *= alpha;
#pragma unroll
      for (int nf = 0; nf < 5; ++nf)
#pragma unroll
        for (int r = 0; r < 4; ++r) oa[nf][r] *= alpha;
      m_r = mn;
    }
#pragma unroll
    for (int nf = 0; nf < 2; ++nf)
#pragma unroll
      for (int r = 0; r < 4; ++r) stA[nf][r] = exp2a(stA[nf][r] - m_r);
    l_r += (stA[0][0] + stA[0][1]) + (stA[0][2] + stA[0][3]) +
           (stA[1][0] + stA[1][1]) + (stA[1][2] + stA[1][3]);
#pragma unroll
    for (int nf = 0; nf < 2; ++nf) {
      uint2* dst = (uint2*)&Pl[w][(2 * nf + (g >> 1)) * 128 + lrow * 8 + (g & 1) * 4];
      *dst = make_uint2(cvt_pk2(stA[nf][0], stA[nf][1]), cvt_pk2(stA[nf][2], stA[nf][3]));
    }
    short8 pa = *(const short8*)&Pl[w][g * 128 + lrow * 8];
#pragma unroll
    for (int nf = 0; nf < 5; ++nf) {
      short8 bv = *(const short8*)&KV3[b0 + 3072 + g * 768 + (nf * 16 + lrow) * 8];
      oa[nf] = __builtin_amdgcn_mfma_f32_16x16x32_bf16(bv, pa, oa[nf], 0, 0, 0);
    }
  }

  // row-reduce the partial l (deferred from the loop), then store
  float lt = l_r;
  lt += __shfl_xor(lt, 16, 64);
  lt += __shfl_xor(lt, 32, 64);
  float rcp = 1.f / lt;
  size_t obase = (size_t)(q0 + lrow) * HID + h * HD;
#pragma unroll
  for (int nf = 0; nf < 5; ++nf) {
    int d = nf * 16 + g * 4;
    if (d + 3 < HD) {
      uint2 pk = make_uint2(cvt_pk2(oa[nf][0] * rcp, oa[nf][1] * rcp),
                            cvt_pk2(oa[nf][2] * rcp, oa[nf][3] * rcp));
      *(uint2*)&o[obase + d] = pk;
    }
  }
}

// ---------------- launch ----------------
extern "C" void kernel_launch(void* const* d_in, const int* in_sizes, int n_in,
                              void* d_out, int out_size, void* d_ws, size_t ws_size,
                              hipStream_t stream) {
  (void)in_sizes; (void)n_in; (void)out_size;
  const float* hidden = (const float*)d_in[0];
  const float* cosb = (const float*)d_in[1];
  const float* sinb = (const float*)d_in[2];
  const float* ln0g = (const float*)d_in[3];
  const float* ln0b = (const float*)d_in[4];
  const float* ln1g = (const float*)d_in[5];
  const float* ln1b = (const float*)d_in[6];
  const float* wqkv = (const float*)d_in[7];
  const float* bqkv = (const float*)d_in[8];
  const float* wo = (const float*)d_in[9];
  const float* bo = (const float*)d_in[10];
  const float* w0 = (const float*)d_in[11];
  const float* b0 = (const float*)d_in[12];
  const float* w1 = (const float*)d_in[13];
  const float* b1 = (const float*)d_in[14];

  char* p = (char*)d_ws;
  auto alloc = [&](size_t n) {
    char* r = p;
    p += (n + 255) & ~(size_t)255;
    return r;
  };
  bf16* wqkv_bf = (bf16*)alloc((size_t)3 * HID * HID * 2);
  bf16* wo_bf = (bf16*)alloc((size_t)HID * HID * 2);
  bf16* fc0_bf = (bf16*)alloc((size_t)MLPP * HID * 2);
  bf16* fc1_bf = (bf16*)alloc((size_t)HID * MLPP * 2);
  bf16* ln0_bf = (bf16*)alloc((size_t)SEQ * HID * 2);
  float* xqkv = (float*)alloc((size_t)SEQ * 3 * HID * 4);
  bf16* qp = (bf16*)alloc((size_t)NHEAD * SEQ * HDP * 2);
  bf16* kp = (bf16*)alloc((size_t)NHEAD * SEQ * HDP * 2);
  bf16* vt = (bf16*)alloc((size_t)NHEAD * HDP * SEQ * 2);
  bf16* attn_bf = (bf16*)alloc((size_t)SEQ * HID * 2);
  float* h1 = (float*)alloc((size_t)SEQ * HID * 4);
  bf16* ln1_bf = (bf16*)alloc((size_t)SEQ * HID * 2);
  bf16* gelu_bf = (bf16*)alloc((size_t)SEQ * MLPP * 2);
  if ((size_t)(p - (char*)d_ws) > ws_size) return;

  dim3 blk(256);
  cast_bf16_k<<<2048, blk, 0, stream>>>(wqkv, (unsigned*)wqkv_bf, 3 * HID * HID / 4);
  cast_bf16_k<<<1024, blk, 0, stream>>>(wo, (unsigned*)wo_bf, HID * HID / 4);
  cast_pad_rows_k<<<2048, blk, 0, stream>>>(w0, (unsigned*)fc0_bf, MLPD, HID / 4, MLPP * HID / 4);
  cast_pad_cols_k<<<2048, blk, 0, stream>>>(w1, (unsigned*)fc1_bf, MLPD / 4, MLPP / 4, HID * MLPP / 4);
  ln_k<<<SEQ, blk, 0, stream>>>(hidden, ln0g, ln0b, ln0_bf);
  gemm_bf16<0><<<dim3((3 * HID / 128) * (SEQ / 128)), blk, 0, stream>>>(
      ln0_bf, wqkv_bf, bqkv, 3 * HID, nullptr, xqkv, nullptr, SEQ, 3 * HID, HID);
  rope_split<<<dim3(SEQ / 64, NHEAD), blk, 0, stream>>>(xqkv, cosb, sinb, qp, kp, vt);
  flash_attn<<<dim3(768), blk, 0, stream>>>(qp, kp, vt, attn_bf);
  gemm_bf16<1><<<dim3((HID / 128) * (SEQ / 128)), blk, 0, stream>>>(
      attn_bf, wo_bf, bo, HID, hidden, h1, nullptr, SEQ, HID, HID);
  ln_k<<<SEQ, blk, 0, stream>>>(h1, ln1g, ln1b, ln1_bf);
  gemm_bf16<2><<<dim3((MLPP / 128) * (SEQ / 128)), blk, 0, stream>>>(
      ln1_bf, fc0_bf, b0, MLPD, nullptr, nullptr, gelu_bf, SEQ, MLPP, HID);
  gemm_bf16<1><<<dim3((HID / 128) * (SEQ / 128)), blk, 0, stream>>>(
      gelu_bf, fc1_bf, b1, HID, h1, (float*)d_out, nullptr, SEQ, HID, MLPP);
}

// Round 12
// 375.305 us; speedup vs baseline: 1.1310x; 1.0075x over previous
//
#include <hip/hip_runtime.h>
#include <hip/hip_bf16.h>
#include <math.h>

typedef __hip_bfloat16 bf16;
typedef __attribute__((ext_vector_type(8))) short short8;
typedef __attribute__((ext_vector_type(4))) short short4v;
typedef __attribute__((ext_vector_type(4))) float f32x4;

#define SEQ 3072
#define HID 1152
#define NHEAD 16
#define HD 72
#define HDP 96
#define MLPD 4304
#define MLPP 4352

__device__ __forceinline__ void async_lds16(void* lds, const void* g) {
  __builtin_amdgcn_global_load_lds((const __attribute__((address_space(1))) void*)g,
                                   (__attribute__((address_space(3))) void*)lds,
                                   16, 0, 0);
}

// one v_cvt_pk_bf16_f32: a -> low16, b -> high16 (RNE)
__device__ __forceinline__ unsigned cvt_pk2(float a, float b) {
  unsigned r;
  asm("v_cvt_pk_bf16_f32 %0, %1, %2" : "=v"(r) : "v"(a), "v"(b));
  return r;
}

// raw v_exp_f32: 2^x
__device__ __forceinline__ float exp2a(float x) {
  float r;
  asm("v_exp_f32 %0, %1" : "=v"(r) : "v"(x));
  return r;
}

// ---------------- weight cast kernels ----------------
__global__ __launch_bounds__(256) void cast_bf16_k(const float* __restrict__ in,
                                                   unsigned* __restrict__ out2, int n4) {
  int stride = gridDim.x * blockDim.x;
  for (int i = blockIdx.x * blockDim.x + threadIdx.x; i < n4; i += stride) {
    float4 u = ((const float4*)in)[i];
    uint2 w = make_uint2(cvt_pk2(u.x, u.y), cvt_pk2(u.z, u.w));
    ((uint2*)out2)[i] = w;
  }
}

__global__ __launch_bounds__(256) void cast_pad_rows_k(const float* __restrict__ in,
                                                       unsigned* __restrict__ out2,
                                                       int R, int C4, int n4) {
  int stride = gridDim.x * blockDim.x;
  for (int i = blockIdx.x * blockDim.x + threadIdx.x; i < n4; i += stride) {
    int r = i / C4;
    uint2 w = make_uint2(0u, 0u);
    if (r < R) {
      float4 u = ((const float4*)in)[i];
      w = make_uint2(cvt_pk2(u.x, u.y), cvt_pk2(u.z, u.w));
    }
    ((uint2*)out2)[i] = w;
  }
}

__global__ __launch_bounds__(256) void cast_pad_cols_k(const float* __restrict__ in,
                                                       unsigned* __restrict__ out2,
                                                       int C4, int Cp4, int n4) {
  int stride = gridDim.x * blockDim.x;
  for (int i = blockIdx.x * blockDim.x + threadIdx.x; i < n4; i += stride) {
    int r = i / Cp4, c4 = i - r * Cp4;
    uint2 w = make_uint2(0u, 0u);
    if (c4 < C4) {
      float4 u = ((const float4*)in)[r * C4 + c4];
      w = make_uint2(cvt_pk2(u.x, u.y), cvt_pk2(u.z, u.w));
    }
    ((uint2*)out2)[i] = w;
  }
}

// ---------------- layernorm (fp32 in -> bf16 out) ----------------
__global__ __launch_bounds__(256) void ln_k(const float* __restrict__ x,
                                            const float* __restrict__ g,
                                            const float* __restrict__ b,
                                            bf16* __restrict__ o) {
  int row = blockIdx.x;
  const float4* xr = (const float4*)(x + (size_t)row * HID);
  float sum = 0.f, sq = 0.f;
  for (int c = threadIdx.x; c < HID / 4; c += 256) {
    float4 u = xr[c];
    sum += u.x + u.y + u.z + u.w;
    sq += u.x * u.x + u.y * u.y + u.z * u.z + u.w * u.w;
  }
#pragma unroll
  for (int off = 32; off > 0; off >>= 1) {
    sum += __shfl_down(sum, off, 64);
    sq += __shfl_down(sq, off, 64);
  }
  __shared__ float red[8];
  int wv = threadIdx.x >> 6;
  if ((threadIdx.x & 63) == 0) { red[wv] = sum; red[4 + wv] = sq; }
  __syncthreads();
  if (threadIdx.x == 0) {
    red[0] = red[0] + red[1] + red[2] + red[3];
    red[4] = red[4] + red[5] + red[6] + red[7];
  }
  __syncthreads();
  float mu = red[0] * (1.f / HID);
  float var = red[4] * (1.f / HID) - mu * mu;
  float inv = rsqrtf(var + 1e-5f);
  uint2* o4 = (uint2*)(o + (size_t)row * HID);
  const float4* g4 = (const float4*)g;
  const float4* b4 = (const float4*)b;
  for (int c = threadIdx.x; c < HID / 4; c += 256) {
    float4 u = xr[c], gg = g4[c], bb = b4[c];
    uint2 w = make_uint2(cvt_pk2((u.x - mu) * inv * gg.x + bb.x, (u.y - mu) * inv * gg.y + bb.y),
                         cvt_pk2((u.z - mu) * inv * gg.z + bb.z, (u.w - mu) * inv * gg.w + bb.w));
    o4[c] = w;
  }
}

// ---------------- GEMM: C[M][N] = A[M][K] @ Bt[N][K]^T  (+ epilogue) ----------------
// 3 LDS buffers (48KB -> 3 blocks/CU), depth-2 prefetch, counted vmcnt,
// bijective XCD swizzle (x-major per XCD -> B-panel L2-resident).
// LDS chunk XOR-swizzle (rule #21: linear dst + inverse-swz SOURCE + swz READ):
//   row r's 4 16B-chunks are stored permuted by xs(r) = (r>>1)&3, turning the
//   4-way ds_read_b128 bank conflict into conflict-free (8 distinct quads/8 lanes).
// EPI 0: +bias -> fp32   1: +bias+res -> fp32   2: +bias, gelu -> bf16
template <int EPI>
__global__ __launch_bounds__(256) void gemm_bf16(const bf16* __restrict__ A,
                                                 const bf16* __restrict__ Bt,
                                                 const float* __restrict__ bias, int nbias,
                                                 const float* __restrict__ res,
                                                 float* __restrict__ outf,
                                                 bf16* __restrict__ outb,
                                                 int M, int N, int K) {
  __shared__ bf16 As[3][128 * 32];
  __shared__ bf16 Bs[3][128 * 32];
  const int t = threadIdx.x;
  const int l = t & 63;
  const int w = t >> 6;
  const int wr = w >> 1, wc = w & 1;
  const int lrow = l & 15;
  // swizzled read chunk: g ^ xs, xs = (lrow>>1)&3  (row>>1 &3 == lrow>>1 &3 for our rows)
  const int lks = (((l >> 4) ^ ((lrow >> 1) & 3)) & 3) * 8;
  const int wg = (blockIdx.x & 7) * (gridDim.x >> 3) + (blockIdx.x >> 3);
  const int gyt = M >> 7;
  const int xt = wg / gyt;
  const int yt = wg - xt * gyt;
  const int m0 = yt * 128;
  const int n0 = xt * 128;
  const int arow = t >> 2;
  // swizzled source chunk: (t&3) ^ xs(arow), xs(arow) = (arow>>1)&3 = (t>>3)&3
  // (rows arow and arow+64 share the same xs since 64>>1 = 32 ≡ 0 mod 4)
  const int ach = (((t & 3) ^ ((t >> 3) & 3)) & 3) * 8;

  const bf16* pa0 = &A[(size_t)(m0 + arow) * K + ach];
  const bf16* pa1 = &A[(size_t)(m0 + arow + 64) * K + ach];
  const bf16* pb0 = &Bt[(size_t)(n0 + arow) * K + ach];
  const bf16* pb1 = &Bt[(size_t)(n0 + arow + 64) * K + ach];
  auto STAGE = [&](int buf, int kt) {
    size_t off = (size_t)kt * 32;
    async_lds16(&As[buf][t * 8], pa0 + off);
    async_lds16(&As[buf][(256 + t) * 8], pa1 + off);
    async_lds16(&Bs[buf][t * 8], pb0 + off);
    async_lds16(&Bs[buf][(256 + t) * 8], pb1 + off);
  };

  f32x4 acc[4][4] = {};
  const int nkt = K >> 5;
  STAGE(0, 0);
  STAGE(1, 1);
  int bcur = 0;
  for (int kt = 0; kt < nkt; ++kt) {
    if (kt + 1 < nkt) {
      asm volatile("s_waitcnt vmcnt(4)" ::: "memory");  // stage kt landed; kt+1 in flight
    } else {
      asm volatile("s_waitcnt vmcnt(0)" ::: "memory");
    }
    __builtin_amdgcn_s_barrier();
    int bn2 = bcur + 2;
    if (bn2 >= 3) bn2 -= 3;
    if (kt + 2 < nkt) STAGE(bn2, kt + 2);

    short8 af[4], bfr[4];
#pragma unroll
    for (int i = 0; i < 4; ++i)
      af[i] = *(const short8*)&As[bcur][(wr * 64 + i * 16 + lrow) * 32 + lks];
#pragma unroll
    for (int i = 0; i < 4; ++i)
      bfr[i] = *(const short8*)&Bs[bcur][(wc * 64 + i * 16 + lrow) * 32 + lks];
    __builtin_amdgcn_s_setprio(1);
#pragma unroll
    for (int i = 0; i < 4; ++i)
#pragma unroll
      for (int j = 0; j < 4; ++j)
        acc[i][j] = __builtin_amdgcn_mfma_f32_16x16x32_bf16(af[i], bfr[j], acc[i][j], 0, 0, 0);
    __builtin_amdgcn_s_setprio(0);
    ++bcur;
    if (bcur == 3) bcur = 0;
  }

#pragma unroll
  for (int i = 0; i < 4; ++i) {
    int rowb = m0 + wr * 64 + i * 16 + (l >> 4) * 4;
#pragma unroll
    for (int j = 0; j < 4; ++j) {
      int col = n0 + wc * 64 + j * 16 + lrow;
      float bv = (col < nbias) ? bias[col] : 0.f;
#pragma unroll
      for (int r2 = 0; r2 < 4; ++r2) {
        size_t idx = (size_t)(rowb + r2) * N + col;
        float v = acc[i][j][r2] + bv;
        if (EPI == 0) {
          outf[idx] = v;
        } else if (EPI == 1) {
          outf[idx] = v + res[idx];
        } else {
          float u = 0.7978845608028654f * (v + 0.044715f * v * v * v);
          u = fminf(fmaxf(u, -15.f), 15.f);
          float tt = __expf(2.f * u);
          outb[idx] = __float2bfloat16(v * tt / (tt + 1.f));
        }
      }
    }
  }
}

// ---------------- rope + qkv split ----------------
// q scale folds log2(e) so flash softmax runs in exp2 domain.
__global__ __launch_bounds__(256) void rope_split(const float* __restrict__ xqkv,
                                                  const float* __restrict__ cosb,
                                                  const float* __restrict__ sinb,
                                                  bf16* __restrict__ qp,
                                                  bf16* __restrict__ kp,
                                                  bf16* __restrict__ vt) {
  __shared__ bf16 vl[64][72];
  const int t = threadIdx.x;
  const int h = blockIdx.y;
  const int s0 = blockIdx.x * 64;
  const float scale = 0.17002445f;  // (1/sqrt(72)) * log2(e)
  for (int idx = t; idx < 64 * 48; idx += 256) {
    int sl = idx / 48, pi = idx - sl * 48;
    int srow = s0 + sl;
    size_t obase = ((size_t)h * SEQ + srow) * HDP + 2 * pi;
    if (pi < 36) {
      const float* xr = xqkv + (size_t)srow * (3 * HID) + h * HD + 2 * pi;
      float qr = xr[0], qi = xr[1];
      float kr = xr[HID], ki = xr[HID + 1];
      float c = cosb[srow * 36 + pi], sn = sinb[srow * 36 + pi];
      *(unsigned*)&qp[obase] = cvt_pk2((qr * c - qi * sn) * scale, (qr * sn + qi * c) * scale);
      *(unsigned*)&kp[obase] = cvt_pk2(kr * c - ki * sn, kr * sn + ki * c);
    } else {
      *(unsigned*)&qp[obase] = 0u;
      *(unsigned*)&kp[obase] = 0u;
    }
  }
  for (int idx = t; idx < 64 * 72; idx += 256) {
    int sl = idx / 72, d = idx - sl * 72;
    vl[sl][d] = __float2bfloat16(xqkv[(size_t)(s0 + sl) * (3 * HID) + 2 * HID + h * HD + d]);
  }
  __syncthreads();
  bf16 z = __float2bfloat16(0.f);
  for (int idx = t; idx < HDP * 64; idx += 256) {
    int d = idx / 64, sl = idx - d * 64;
    vt[((size_t)h * HDP + d) * SEQ + s0 + sl] = (d < 72) ? vl[sl][d] : z;
  }
}

// ---------------- flash attention (best-known config: KVBLK=32, 4 waves, 40KB) ----------------
// Triple-buffered KV, QK(t+1)-ahead, swapped operands (lane-local softmax),
// exp2-domain (log2e folded into q scale), defer-max THR=8*log2(e)=11.54,
// lane-local partial l (row-reduced once in epilogue). Grid 768 = 3 blocks/CU.
__global__ __launch_bounds__(256) void flash_attn(const bf16* __restrict__ q,
                                                  const bf16* __restrict__ kk,
                                                  const bf16* __restrict__ vT,
                                                  bf16* __restrict__ o) {
  __shared__ alignas(16) bf16 KV3[3 * 6144];
  __shared__ alignas(16) bf16 Pl[4][512];
  const int t = threadIdx.x;
  const int l = t & 63;
  const int w = t >> 6;
  const int g = l >> 4;
  const int lrow = l & 15;
  const int bid = blockIdx.x;
  const int kq = bid >> 3;
  const int h = (bid & 7) * 2 + (kq & 1);
  const int q0 = (kq >> 1) * 64 + w * 16;
  const int NT = SEQ / 32;

  const bf16* sbase[3];
  int smul[3];
#pragma unroll
  for (int i = 0; i < 3; ++i) {
    int s = t + i * 256;
    if (s < 384) {
      int cb = s >> 5, kv = s & 31;
      sbase[i] = kk + ((size_t)h * SEQ + kv) * HDP + cb * 8;
      smul[i] = 32 * HDP;
    } else {
      int vs = s - 384;
      int cb = vs / 96, d = vs - cb * 96;
      sbase[i] = vT + ((size_t)h * HDP + d) * SEQ + cb * 8;
      smul[i] = 32;
    }
  }
  auto STAGE = [&](int tile, int bufOff) {
#pragma unroll
    for (int i = 0; i < 3; ++i)
      async_lds16(&KV3[bufOff + (t + i * 256) * 8], sbase[i] + (size_t)tile * smul[i]);
  };

  short8 qf[3];
#pragma unroll
  for (int f = 0; f < 3; ++f)
    qf[f] = *(const short8*)&q[((size_t)h * SEQ + q0 + lrow) * HDP + f * 32 + g * 8];

  float m_r = -1e30f, l_r = 0.f;
  f32x4 oa[5] = {};

  STAGE(0, 0);
  STAGE(1, 6144);
  STAGE(2, 12288);
  asm volatile("s_waitcnt vmcnt(6)" ::: "memory");
  __builtin_amdgcn_s_barrier();

  f32x4 stA[2] = {}, stB[2];
  int b0 = 0;
#pragma unroll
  for (int nf = 0; nf < 2; ++nf)
#pragma unroll
    for (int f = 0; f < 3; ++f) {
      short8 kfrag = *(const short8*)&KV3[0 + (f * 4 + g) * 256 + (nf * 16 + lrow) * 8];
      stA[nf] = __builtin_amdgcn_mfma_f32_16x16x32_bf16(kfrag, qf[f], stA[nf], 0, 0, 0);
    }

  for (int kt = 0; kt < NT - 1; ++kt) {
    int b1 = b0 + 6144;
    if (b1 == 18432) b1 = 0;
    asm volatile("s_waitcnt vmcnt(3)" ::: "memory");
    __builtin_amdgcn_s_barrier();

    // QK(kt+1) from b1 (independent of softmax(kt) below)
    stB[0] = (f32x4){0.f, 0.f, 0.f, 0.f};
    stB[1] = (f32x4){0.f, 0.f, 0.f, 0.f};
    __builtin_amdgcn_s_setprio(1);
#pragma unroll
    for (int nf = 0; nf < 2; ++nf)
#pragma unroll
      for (int f = 0; f < 3; ++f) {
        short8 kfrag = *(const short8*)&KV3[b1 + (f * 4 + g) * 256 + (nf * 16 + lrow) * 8];
        stB[nf] = __builtin_amdgcn_mfma_f32_16x16x32_bf16(kfrag, qf[f], stB[nf], 0, 0, 0);
      }
    __builtin_amdgcn_s_setprio(0);

    // softmax(kt): defer-max (exp2 domain), lane-local partial l
    float pmax = fmaxf(fmaxf(fmaxf(stA[0][0], stA[0][1]), fmaxf(stA[0][2], stA[0][3])),
                       fmaxf(fmaxf(stA[1][0], stA[1][1]), fmaxf(stA[1][2], stA[1][3])));
    if (!__all(pmax - m_r <= 11.54f)) {
      float rm = pmax;
      rm = fmaxf(rm, __shfl_xor(rm, 16, 64));
      rm = fmaxf(rm, __shfl_xor(rm, 32, 64));
      float mn = fmaxf(m_r, rm);
      float alpha = exp2a(m_r - mn);
      l_r *= alpha;
#pragma unroll
      for (int nf = 0; nf < 5; ++nf)
#pragma unroll
        for (int r = 0; r < 4; ++r) oa[nf][r] *= alpha;
      m_r = mn;
    }
#pragma unroll
    for (int nf = 0; nf < 2; ++nf)
#pragma unroll
      for (int r = 0; r < 4; ++r) stA[nf][r] = exp2a(stA[nf][r] - m_r);
    l_r += (stA[0][0] + stA[0][1]) + (stA[0][2] + stA[0][3]) +
           (stA[1][0] + stA[1][1]) + (stA[1][2] + stA[1][3]);

    // P write: kv = nf*16+g*4+r, q=lrow -> elem = (2nf+(g>>1))*128 + lrow*8 + (g&1)*4
#pragma unroll
    for (int nf = 0; nf < 2; ++nf) {
      uint2* dst = (uint2*)&Pl[w][(2 * nf + (g >> 1)) * 128 + lrow * 8 + (g & 1) * 4];
      *dst = make_uint2(cvt_pk2(stA[nf][0], stA[nf][1]), cvt_pk2(stA[nf][2], stA[nf][3]));
    }

    // PV(kt) from b0: O^T += V' x P'
    {
      short8 pa = *(const short8*)&Pl[w][g * 128 + lrow * 8];
      __builtin_amdgcn_s_setprio(1);
#pragma unroll
      for (int nf = 0; nf < 5; ++nf) {
        short8 bv = *(const short8*)&KV3[b0 + 3072 + g * 768 + (nf * 16 + lrow) * 8];
        oa[nf] = __builtin_amdgcn_mfma_f32_16x16x32_bf16(bv, pa, oa[nf], 0, 0, 0);
      }
      __builtin_amdgcn_s_setprio(0);
    }

    asm volatile("s_waitcnt lgkmcnt(0)" ::: "memory");
    __builtin_amdgcn_s_barrier();
    int s = kt + 3;
    if (s >= NT) s -= NT;
    STAGE(s, b0);
    stA[0] = stB[0];
    stA[1] = stB[1];
    b0 = b1;
  }

  // epilogue tile NT-1
  {
    float pmax = fmaxf(fmaxf(fmaxf(stA[0][0], stA[0][1]), fmaxf(stA[0][2], stA[0][3])),
                       fmaxf(fmaxf(stA[1][0], stA[1][1]), fmaxf(stA[1][2], stA[1][3])));
    if (!__all(pmax - m_r <= 11.54f)) {
      float rm = pmax;
      rm = fmaxf(rm, __shfl_xor(rm, 16, 64));
      rm = fmaxf(rm, __shfl_xor(rm, 32, 64));
      float mn = fmaxf(m_r, rm);
      float alpha = exp2a(m_r - mn);
      l_r *= alpha;
#pragma unroll
      for (int nf = 0; nf < 5; ++nf)
#pragma unroll
        for (int r = 0; r < 4; ++r) oa[nf][r] *= alpha;
      m_r = mn;
    }
#pragma unroll
    for (int nf = 0; nf < 2; ++nf)
#pragma unroll
      for (int r = 0; r < 4; ++r) stA[nf][r] = exp2a(stA[nf][r] - m_r);
    l_r += (stA[0][0] + stA[0][1]) + (stA[0][2] + stA[0][3]) +
           (stA[1][0] + stA[1][1]) + (stA[1][2] + stA[1][3]);
#pragma unroll
    for (int nf = 0; nf < 2; ++nf) {
      uint2* dst = (uint2*)&Pl[w][(2 * nf + (g >> 1)) * 128 + lrow * 8 + (g & 1) * 4];
      *dst = make_uint2(cvt_pk2(stA[nf][0], stA[nf][1]), cvt_pk2(stA[nf][2], stA[nf][3]));
    }
    short8 pa = *(const short8*)&Pl[w][g * 128 + lrow * 8];
#pragma unroll
    for (int nf = 0; nf < 5; ++nf) {
      short8 bv = *(const short8*)&KV3[b0 + 3072 + g * 768 + (nf * 16 + lrow) * 8];
      oa[nf] = __builtin_amdgcn_mfma_f32_16x16x32_bf16(bv, pa, oa[nf], 0, 0, 0);
    }
  }

  // row-reduce the partial l (deferred from the loop), then store
  float lt = l_r;
  lt += __shfl_xor(lt, 16, 64);
  lt += __shfl_xor(lt, 32, 64);
  float rcp = 1.f / lt;
  size_t obase = (size_t)(q0 + lrow) * HID + h * HD;
#pragma unroll
  for (int nf = 0; nf < 5; ++nf) {
    int d = nf * 16 + g * 4;
    if (d + 3 < HD) {
      uint2 pk = make_uint2(cvt_pk2(oa[nf][0] * rcp, oa[nf][1] * rcp),
                            cvt_pk2(oa[nf][2] * rcp, oa[nf][3] * rcp));
      *(uint2*)&o[obase + d] = pk;
    }
  }
}

// ---------------- launch ----------------
extern "C" void kernel_launch(void* const* d_in, const int* in_sizes, int n_in,
                              void* d_out, int out_size, void* d_ws, size_t ws_size,
                              hipStream_t stream) {
  (void)in_sizes; (void)n_in; (void)out_size;
  const float* hidden = (const float*)d_in[0];
  const float* cosb = (const float*)d_in[1];
  const float* sinb = (const float*)d_in[2];
  const float* ln0g = (const float*)d_in[3];
  const float* ln0b = (const float*)d_in[4];
  const float* ln1g = (const float*)d_in[5];
  const float* ln1b = (const float*)d_in[6];
  const float* wqkv = (const float*)d_in[7];
  const float* bqkv = (const float*)d_in[8];
  const float* wo = (const float*)d_in[9];
  const float* bo = (const float*)d_in[10];
  const float* w0 = (const float*)d_in[11];
  const float* b0 = (const float*)d_in[12];
  const float* w1 = (const float*)d_in[13];
  const float* b1 = (const float*)d_in[14];

  char* p = (char*)d_ws;
  auto alloc = [&](size_t n) {
    char* r = p;
    p += (n + 255) & ~(size_t)255;
    return r;
  };
  bf16* wqkv_bf = (bf16*)alloc((size_t)3 * HID * HID * 2);
  bf16* wo_bf = (bf16*)alloc((size_t)HID * HID * 2);
  bf16* fc0_bf = (bf16*)alloc((size_t)MLPP * HID * 2);
  bf16* fc1_bf = (bf16*)alloc((size_t)HID * MLPP * 2);
  bf16* ln0_bf = (bf16*)alloc((size_t)SEQ * HID * 2);
  float* xqkv = (float*)alloc((size_t)SEQ * 3 * HID * 4);
  bf16* qp = (bf16*)alloc((size_t)NHEAD * SEQ * HDP * 2);
  bf16* kp = (bf16*)alloc((size_t)NHEAD * SEQ * HDP * 2);
  bf16* vt = (bf16*)alloc((size_t)NHEAD * HDP * SEQ * 2);
  bf16* attn_bf = (bf16*)alloc((size_t)SEQ * HID * 2);
  float* h1 = (float*)alloc((size_t)SEQ * HID * 4);
  bf16* ln1_bf = (bf16*)alloc((size_t)SEQ * HID * 2);
  bf16* gelu_bf = (bf16*)alloc((size_t)SEQ * MLPP * 2);
  if ((size_t)(p - (char*)d_ws) > ws_size) return;

  dim3 blk(256);
  cast_bf16_k<<<2048, blk, 0, stream>>>(wqkv, (unsigned*)wqkv_bf, 3 * HID * HID / 4);
  cast_bf16_k<<<1024, blk, 0, stream>>>(wo, (unsigned*)wo_bf, HID * HID / 4);
  cast_pad_rows_k<<<2048, blk, 0, stream>>>(w0, (unsigned*)fc0_bf, MLPD, HID / 4, MLPP * HID / 4);
  cast_pad_cols_k<<<2048, blk, 0, stream>>>(w1, (unsigned*)fc1_bf, MLPD / 4, MLPP / 4, HID * MLPP / 4);
  ln_k<<<SEQ, blk, 0, stream>>>(hidden, ln0g, ln0b, ln0_bf);
  gemm_bf16<0><<<dim3((3 * HID / 128) * (SEQ / 128)), blk, 0, stream>>>(
      ln0_bf, wqkv_bf, bqkv, 3 * HID, nullptr, xqkv, nullptr, SEQ, 3 * HID, HID);
  rope_split<<<dim3(SEQ / 64, NHEAD), blk, 0, stream>>>(xqkv, cosb, sinb, qp, kp, vt);
  flash_attn<<<dim3(768), blk, 0, stream>>>(qp, kp, vt, attn_bf);
  gemm_bf16<1><<<dim3((HID / 128) * (SEQ / 128)), blk, 0, stream>>>(
      attn_bf, wo_bf, bo, HID, hidden, h1, nullptr, SEQ, HID, HID);
  ln_k<<<SEQ, blk, 0, stream>>>(h1, ln1g, ln1b, ln1_bf);
  gemm_bf16<2><<<dim3((MLPP / 128) * (SEQ / 128)), blk, 0, stream>>>(
      ln1_bf, fc0_bf, b0, MLPD, nullptr, nullptr, gelu_bf, SEQ, MLPP, HID);
  gemm_bf16<1><<<dim3((HID / 128) * (SEQ / 128)), blk, 0, stream>>>(
      gelu_bf, fc1_bf, b1, HID, h1, (float*)d_out, nullptr, SEQ, HID, MLPP);
}

// Round 14
// 351.509 us; speedup vs baseline: 1.2075x; 1.0677x over previous
//
#include <hip/hip_runtime.h>
#include <hip/hip_bf16.h>
#include <math.h>

typedef __hip_bfloat16 bf16;
typedef __attribute__((ext_vector_type(8))) short short8;
typedef __attribute__((ext_vector_type(4))) short short4v;
typedef __attribute__((ext_vector_type(4))) float f32x4;

#define SEQ 3072
#define HID 1152
#define NHEAD 16
#define HD 72
#define HDP 96
#define MLPD 4304
#define MLPP 4352

__device__ __forceinline__ void async_lds16(void* lds, const void* g) {
  __builtin_amdgcn_global_load_lds((const __attribute__((address_space(1))) void*)g,
                                   (__attribute__((address_space(3))) void*)lds,
                                   16, 0, 0);
}

// one v_cvt_pk_bf16_f32: a -> low16, b -> high16 (RNE)
__device__ __forceinline__ unsigned cvt_pk2(float a, float b) {
  unsigned r;
  asm("v_cvt_pk_bf16_f32 %0, %1, %2" : "=v"(r) : "v"(a), "v"(b));
  return r;
}

// raw v_exp_f32: 2^x
__device__ __forceinline__ float exp2a(float x) {
  float r;
  asm("v_exp_f32 %0, %1" : "=v"(r) : "v"(x));
  return r;
}

// ---------------- fused weight cast (all 4 weights, one dispatch) ----------------
__global__ __launch_bounds__(256) void cast_all_k(const float* __restrict__ wqkv,
                                                  const float* __restrict__ wo,
                                                  const float* __restrict__ w0,
                                                  const float* __restrict__ w1,
                                                  unsigned* __restrict__ wqkv_o,
                                                  unsigned* __restrict__ wo_o,
                                                  unsigned* __restrict__ fc0_o,
                                                  unsigned* __restrict__ fc1_o) {
  const int n0 = 3 * HID * HID / 4;   // wqkv (plain)
  const int n1 = HID * HID / 4;       // wo (plain)
  const int n2 = MLPP * HID / 4;      // fc0 (pad rows >= MLPD)
  const int n3 = HID * MLPP / 4;      // fc1 (pad cols >= MLPD/4 chunks)
  const int total = n0 + n1 + n2 + n3;
  int stride = gridDim.x * blockDim.x;
  for (int i = blockIdx.x * blockDim.x + threadIdx.x; i < total; i += stride) {
    if (i < n0) {
      float4 u = ((const float4*)wqkv)[i];
      ((uint2*)wqkv_o)[i] = make_uint2(cvt_pk2(u.x, u.y), cvt_pk2(u.z, u.w));
    } else if (i < n0 + n1) {
      int k = i - n0;
      float4 u = ((const float4*)wo)[k];
      ((uint2*)wo_o)[k] = make_uint2(cvt_pk2(u.x, u.y), cvt_pk2(u.z, u.w));
    } else if (i < n0 + n1 + n2) {
      int k = i - n0 - n1;
      int r = k / (HID / 4);
      uint2 w = make_uint2(0u, 0u);
      if (r < MLPD) {
        float4 u = ((const float4*)w0)[k];
        w = make_uint2(cvt_pk2(u.x, u.y), cvt_pk2(u.z, u.w));
      }
      ((uint2*)fc0_o)[k] = w;
    } else {
      int k = i - n0 - n1 - n2;
      int r = k / (MLPP / 4), c4 = k - r * (MLPP / 4);
      uint2 w = make_uint2(0u, 0u);
      if (c4 < MLPD / 4) {
        float4 u = ((const float4*)w1)[r * (MLPD / 4) + c4];
        w = make_uint2(cvt_pk2(u.x, u.y), cvt_pk2(u.z, u.w));
      }
      ((uint2*)fc1_o)[k] = w;
    }
  }
}

// ---------------- layernorm (fp32 in -> bf16 out) ----------------
__global__ __launch_bounds__(256) void ln_k(const float* __restrict__ x,
                                            const float* __restrict__ g,
                                            const float* __restrict__ b,
                                            bf16* __restrict__ o) {
  int row = blockIdx.x;
  const float4* xr = (const float4*)(x + (size_t)row * HID);
  float sum = 0.f, sq = 0.f;
  for (int c = threadIdx.x; c < HID / 4; c += 256) {
    float4 u = xr[c];
    sum += u.x + u.y + u.z + u.w;
    sq += u.x * u.x + u.y * u.y + u.z * u.z + u.w * u.w;
  }
#pragma unroll
  for (int off = 32; off > 0; off >>= 1) {
    sum += __shfl_down(sum, off, 64);
    sq += __shfl_down(sq, off, 64);
  }
  __shared__ float red[8];
  int wv = threadIdx.x >> 6;
  if ((threadIdx.x & 63) == 0) { red[wv] = sum; red[4 + wv] = sq; }
  __syncthreads();
  if (threadIdx.x == 0) {
    red[0] = red[0] + red[1] + red[2] + red[3];
    red[4] = red[4] + red[5] + red[6] + red[7];
  }
  __syncthreads();
  float mu = red[0] * (1.f / HID);
  float var = red[4] * (1.f / HID) - mu * mu;
  float inv = rsqrtf(var + 1e-5f);
  uint2* o4 = (uint2*)(o + (size_t)row * HID);
  const float4* g4 = (const float4*)g;
  const float4* b4 = (const float4*)b;
  for (int c = threadIdx.x; c < HID / 4; c += 256) {
    float4 u = xr[c], gg = g4[c], bb = b4[c];
    uint2 w = make_uint2(cvt_pk2((u.x - mu) * inv * gg.x + bb.x, (u.y - mu) * inv * gg.y + bb.y),
                         cvt_pk2((u.z - mu) * inv * gg.z + bb.z, (u.w - mu) * inv * gg.w + bb.w));
    o4[c] = w;
  }
}

// ---------------- GEMM: C[M][N] = A[M][K] @ Bt[N][K]^T  (+ epilogue) ----------------
// 3 LDS buffers, depth-2 prefetch, counted vmcnt, bijective XCD swizzle,
// LDS chunk XOR-swizzle (linear dst + inverse-swz source + swz read).
// BN=128: 4 waves 2x2, wave tile 64x64 (acc 4x4). Grid (N/128)*(M/128).
// BN=64:  4 waves 2x2, wave tile 64x32 (acc 4x2), B-stage halves -> grid
//         (N/64)*(M/128) = 2x blocks for small-N GEMMs (WO/FC1 parallelism fix).
// EPI 0: +bias -> fp32   1: +bias+res -> fp32   2: +bias, gelu -> bf16
template <int EPI, int BN>
__global__ __launch_bounds__(256) void gemm_bf16(const bf16* __restrict__ A,
                                                 const bf16* __restrict__ Bt,
                                                 const float* __restrict__ bias, int nbias,
                                                 const float* __restrict__ res,
                                                 float* __restrict__ outf,
                                                 bf16* __restrict__ outb,
                                                 int M, int N, int K) {
  constexpr int NFR = (BN == 128) ? 4 : 2;  // B frags per wave
  __shared__ bf16 As[3][128 * 32];
  __shared__ bf16 Bs[3][BN * 32];
  const int t = threadIdx.x;
  const int l = t & 63;
  const int w = t >> 6;
  const int wr = w >> 1, wc = w & 1;
  const int lrow = l & 15;
  // swizzled read chunk: g ^ xs, xs = (lrow>>1)&3
  const int lks = (((l >> 4) ^ ((lrow >> 1) & 3)) & 3) * 8;
  const int wg = (blockIdx.x & 7) * (gridDim.x >> 3) + (blockIdx.x >> 3);
  const int gyt = M >> 7;
  const int xt = wg / gyt;
  const int yt = wg - xt * gyt;
  const int m0 = yt * 128;
  const int n0 = xt * BN;
  const int arow = t >> 2;
  // swizzled source chunk: (t&3) ^ ((t>>3)&3)
  const int ach = (((t & 3) ^ ((t >> 3) & 3)) & 3) * 8;

  const bf16* pa0 = &A[(size_t)(m0 + arow) * K + ach];
  const bf16* pa1 = &A[(size_t)(m0 + arow + 64) * K + ach];
  const bf16* pb0 = &Bt[(size_t)(n0 + arow) * K + ach];
  const bf16* pb1 = (BN == 128) ? &Bt[(size_t)(n0 + arow + 64) * K + ach] : pb0;
  auto STAGE = [&](int buf, int kt) {
    size_t off = (size_t)kt * 32;
    async_lds16(&As[buf][t * 8], pa0 + off);
    async_lds16(&As[buf][(256 + t) * 8], pa1 + off);
    async_lds16(&Bs[buf][t * 8], pb0 + off);
    if constexpr (BN == 128) async_lds16(&Bs[buf][(256 + t) * 8], pb1 + off);
  };

  f32x4 acc[4][NFR] = {};
  const int nkt = K >> 5;
  STAGE(0, 0);
  STAGE(1, 1);
  int bcur = 0;
  for (int kt = 0; kt < nkt; ++kt) {
    if (kt + 1 < nkt) {
      if constexpr (BN == 128)
        asm volatile("s_waitcnt vmcnt(4)" ::: "memory");  // stage kt landed; kt+1 in flight
      else
        asm volatile("s_waitcnt vmcnt(3)" ::: "memory");
    } else {
      asm volatile("s_waitcnt vmcnt(0)" ::: "memory");
    }
    __builtin_amdgcn_s_barrier();
    int bn2 = bcur + 2;
    if (bn2 >= 3) bn2 -= 3;
    if (kt + 2 < nkt) STAGE(bn2, kt + 2);

    short8 af[4], bfr[NFR];
#pragma unroll
    for (int i = 0; i < 4; ++i)
      af[i] = *(const short8*)&As[bcur][(wr * 64 + i * 16 + lrow) * 32 + lks];
#pragma unroll
    for (int j = 0; j < NFR; ++j)
      bfr[j] = *(const short8*)&Bs[bcur][(wc * (BN >> 1) + j * 16 + lrow) * 32 + lks];
    __builtin_amdgcn_s_setprio(1);
#pragma unroll
    for (int i = 0; i < 4; ++i)
#pragma unroll
      for (int j = 0; j < NFR; ++j)
        acc[i][j] = __builtin_amdgcn_mfma_f32_16x16x32_bf16(af[i], bfr[j], acc[i][j], 0, 0, 0);
    __builtin_amdgcn_s_setprio(0);
    ++bcur;
    if (bcur == 3) bcur = 0;
  }

#pragma unroll
  for (int i = 0; i < 4; ++i) {
    int rowb = m0 + wr * 64 + i * 16 + (l >> 4) * 4;
#pragma unroll
    for (int j = 0; j < NFR; ++j) {
      int col = n0 + wc * (BN >> 1) + j * 16 + lrow;
      float bv = (col < nbias) ? bias[col] : 0.f;
#pragma unroll
      for (int r2 = 0; r2 < 4; ++r2) {
        size_t idx = (size_t)(rowb + r2) * N + col;
        float v = acc[i][j][r2] + bv;
        if (EPI == 0) {
          outf[idx] = v;
        } else if (EPI == 1) {
          outf[idx] = v + res[idx];
        } else {
          float u = 0.7978845608028654f * (v + 0.044715f * v * v * v);
          u = fminf(fmaxf(u, -15.f), 15.f);
          float tt = __expf(2.f * u);
          outb[idx] = __float2bfloat16(v * tt / (tt + 1.f));
        }
      }
    }
  }
}

// ---------------- rope + qkv split ----------------
// q scale folds log2(e) so flash softmax runs in exp2 domain.
__global__ __launch_bounds__(256) void rope_split(const float* __restrict__ xqkv,
                                                  const float* __restrict__ cosb,
                                                  const float* __restrict__ sinb,
                                                  bf16* __restrict__ qp,
                                                  bf16* __restrict__ kp,
                                                  bf16* __restrict__ vt) {
  __shared__ bf16 vl[64][72];
  const int t = threadIdx.x;
  const int h = blockIdx.y;
  const int s0 = blockIdx.x * 64;
  const float scale = 0.17002445f;  // (1/sqrt(72)) * log2(e)
  for (int idx = t; idx < 64 * 48; idx += 256) {
    int sl = idx / 48, pi = idx - sl * 48;
    int srow = s0 + sl;
    size_t obase = ((size_t)h * SEQ + srow) * HDP + 2 * pi;
    if (pi < 36) {
      const float* xr = xqkv + (size_t)srow * (3 * HID) + h * HD + 2 * pi;
      float qr = xr[0], qi = xr[1];
      float kr = xr[HID], ki = xr[HID + 1];
      float c = cosb[srow * 36 + pi], sn = sinb[srow * 36 + pi];
      *(unsigned*)&qp[obase] = cvt_pk2((qr * c - qi * sn) * scale, (qr * sn + qi * c) * scale);
      *(unsigned*)&kp[obase] = cvt_pk2(kr * c - ki * sn, kr * sn + ki * c);
    } else {
      *(unsigned*)&qp[obase] = 0u;
      *(unsigned*)&kp[obase] = 0u;
    }
  }
  for (int idx = t; idx < 64 * 72; idx += 256) {
    int sl = idx / 72, d = idx - sl * 72;
    vl[sl][d] = __float2bfloat16(xqkv[(size_t)(s0 + sl) * (3 * HID) + 2 * HID + h * HD + d]);
  }
  __syncthreads();
  bf16 z = __float2bfloat16(0.f);
  for (int idx = t; idx < HDP * 64; idx += 256) {
    int d = idx / 64, sl = idx - d * 64;
    vt[((size_t)h * HDP + d) * SEQ + s0 + sl] = (d < 72) ? vl[sl][d] : z;
  }
}

// ---------------- flash attention (best-known config: KVBLK=32, 4 waves, 40KB) ----------------
// Triple-buffered KV, QK(t+1)-ahead, swapped operands (lane-local softmax),
// exp2-domain (log2e folded into q scale), defer-max THR=8*log2(e)=11.54,
// lane-local partial l (row-reduced once in epilogue). Grid 768 = 3 blocks/CU.
// NOTE: wrapped tail STAGEs keep the vmcnt counting uniform, so the kernel
// MUST drain vmcnt(0) before s_endpgm — in-flight global_load_lds writes land
// in this workgroup's LDS slot, which may already belong to the NEXT kernel's
// workgroup (cross-kernel LDS corruption; R13 post-timing divergence).
__global__ __launch_bounds__(256) void flash_attn(const bf16* __restrict__ q,
                                                  const bf16* __restrict__ kk,
                                                  const bf16* __restrict__ vT,
                                                  bf16* __restrict__ o) {
  __shared__ alignas(16) bf16 KV3[3 * 6144];
  __shared__ alignas(16) bf16 Pl[4][512];
  const int t = threadIdx.x;
  const int l = t & 63;
  const int w = t >> 6;
  const int g = l >> 4;
  const int lrow = l & 15;
  const int bid = blockIdx.x;
  const int kq = bid >> 3;
  const int h = (bid & 7) * 2 + (kq & 1);
  const int q0 = (kq >> 1) * 64 + w * 16;
  const int NT = SEQ / 32;

  const bf16* sbase[3];
  int smul[3];
#pragma unroll
  for (int i = 0; i < 3; ++i) {
    int s = t + i * 256;
    if (s < 384) {
      int cb = s >> 5, kv = s & 31;
      sbase[i] = kk + ((size_t)h * SEQ + kv) * HDP + cb * 8;
      smul[i] = 32 * HDP;
    } else {
      int vs = s - 384;
      int cb = vs / 96, d = vs - cb * 96;
      sbase[i] = vT + ((size_t)h * HDP + d) * SEQ + cb * 8;
      smul[i] = 32;
    }
  }
  auto STAGE = [&](int tile, int bufOff) {
#pragma unroll
    for (int i = 0; i < 3; ++i)
      async_lds16(&KV3[bufOff + (t + i * 256) * 8], sbase[i] + (size_t)tile * smul[i]);
  };

  short8 qf[3];
#pragma unroll
  for (int f = 0; f < 3; ++f)
    qf[f] = *(const short8*)&q[((size_t)h * SEQ + q0 + lrow) * HDP + f * 32 + g * 8];

  float m_r = -1e30f, l_r = 0.f;
  f32x4 oa[5] = {};

  STAGE(0, 0);
  STAGE(1, 6144);
  STAGE(2, 12288);
  asm volatile("s_waitcnt vmcnt(6)" ::: "memory");
  __builtin_amdgcn_s_barrier();

  f32x4 stA[2] = {}, stB[2];
  int b0 = 0;
#pragma unroll
  for (int nf = 0; nf < 2; ++nf)
#pragma unroll
    for (int f = 0; f < 3; ++f) {
      short8 kfrag = *(const short8*)&KV3[0 + (f * 4 + g) * 256 + (nf * 16 + lrow) * 8];
      stA[nf] = __builtin_amdgcn_mfma_f32_16x16x32_bf16(kfrag, qf[f], stA[nf], 0, 0, 0);
    }

  for (int kt = 0; kt < NT - 1; ++kt) {
    int b1 = b0 + 6144;
    if (b1 == 18432) b1 = 0;
    asm volatile("s_waitcnt vmcnt(3)" ::: "memory");
    __builtin_amdgcn_s_barrier();

    // QK(kt+1) from b1 (independent of softmax(kt) below)
    stB[0] = (f32x4){0.f, 0.f, 0.f, 0.f};
    stB[1] = (f32x4){0.f, 0.f, 0.f, 0.f};
    __builtin_amdgcn_s_setprio(1);
#pragma unroll
    for (int nf = 0; nf < 2; ++nf)
#pragma unroll
      for (int f = 0; f < 3; ++f) {
        short8 kfrag = *(const short8*)&KV3[b1 + (f * 4 + g) * 256 + (nf * 16 + lrow) * 8];
        stB[nf] = __builtin_amdgcn_mfma_f32_16x16x32_bf16(kfrag, qf[f], stB[nf], 0, 0, 0);
      }
    __builtin_amdgcn_s_setprio(0);

    // softmax(kt): defer-max (exp2 domain), lane-local partial l
    float pmax = fmaxf(fmaxf(fmaxf(stA[0][0], stA[0][1]), fmaxf(stA[0][2], stA[0][3])),
                       fmaxf(fmaxf(stA[1][0], stA[1][1]), fmaxf(stA[1][2], stA[1][3])));
    if (!__all(pmax - m_r <= 11.54f)) {
      float rm = pmax;
      rm = fmaxf(rm, __shfl_xor(rm, 16, 64));
      rm = fmaxf(rm, __shfl_xor(rm, 32, 64));
      float mn = fmaxf(m_r, rm);
      float alpha = exp2a(m_r - mn);
      l_r *= alpha;
#pragma unroll
      for (int nf = 0; nf < 5; ++nf)
#pragma unroll
        for (int r = 0; r < 4; ++r) oa[nf][r] *= alpha;
      m_r = mn;
    }
#pragma unroll
    for (int nf = 0; nf < 2; ++nf)
#pragma unroll
      for (int r = 0; r < 4; ++r) stA[nf][r] = exp2a(stA[nf][r] - m_r);
    l_r += (stA[0][0] + stA[0][1]) + (stA[0][2] + stA[0][3]) +
           (stA[1][0] + stA[1][1]) + (stA[1][2] + stA[1][3]);

    // P write: kv = nf*16+g*4+r, q=lrow -> elem = (2nf+(g>>1))*128 + lrow*8 + (g&1)*4
#pragma unroll
    for (int nf = 0; nf < 2; ++nf) {
      uint2* dst = (uint2*)&Pl[w][(2 * nf + (g >> 1)) * 128 + lrow * 8 + (g & 1) * 4];
      *dst = make_uint2(cvt_pk2(stA[nf][0], stA[nf][1]), cvt_pk2(stA[nf][2], stA[nf][3]));
    }

    // PV(kt) from b0: O^T += V' x P'
    {
      short8 pa = *(const short8*)&Pl[w][g * 128 + lrow * 8];
      __builtin_amdgcn_s_setprio(1);
#pragma unroll
      for (int nf = 0; nf < 5; ++nf) {
        short8 bv = *(const short8*)&KV3[b0 + 3072 + g * 768 + (nf * 16 + lrow) * 8];
        oa[nf] = __builtin_amdgcn_mfma_f32_16x16x32_bf16(bv, pa, oa[nf], 0, 0, 0);
      }
      __builtin_amdgcn_s_setprio(0);
    }

    asm volatile("s_waitcnt lgkmcnt(0)" ::: "memory");
    __builtin_amdgcn_s_barrier();
    int s = kt + 3;
    if (s >= NT) s -= NT;
    STAGE(s, b0);
    stA[0] = stB[0];
    stA[1] = stB[1];
    b0 = b1;
  }

  // epilogue tile NT-1
  {
    float pmax = fmaxf(fmaxf(fmaxf(stA[0][0], stA[0][1]), fmaxf(stA[0][2], stA[0][3])),
                       fmaxf(fmaxf(stA[1][0], stA[1][1]), fmaxf(stA[1][2], stA[1][3])));
    if (!__all(pmax - m_r <= 11.54f)) {
      float rm = pmax;
      rm = fmaxf(rm, __shfl_xor(rm, 16, 64));
      rm = fmaxf(rm, __shfl_xor(rm, 32, 64));
      float mn = fmaxf(m_r, rm);
      float alpha = exp2a(m_r - mn);
      l_r *= alpha;
#pragma unroll
      for (int nf = 0; nf < 5; ++nf)
#pragma unroll
        for (int r = 0; r < 4; ++r) oa[nf][r] *= alpha;
      m_r = mn;
    }
#pragma unroll
    for (int nf = 0; nf < 2; ++nf)
#pragma unroll
      for (int r = 0; r < 4; ++r) stA[nf][r] = exp2a(stA[nf][r] - m_r);
    l_r += (stA[0][0] + stA[0][1]) + (stA[0][2] + stA[0][3]) +
           (stA[1][0] + stA[1][1]) + (stA[1][2] + stA[1][3]);
#pragma unroll
    for (int nf = 0; nf < 2; ++nf) {
      uint2* dst = (uint2*)&Pl[w][(2 * nf + (g >> 1)) * 128 + lrow * 8 + (g & 1) * 4];
      *dst = make_uint2(cvt_pk2(stA[nf][0], stA[nf][1]), cvt_pk2(stA[nf][2], stA[nf][3]));
    }
    short8 pa = *(const short8*)&Pl[w][g * 128 + lrow * 8];
#pragma unroll
    for (int nf = 0; nf < 5; ++nf) {
      short8 bv = *(const short8*)&KV3[b0 + 3072 + g * 768 + (nf * 16 + lrow) * 8];
      oa[nf] = __builtin_amdgcn_mfma_f32_16x16x32_bf16(bv, pa, oa[nf], 0, 0, 0);
    }
  }

  // drain stale wrapped stages BEFORE exit (see kernel comment)
  asm volatile("s_waitcnt vmcnt(0)" ::: "memory");

  // row-reduce the partial l (deferred from the loop), then store
  float lt = l_r;
  lt += __shfl_xor(lt, 16, 64);
  lt += __shfl_xor(lt, 32, 64);
  float rcp = 1.f / lt;
  size_t obase = (size_t)(q0 + lrow) * HID + h * HD;
#pragma unroll
  for (int nf = 0; nf < 5; ++nf) {
    int d = nf * 16 + g * 4;
    if (d + 3 < HD) {
      uint2 pk = make_uint2(cvt_pk2(oa[nf][0] * rcp, oa[nf][1] * rcp),
                            cvt_pk2(oa[nf][2] * rcp, oa[nf][3] * rcp));
      *(uint2*)&o[obase + d] = pk;
    }
  }
}

// ---------------- launch ----------------
extern "C" void kernel_launch(void* const* d_in, const int* in_sizes, int n_in,
                              void* d_out, int out_size, void* d_ws, size_t ws_size,
                              hipStream_t stream) {
  (void)in_sizes; (void)n_in; (void)out_size;
  const float* hidden = (const float*)d_in[0];
  const float* cosb = (const float*)d_in[1];
  const float* sinb = (const float*)d_in[2];
  const float* ln0g = (const float*)d_in[3];
  const float* ln0b = (const float*)d_in[4];
  const float* ln1g = (const float*)d_in[5];
  const float* ln1b = (const float*)d_in[6];
  const float* wqkv = (const float*)d_in[7];
  const float* bqkv = (const float*)d_in[8];
  const float* wo = (const float*)d_in[9];
  const float* bo = (const float*)d_in[10];
  const float* w0 = (const float*)d_in[11];
  const float* b0 = (const float*)d_in[12];
  const float* w1 = (const float*)d_in[13];
  const float* b1 = (const float*)d_in[14];

  char* p = (char*)d_ws;
  auto alloc = [&](size_t n) {
    char* r = p;
    p += (n + 255) & ~(size_t)255;
    return r;
  };
  bf16* wqkv_bf = (bf16*)alloc((size_t)3 * HID * HID * 2);
  bf16* wo_bf = (bf16*)alloc((size_t)HID * HID * 2);
  bf16* fc0_bf = (bf16*)alloc((size_t)MLPP * HID * 2);
  bf16* fc1_bf = (bf16*)alloc((size_t)HID * MLPP * 2);
  bf16* ln0_bf = (bf16*)alloc((size_t)SEQ * HID * 2);
  float* xqkv = (float*)alloc((size_t)SEQ * 3 * HID * 4);
  bf16* qp = (bf16*)alloc((size_t)NHEAD * SEQ * HDP * 2);
  bf16* kp = (bf16*)alloc((size_t)NHEAD * SEQ * HDP * 2);
  bf16* vt = (bf16*)alloc((size_t)NHEAD * HDP * SEQ * 2);
  bf16* attn_bf = (bf16*)alloc((size_t)SEQ * HID * 2);
  float* h1 = (float*)alloc((size_t)SEQ * HID * 4);
  bf16* ln1_bf = (bf16*)alloc((size_t)SEQ * HID * 2);
  bf16* gelu_bf = (bf16*)alloc((size_t)SEQ * MLPP * 2);
  if ((size_t)(p - (char*)d_ws) > ws_size) return;

  dim3 blk(256);
  cast_all_k<<<2048, blk, 0, stream>>>(wqkv, wo, w0, w1, (unsigned*)wqkv_bf, (unsigned*)wo_bf,
                                       (unsigned*)fc0_bf, (unsigned*)fc1_bf);
  ln_k<<<SEQ, blk, 0, stream>>>(hidden, ln0g, ln0b, ln0_bf);
  gemm_bf16<0, 128><<<dim3((3 * HID / 128) * (SEQ / 128)), blk, 0, stream>>>(
      ln0_bf, wqkv_bf, bqkv, 3 * HID, nullptr, xqkv, nullptr, SEQ, 3 * HID, HID);
  rope_split<<<dim3(SEQ / 64, NHEAD), blk, 0, stream>>>(xqkv, cosb, sinb, qp, kp, vt);
  flash_attn<<<dim3(768), blk, 0, stream>>>(qp, kp, vt, attn_bf);
  gemm_bf16<1, 64><<<dim3((HID / 64) * (SEQ / 128)), blk, 0, stream>>>(
      attn_bf, wo_bf, bo, HID, hidden, h1, nullptr, SEQ, HID, HID);
  ln_k<<<SEQ, blk, 0, stream>>>(h1, ln1g, ln1b, ln1_bf);
  gemm_bf16<2, 128><<<dim3((MLPP / 128) * (SEQ / 128)), blk, 0, stream>>>(
      ln1_bf, fc0_bf, b0, MLPD, nullptr, nullptr, gelu_bf, SEQ, MLPP, HID);
  gemm_bf16<1, 64><<<dim3((HID / 64) * (SEQ / 128)), blk, 0, stream>>>(
      gelu_bf, fc1_bf, b1, HID, h1, (float*)d_out, nullptr, SEQ, HID, MLPP);
}

// Round 15
// 343.346 us; speedup vs baseline: 1.2362x; 1.0238x over previous
//
#include <hip/hip_runtime.h>
#include <hip/hip_bf16.h>
#include <math.h>

typedef __hip_bfloat16 bf16;
typedef __attribute__((ext_vector_type(8))) short short8;
typedef __attribute__((ext_vector_type(4))) short short4v;
typedef __attribute__((ext_vector_type(4))) float f32x4;

#define SEQ 3072
#define HID 1152
#define NHEAD 16
#define HD 72
#define HDP 96
#define MLPD 4304
#define MLPP 4352

__device__ __forceinline__ void async_lds16(void* lds, const void* g) {
  __builtin_amdgcn_global_load_lds((const __attribute__((address_space(1))) void*)g,
                                   (__attribute__((address_space(3))) void*)lds,
                                   16, 0, 0);
}

// one v_cvt_pk_bf16_f32: a -> low16, b -> high16 (RNE)
__device__ __forceinline__ unsigned cvt_pk2(float a, float b) {
  unsigned r;
  asm("v_cvt_pk_bf16_f32 %0, %1, %2" : "=v"(r) : "v"(a), "v"(b));
  return r;
}

// raw v_exp_f32: 2^x
__device__ __forceinline__ float exp2a(float x) {
  float r;
  asm("v_exp_f32 %0, %1" : "=v"(r) : "v"(x));
  return r;
}

// bf16 pair (packed in u32) -> two floats, bit-ops only
__device__ __forceinline__ float bflo(unsigned u) { return __uint_as_float(u << 16); }
__device__ __forceinline__ float bfhi(unsigned u) { return __uint_as_float(u & 0xffff0000u); }

// ---------------- prep: LN0 (blocks < SEQ) + all weight casts (rest) ----------------
__global__ __launch_bounds__(256) void prep_k(const float* __restrict__ hidden,
                                              const float* __restrict__ ln0g,
                                              const float* __restrict__ ln0b,
                                              const float* __restrict__ wqkv,
                                              const float* __restrict__ wo,
                                              const float* __restrict__ w0,
                                              const float* __restrict__ w1,
                                              bf16* __restrict__ ln0_o,
                                              unsigned* __restrict__ wqkv_o,
                                              unsigned* __restrict__ wo_o,
                                              unsigned* __restrict__ fc0_o,
                                              unsigned* __restrict__ fc1_o) {
  if (blockIdx.x < SEQ) {
    // ---- LN0 row ----
    int row = blockIdx.x;
    const float4* xr = (const float4*)(hidden + (size_t)row * HID);
    float sum = 0.f, sq = 0.f;
    for (int c = threadIdx.x; c < HID / 4; c += 256) {
      float4 u = xr[c];
      sum += u.x + u.y + u.z + u.w;
      sq += u.x * u.x + u.y * u.y + u.z * u.z + u.w * u.w;
    }
#pragma unroll
    for (int off = 32; off > 0; off >>= 1) {
      sum += __shfl_down(sum, off, 64);
      sq += __shfl_down(sq, off, 64);
    }
    __shared__ float red[8];
    int wv = threadIdx.x >> 6;
    if ((threadIdx.x & 63) == 0) { red[wv] = sum; red[4 + wv] = sq; }
    __syncthreads();
    if (threadIdx.x == 0) {
      red[0] = red[0] + red[1] + red[2] + red[3];
      red[4] = red[4] + red[5] + red[6] + red[7];
    }
    __syncthreads();
    float mu = red[0] * (1.f / HID);
    float var = red[4] * (1.f / HID) - mu * mu;
    float inv = rsqrtf(var + 1e-5f);
    uint2* o4 = (uint2*)(ln0_o + (size_t)row * HID);
    const float4* g4 = (const float4*)ln0g;
    const float4* b4 = (const float4*)ln0b;
    for (int c = threadIdx.x; c < HID / 4; c += 256) {
      float4 u = xr[c], gg = g4[c], bb = b4[c];
      o4[c] = make_uint2(cvt_pk2((u.x - mu) * inv * gg.x + bb.x, (u.y - mu) * inv * gg.y + bb.y),
                         cvt_pk2((u.z - mu) * inv * gg.z + bb.z, (u.w - mu) * inv * gg.w + bb.w));
    }
    return;
  }
  // ---- weight casts (grid-stride over the cast blocks) ----
  const int n0 = 3 * HID * HID / 4;
  const int n1 = HID * HID / 4;
  const int n2 = MLPP * HID / 4;
  const int n3 = HID * MLPP / 4;
  const int total = n0 + n1 + n2 + n3;
  int nb = gridDim.x - SEQ;
  int stride = nb * blockDim.x;
  for (int i = (blockIdx.x - SEQ) * blockDim.x + threadIdx.x; i < total; i += stride) {
    if (i < n0) {
      float4 u = ((const float4*)wqkv)[i];
      ((uint2*)wqkv_o)[i] = make_uint2(cvt_pk2(u.x, u.y), cvt_pk2(u.z, u.w));
    } else if (i < n0 + n1) {
      int k = i - n0;
      float4 u = ((const float4*)wo)[k];
      ((uint2*)wo_o)[k] = make_uint2(cvt_pk2(u.x, u.y), cvt_pk2(u.z, u.w));
    } else if (i < n0 + n1 + n2) {
      int k = i - n0 - n1;
      int r = k / (HID / 4);
      uint2 w = make_uint2(0u, 0u);
      if (r < MLPD) {
        float4 u = ((const float4*)w0)[k];
        w = make_uint2(cvt_pk2(u.x, u.y), cvt_pk2(u.z, u.w));
      }
      ((uint2*)fc0_o)[k] = w;
    } else {
      int k = i - n0 - n1 - n2;
      int r = k / (MLPP / 4), c4 = k - r * (MLPP / 4);
      uint2 w = make_uint2(0u, 0u);
      if (c4 < MLPD / 4) {
        float4 u = ((const float4*)w1)[r * (MLPD / 4) + c4];
        w = make_uint2(cvt_pk2(u.x, u.y), cvt_pk2(u.z, u.w));
      }
      ((uint2*)fc1_o)[k] = w;
    }
  }
}

// ---------------- layernorm (fp32 in -> bf16 out) ----------------
__global__ __launch_bounds__(256) void ln_k(const float* __restrict__ x,
                                            const float* __restrict__ g,
                                            const float* __restrict__ b,
                                            bf16* __restrict__ o) {
  int row = blockIdx.x;
  const float4* xr = (const float4*)(x + (size_t)row * HID);
  float sum = 0.f, sq = 0.f;
  for (int c = threadIdx.x; c < HID / 4; c += 256) {
    float4 u = xr[c];
    sum += u.x + u.y + u.z + u.w;
    sq += u.x * u.x + u.y * u.y + u.z * u.z + u.w * u.w;
  }
#pragma unroll
  for (int off = 32; off > 0; off >>= 1) {
    sum += __shfl_down(sum, off, 64);
    sq += __shfl_down(sq, off, 64);
  }
  __shared__ float red[8];
  int wv = threadIdx.x >> 6;
  if ((threadIdx.x & 63) == 0) { red[wv] = sum; red[4 + wv] = sq; }
  __syncthreads();
  if (threadIdx.x == 0) {
    red[0] = red[0] + red[1] + red[2] + red[3];
    red[4] = red[4] + red[5] + red[6] + red[7];
  }
  __syncthreads();
  float mu = red[0] * (1.f / HID);
  float var = red[4] * (1.f / HID) - mu * mu;
  float inv = rsqrtf(var + 1e-5f);
  uint2* o4 = (uint2*)(o + (size_t)row * HID);
  const float4* g4 = (const float4*)g;
  const float4* b4 = (const float4*)b;
  for (int c = threadIdx.x; c < HID / 4; c += 256) {
    float4 u = xr[c], gg = g4[c], bb = b4[c];
    uint2 w = make_uint2(cvt_pk2((u.x - mu) * inv * gg.x + bb.x, (u.y - mu) * inv * gg.y + bb.y),
                         cvt_pk2((u.z - mu) * inv * gg.z + bb.z, (u.w - mu) * inv * gg.w + bb.w));
    o4[c] = w;
  }
}

// ---------------- GEMM: C[M][N] = A[M][K] @ Bt[N][K]^T  (+ epilogue) ----------------
// 3 LDS buffers, depth-2 prefetch, counted vmcnt, bijective XCD swizzle,
// LDS chunk XOR-swizzle (linear dst + inverse-swz source + swz read).
// BN=128: 4 waves 2x2, wave tile 64x64 (acc 4x4). BN=64: wave tile 64x32.
// EPI 0: +bias -> bf16   1: +bias+res -> fp32   2: +bias, gelu -> bf16
template <int EPI, int BN>
__global__ __launch_bounds__(256) void gemm_bf16(const bf16* __restrict__ A,
                                                 const bf16* __restrict__ Bt,
                                                 const float* __restrict__ bias, int nbias,
                                                 const float* __restrict__ res,
                                                 float* __restrict__ outf,
                                                 bf16* __restrict__ outb,
                                                 int M, int N, int K) {
  constexpr int NFR = (BN == 128) ? 4 : 2;  // B frags per wave
  __shared__ bf16 As[3][128 * 32];
  __shared__ bf16 Bs[3][BN * 32];
  const int t = threadIdx.x;
  const int l = t & 63;
  const int w = t >> 6;
  const int wr = w >> 1, wc = w & 1;
  const int lrow = l & 15;
  // swizzled read chunk: g ^ xs, xs = (lrow>>1)&3
  const int lks = (((l >> 4) ^ ((lrow >> 1) & 3)) & 3) * 8;
  const int wg = (blockIdx.x & 7) * (gridDim.x >> 3) + (blockIdx.x >> 3);
  const int gyt = M >> 7;
  const int xt = wg / gyt;
  const int yt = wg - xt * gyt;
  const int m0 = yt * 128;
  const int n0 = xt * BN;
  const int arow = t >> 2;
  // swizzled source chunk: (t&3) ^ ((t>>3)&3)
  const int ach = (((t & 3) ^ ((t >> 3) & 3)) & 3) * 8;

  const bf16* pa0 = &A[(size_t)(m0 + arow) * K + ach];
  const bf16* pa1 = &A[(size_t)(m0 + arow + 64) * K + ach];
  const bf16* pb0 = &Bt[(size_t)(n0 + arow) * K + ach];
  const bf16* pb1 = (BN == 128) ? &Bt[(size_t)(n0 + arow + 64) * K + ach] : pb0;
  auto STAGE = [&](int buf, int kt) {
    size_t off = (size_t)kt * 32;
    async_lds16(&As[buf][t * 8], pa0 + off);
    async_lds16(&As[buf][(256 + t) * 8], pa1 + off);
    async_lds16(&Bs[buf][t * 8], pb0 + off);
    if constexpr (BN == 128) async_lds16(&Bs[buf][(256 + t) * 8], pb1 + off);
  };

  f32x4 acc[4][NFR] = {};
  const int nkt = K >> 5;
  STAGE(0, 0);
  STAGE(1, 1);
  int bcur = 0;
  for (int kt = 0; kt < nkt; ++kt) {
    if (kt + 1 < nkt) {
      if constexpr (BN == 128)
        asm volatile("s_waitcnt vmcnt(4)" ::: "memory");  // stage kt landed; kt+1 in flight
      else
        asm volatile("s_waitcnt vmcnt(3)" ::: "memory");
    } else {
      asm volatile("s_waitcnt vmcnt(0)" ::: "memory");
    }
    __builtin_amdgcn_s_barrier();
    int bn2 = bcur + 2;
    if (bn2 >= 3) bn2 -= 3;
    if (kt + 2 < nkt) STAGE(bn2, kt + 2);

    short8 af[4], bfr[NFR];
#pragma unroll
    for (int i = 0; i < 4; ++i)
      af[i] = *(const short8*)&As[bcur][(wr * 64 + i * 16 + lrow) * 32 + lks];
#pragma unroll
    for (int j = 0; j < NFR; ++j)
      bfr[j] = *(const short8*)&Bs[bcur][(wc * (BN >> 1) + j * 16 + lrow) * 32 + lks];
    __builtin_amdgcn_s_setprio(1);
#pragma unroll
    for (int i = 0; i < 4; ++i)
#pragma unroll
      for (int j = 0; j < NFR; ++j)
        acc[i][j] = __builtin_amdgcn_mfma_f32_16x16x32_bf16(af[i], bfr[j], acc[i][j], 0, 0, 0);
    __builtin_amdgcn_s_setprio(0);
    ++bcur;
    if (bcur == 3) bcur = 0;
  }

#pragma unroll
  for (int i = 0; i < 4; ++i) {
    int rowb = m0 + wr * 64 + i * 16 + (l >> 4) * 4;
#pragma unroll
    for (int j = 0; j < NFR; ++j) {
      int col = n0 + wc * (BN >> 1) + j * 16 + lrow;
      float bv = (col < nbias) ? bias[col] : 0.f;
#pragma unroll
      for (int r2 = 0; r2 < 4; ++r2) {
        size_t idx = (size_t)(rowb + r2) * N + col;
        float v = acc[i][j][r2] + bv;
        if (EPI == 0) {
          outb[idx] = __float2bfloat16(v);
        } else if (EPI == 1) {
          outf[idx] = v + res[idx];
        } else {
          float u = 0.7978845608028654f * (v + 0.044715f * v * v * v);
          u = fminf(fmaxf(u, -15.f), 15.f);
          float tt = __expf(2.f * u);
          outb[idx] = __float2bfloat16(v * tt / (tt + 1.f));
        }
      }
    }
  }
}

// ---------------- rope + qkv split (xqkv now bf16) ----------------
// q scale folds log2(e) so flash softmax runs in exp2 domain.
__global__ __launch_bounds__(256) void rope_split(const bf16* __restrict__ xqkv,
                                                  const float* __restrict__ cosb,
                                                  const float* __restrict__ sinb,
                                                  bf16* __restrict__ qp,
                                                  bf16* __restrict__ kp,
                                                  bf16* __restrict__ vt) {
  __shared__ bf16 vl[64][72];
  const int t = threadIdx.x;
  const int h = blockIdx.y;
  const int s0 = blockIdx.x * 64;
  const float scale = 0.17002445f;  // (1/sqrt(72)) * log2(e)
  for (int idx = t; idx < 64 * 48; idx += 256) {
    int sl = idx / 48, pi = idx - sl * 48;
    int srow = s0 + sl;
    size_t obase = ((size_t)h * SEQ + srow) * HDP + 2 * pi;
    if (pi < 36) {
      const bf16* xr = xqkv + (size_t)srow * (3 * HID) + h * HD + 2 * pi;
      unsigned qw = *(const unsigned*)xr;
      unsigned kw = *(const unsigned*)(xr + HID);
      float qr = bflo(qw), qi = bfhi(qw);
      float kr = bflo(kw), ki = bfhi(kw);
      float c = cosb[srow * 36 + pi], sn = sinb[srow * 36 + pi];
      *(unsigned*)&qp[obase] = cvt_pk2((qr * c - qi * sn) * scale, (qr * sn + qi * c) * scale);
      *(unsigned*)&kp[obase] = cvt_pk2(kr * c - ki * sn, kr * sn + ki * c);
    } else {
      *(unsigned*)&qp[obase] = 0u;
      *(unsigned*)&kp[obase] = 0u;
    }
  }
  for (int idx = t; idx < 64 * 72; idx += 256) {
    int sl = idx / 72, d = idx - sl * 72;
    vl[sl][d] = xqkv[(size_t)(s0 + sl) * (3 * HID) + 2 * HID + h * HD + d];
  }
  __syncthreads();
  bf16 z = __float2bfloat16(0.f);
  for (int idx = t; idx < HDP * 64; idx += 256) {
    int d = idx / 64, sl = idx - d * 64;
    vt[((size_t)h * HDP + d) * SEQ + s0 + sl] = (d < 72) ? vl[sl][d] : z;
  }
}

// ---------------- flash attention (best-known config: KVBLK=32, 4 waves, 40KB) ----------------
// Triple-buffered KV, QK(t+1)-ahead, swapped operands (lane-local softmax),
// exp2-domain (log2e folded into q scale), defer-max THR=8*log2(e)=11.54,
// lane-local partial l (row-reduced once in epilogue). Grid 768 = 3 blocks/CU.
// NOTE: wrapped tail STAGEs keep the vmcnt counting uniform, so the kernel
// MUST drain vmcnt(0) before s_endpgm — in-flight global_load_lds writes land
// in this workgroup's LDS slot, which may already belong to the NEXT kernel's
// workgroup (cross-kernel LDS corruption; R13 post-timing divergence).
__global__ __launch_bounds__(256) void flash_attn(const bf16* __restrict__ q,
                                                  const bf16* __restrict__ kk,
                                                  const bf16* __restrict__ vT,
                                                  bf16* __restrict__ o) {
  __shared__ alignas(16) bf16 KV3[3 * 6144];
  __shared__ alignas(16) bf16 Pl[4][512];
  const int t = threadIdx.x;
  const int l = t & 63;
  const int w = t >> 6;
  const int g = l >> 4;
  const int lrow = l & 15;
  const int bid = blockIdx.x;
  const int kq = bid >> 3;
  const int h = (bid & 7) * 2 + (kq & 1);
  const int q0 = (kq >> 1) * 64 + w * 16;
  const int NT = SEQ / 32;

  const bf16* sbase[3];
  int smul[3];
#pragma unroll
  for (int i = 0; i < 3; ++i) {
    int s = t + i * 256;
    if (s < 384) {
      int cb = s >> 5, kv = s & 31;
      sbase[i] = kk + ((size_t)h * SEQ + kv) * HDP + cb * 8;
      smul[i] = 32 * HDP;
    } else {
      int vs = s - 384;
      int cb = vs / 96, d = vs - cb * 96;
      sbase[i] = vT + ((size_t)h * HDP + d) * SEQ + cb * 8;
      smul[i] = 32;
    }
  }
  auto STAGE = [&](int tile, int bufOff) {
#pragma unroll
    for (int i = 0; i < 3; ++i)
      async_lds16(&KV3[bufOff + (t + i * 256) * 8], sbase[i] + (size_t)tile * smul[i]);
  };

  short8 qf[3];
#pragma unroll
  for (int f = 0; f < 3; ++f)
    qf[f] = *(const short8*)&q[((size_t)h * SEQ + q0 + lrow) * HDP + f * 32 + g * 8];

  float m_r = -1e30f, l_r = 0.f;
  f32x4 oa[5] = {};

  STAGE(0, 0);
  STAGE(1, 6144);
  STAGE(2, 12288);
  asm volatile("s_waitcnt vmcnt(6)" ::: "memory");
  __builtin_amdgcn_s_barrier();

  f32x4 stA[2] = {}, stB[2];
  int b0 = 0;
#pragma unroll
  for (int nf = 0; nf < 2; ++nf)
#pragma unroll
    for (int f = 0; f < 3; ++f) {
      short8 kfrag = *(const short8*)&KV3[0 + (f * 4 + g) * 256 + (nf * 16 + lrow) * 8];
      stA[nf] = __builtin_amdgcn_mfma_f32_16x16x32_bf16(kfrag, qf[f], stA[nf], 0, 0, 0);
    }

  for (int kt = 0; kt < NT - 1; ++kt) {
    int b1 = b0 + 6144;
    if (b1 == 18432) b1 = 0;
    asm volatile("s_waitcnt vmcnt(3)" ::: "memory");
    __builtin_amdgcn_s_barrier();

    // QK(kt+1) from b1 (independent of softmax(kt) below)
    stB[0] = (f32x4){0.f, 0.f, 0.f, 0.f};
    stB[1] = (f32x4){0.f, 0.f, 0.f, 0.f};
    __builtin_amdgcn_s_setprio(1);
#pragma unroll
    for (int nf = 0; nf < 2; ++nf)
#pragma unroll
      for (int f = 0; f < 3; ++f) {
        short8 kfrag = *(const short8*)&KV3[b1 + (f * 4 + g) * 256 + (nf * 16 + lrow) * 8];
        stB[nf] = __builtin_amdgcn_mfma_f32_16x16x32_bf16(kfrag, qf[f], stB[nf], 0, 0, 0);
      }
    __builtin_amdgcn_s_setprio(0);

    // softmax(kt): defer-max (exp2 domain), lane-local partial l
    float pmax = fmaxf(fmaxf(fmaxf(stA[0][0], stA[0][1]), fmaxf(stA[0][2], stA[0][3])),
                       fmaxf(fmaxf(stA[1][0], stA[1][1]), fmaxf(stA[1][2], stA[1][3])));
    if (!__all(pmax - m_r <= 11.54f)) {
      float rm = pmax;
      rm = fmaxf(rm, __shfl_xor(rm, 16, 64));
      rm = fmaxf(rm, __shfl_xor(rm, 32, 64));
      float mn = fmaxf(m_r, rm);
      float alpha = exp2a(m_r - mn);
      l_r *= alpha;
#pragma unroll
      for (int nf = 0; nf < 5; ++nf)
#pragma unroll
        for (int r = 0; r < 4; ++r) oa[nf][r] *= alpha;
      m_r = mn;
    }
#pragma unroll
    for (int nf = 0; nf < 2; ++nf)
#pragma unroll
      for (int r = 0; r < 4; ++r) stA[nf][r] = exp2a(stA[nf][r] - m_r);
    l_r += (stA[0][0] + stA[0][1]) + (stA[0][2] + stA[0][3]) +
           (stA[1][0] + stA[1][1]) + (stA[1][2] + stA[1][3]);

    // P write: kv = nf*16+g*4+r, q=lrow -> elem = (2nf+(g>>1))*128 + lrow*8 + (g&1)*4
#pragma unroll
    for (int nf = 0; nf < 2; ++nf) {
      uint2* dst = (uint2*)&Pl[w][(2 * nf + (g >> 1)) * 128 + lrow * 8 + (g & 1) * 4];
      *dst = make_uint2(cvt_pk2(stA[nf][0], stA[nf][1]), cvt_pk2(stA[nf][2], stA[nf][3]));
    }

    // PV(kt) from b0: O^T += V' x P'
    {
      short8 pa = *(const short8*)&Pl[w][g * 128 + lrow * 8];
      __builtin_amdgcn_s_setprio(1);
#pragma unroll
      for (int nf = 0; nf < 5; ++nf) {
        short8 bv = *(const short8*)&KV3[b0 + 3072 + g * 768 + (nf * 16 + lrow) * 8];
        oa[nf] = __builtin_amdgcn_mfma_f32_16x16x32_bf16(bv, pa, oa[nf], 0, 0, 0);
      }
      __builtin_amdgcn_s_setprio(0);
    }

    asm volatile("s_waitcnt lgkmcnt(0)" ::: "memory");
    __builtin_amdgcn_s_barrier();
    int s = kt + 3;
    if (s >= NT) s -= NT;
    STAGE(s, b0);
    stA[0] = stB[0];
    stA[1] = stB[1];
    b0 = b1;
  }

  // epilogue tile NT-1
  {
    float pmax = fmaxf(fmaxf(fmaxf(stA[0][0], stA[0][1]), fmaxf(stA[0][2], stA[0][3])),
                       fmaxf(fmaxf(stA[1][0], stA[1][1]), fmaxf(stA[1][2], stA[1][3])));
    if (!__all(pmax - m_r <= 11.54f)) {
      float rm = pmax;
      rm = fmaxf(rm, __shfl_xor(rm, 16, 64));
      rm = fmaxf(rm, __shfl_xor(rm, 32, 64));
      float mn = fmaxf(m_r, rm);
      float alpha = exp2a(m_r - mn);
      l_r *= alpha;
#pragma unroll
      for (int nf = 0; nf < 5; ++nf)
#pragma unroll
        for (int r = 0; r < 4; ++r) oa[nf][r] *= alpha;
      m_r = mn;
    }
#pragma unroll
    for (int nf = 0; nf < 2; ++nf)
#pragma unroll
      for (int r = 0; r < 4; ++r) stA[nf][r] = exp2a(stA[nf][r] - m_r);
    l_r += (stA[0][0] + stA[0][1]) + (stA[0][2] + stA[0][3]) +
           (stA[1][0] + stA[1][1]) + (stA[1][2] + stA[1][3]);
#pragma unroll
    for (int nf = 0; nf < 2; ++nf) {
      uint2* dst = (uint2*)&Pl[w][(2 * nf + (g >> 1)) * 128 + lrow * 8 + (g & 1) * 4];
      *dst = make_uint2(cvt_pk2(stA[nf][0], stA[nf][1]), cvt_pk2(stA[nf][2], stA[nf][3]));
    }
    short8 pa = *(const short8*)&Pl[w][g * 128 + lrow * 8];
#pragma unroll
    for (int nf = 0; nf < 5; ++nf) {
      short8 bv = *(const short8*)&KV3[b0 + 3072 + g * 768 + (nf * 16 + lrow) * 8];
      oa[nf] = __builtin_amdgcn_mfma_f32_16x16x32_bf16(bv, pa, oa[nf], 0, 0, 0);
    }
  }

  // drain stale wrapped stages BEFORE exit (see kernel comment)
  asm volatile("s_waitcnt vmcnt(0)" ::: "memory");

  // row-reduce the partial l (deferred from the loop), then store
  float lt = l_r;
  lt += __shfl_xor(lt, 16, 64);
  lt += __shfl_xor(lt, 32, 64);
  float rcp = 1.f / lt;
  size_t obase = (size_t)(q0 + lrow) * HID + h * HD;
#pragma unroll
  for (int nf = 0; nf < 5; ++nf) {
    int d = nf * 16 + g * 4;
    if (d + 3 < HD) {
      uint2 pk = make_uint2(cvt_pk2(oa[nf][0] * rcp, oa[nf][1] * rcp),
                            cvt_pk2(oa[nf][2] * rcp, oa[nf][3] * rcp));
      *(uint2*)&o[obase + d] = pk;
    }
  }
}

// ---------------- launch ----------------
extern "C" void kernel_launch(void* const* d_in, const int* in_sizes, int n_in,
                              void* d_out, int out_size, void* d_ws, size_t ws_size,
                              hipStream_t stream) {
  (void)in_sizes; (void)n_in; (void)out_size;
  const float* hidden = (const float*)d_in[0];
  const float* cosb = (const float*)d_in[1];
  const float* sinb = (const float*)d_in[2];
  const float* ln0g = (const float*)d_in[3];
  const float* ln0b = (const float*)d_in[4];
  const float* ln1g = (const float*)d_in[5];
  const float* ln1b = (const float*)d_in[6];
  const float* wqkv = (const float*)d_in[7];
  const float* bqkv = (const float*)d_in[8];
  const float* wo = (const float*)d_in[9];
  const float* bo = (const float*)d_in[10];
  const float* w0 = (const float*)d_in[11];
  const float* b0 = (const float*)d_in[12];
  const float* w1 = (const float*)d_in[13];
  const float* b1 = (const float*)d_in[14];

  char* p = (char*)d_ws;
  auto alloc = [&](size_t n) {
    char* r = p;
    p += (n + 255) & ~(size_t)255;
    return r;
  };
  bf16* wqkv_bf = (bf16*)alloc((size_t)3 * HID * HID * 2);
  bf16* wo_bf = (bf16*)alloc((size_t)HID * HID * 2);
  bf16* fc0_bf = (bf16*)alloc((size_t)MLPP * HID * 2);
  bf16* fc1_bf = (bf16*)alloc((size_t)HID * MLPP * 2);
  bf16* ln0_bf = (bf16*)alloc((size_t)SEQ * HID * 2);
  bf16* xqkv = (bf16*)alloc((size_t)SEQ * 3 * HID * 2);
  bf16* qp = (bf16*)alloc((size_t)NHEAD * SEQ * HDP * 2);
  bf16* kp = (bf16*)alloc((size_t)NHEAD * SEQ * HDP * 2);
  bf16* vt = (bf16*)alloc((size_t)NHEAD * HDP * SEQ * 2);
  bf16* attn_bf = (bf16*)alloc((size_t)SEQ * HID * 2);
  float* h1 = (float*)alloc((size_t)SEQ * HID * 4);
  bf16* ln1_bf = (bf16*)alloc((size_t)SEQ * HID * 2);
  bf16* gelu_bf = (bf16*)alloc((size_t)SEQ * MLPP * 2);
  if ((size_t)(p - (char*)d_ws) > ws_size) return;

  dim3 blk(256);
  prep_k<<<SEQ + 1024, blk, 0, stream>>>(hidden, ln0g, ln0b, wqkv, wo, w0, w1, ln0_bf,
                                         (unsigned*)wqkv_bf, (unsigned*)wo_bf,
                                         (unsigned*)fc0_bf, (unsigned*)fc1_bf);
  gemm_bf16<0, 128><<<dim3((3 * HID / 128) * (SEQ / 128)), blk, 0, stream>>>(
      ln0_bf, wqkv_bf, bqkv, 3 * HID, nullptr, nullptr, xqkv, SEQ, 3 * HID, HID);
  rope_split<<<dim3(SEQ / 64, NHEAD), blk, 0, stream>>>(xqkv, cosb, sinb, qp, kp, vt);
  flash_attn<<<dim3(768), blk, 0, stream>>>(qp, kp, vt, attn_bf);
  gemm_bf16<1, 64><<<dim3((HID / 64) * (SEQ / 128)), blk, 0, stream>>>(
      attn_bf, wo_bf, bo, HID, hidden, h1, nullptr, SEQ, HID, HID);
  ln_k<<<SEQ, blk, 0, stream>>>(h1, ln1g, ln1b, ln1_bf);
  gemm_bf16<2, 128><<<dim3((MLPP / 128) * (SEQ / 128)), blk, 0, stream>>>(
      ln1_bf, fc0_bf, b0, MLPD, nullptr, nullptr, gelu_bf, SEQ, MLPP, HID);
  gemm_bf16<1, 64><<<dim3((HID / 64) * (SEQ / 128)), blk, 0, stream>>>(
      gelu_bf, fc1_bf, b1, HID, h1, (float*)d_out, nullptr, SEQ, HID, MLPP);
}

// Round 16
// 343.239 us; speedup vs baseline: 1.2366x; 1.0003x over previous
//
#include <hip/hip_runtime.h>
#include <hip/hip_bf16.h>
#include <math.h>

typedef __hip_bfloat16 bf16;
typedef __attribute__((ext_vector_type(8))) short short8;
typedef __attribute__((ext_vector_type(4))) short short4v;
typedef __attribute__((ext_vector_type(4))) float f32x4;

#define SEQ 3072
#define HID 1152
#define NHEAD 16
#define HD 72
#define HDP 96
#define MLPD 4304
#define MLPP 4352

__device__ __forceinline__ void async_lds16(void* lds, const void* g) {
  __builtin_amdgcn_global_load_lds((const __attribute__((address_space(1))) void*)g,
                                   (__attribute__((address_space(3))) void*)lds,
                                   16, 0, 0);
}

// one v_cvt_pk_bf16_f32: a -> low16, b -> high16 (RNE)
__device__ __forceinline__ unsigned cvt_pk2(float a, float b) {
  unsigned r;
  asm("v_cvt_pk_bf16_f32 %0, %1, %2" : "=v"(r) : "v"(a), "v"(b));
  return r;
}

// raw v_exp_f32: 2^x
__device__ __forceinline__ float exp2a(float x) {
  float r;
  asm("v_exp_f32 %0, %1" : "=v"(r) : "v"(x));
  return r;
}

// bf16 pair (packed in u32) -> two floats, bit-ops only
__device__ __forceinline__ float bflo(unsigned u) { return __uint_as_float(u << 16); }
__device__ __forceinline__ float bfhi(unsigned u) { return __uint_as_float(u & 0xffff0000u); }

// ---------------- prep: LN0 (blocks < SEQ) + all weight casts (rest) ----------------
__global__ __launch_bounds__(256) void prep_k(const float* __restrict__ hidden,
                                              const float* __restrict__ ln0g,
                                              const float* __restrict__ ln0b,
                                              const float* __restrict__ wqkv,
                                              const float* __restrict__ wo,
                                              const float* __restrict__ w0,
                                              const float* __restrict__ w1,
                                              bf16* __restrict__ ln0_o,
                                              unsigned* __restrict__ wqkv_o,
                                              unsigned* __restrict__ wo_o,
                                              unsigned* __restrict__ fc0_o,
                                              unsigned* __restrict__ fc1_o) {
  if (blockIdx.x < SEQ) {
    // ---- LN0 row ----
    int row = blockIdx.x;
    const float4* xr = (const float4*)(hidden + (size_t)row * HID);
    float sum = 0.f, sq = 0.f;
    for (int c = threadIdx.x; c < HID / 4; c += 256) {
      float4 u = xr[c];
      sum += u.x + u.y + u.z + u.w;
      sq += u.x * u.x + u.y * u.y + u.z * u.z + u.w * u.w;
    }
#pragma unroll
    for (int off = 32; off > 0; off >>= 1) {
      sum += __shfl_down(sum, off, 64);
      sq += __shfl_down(sq, off, 64);
    }
    __shared__ float red[8];
    int wv = threadIdx.x >> 6;
    if ((threadIdx.x & 63) == 0) { red[wv] = sum; red[4 + wv] = sq; }
    __syncthreads();
    if (threadIdx.x == 0) {
      red[0] = red[0] + red[1] + red[2] + red[3];
      red[4] = red[4] + red[5] + red[6] + red[7];
    }
    __syncthreads();
    float mu = red[0] * (1.f / HID);
    float var = red[4] * (1.f / HID) - mu * mu;
    float inv = rsqrtf(var + 1e-5f);
    uint2* o4 = (uint2*)(ln0_o + (size_t)row * HID);
    const float4* g4 = (const float4*)ln0g;
    const float4* b4 = (const float4*)ln0b;
    for (int c = threadIdx.x; c < HID / 4; c += 256) {
      float4 u = xr[c], gg = g4[c], bb = b4[c];
      o4[c] = make_uint2(cvt_pk2((u.x - mu) * inv * gg.x + bb.x, (u.y - mu) * inv * gg.y + bb.y),
                         cvt_pk2((u.z - mu) * inv * gg.z + bb.z, (u.w - mu) * inv * gg.w + bb.w));
    }
    return;
  }
  // ---- weight casts (grid-stride over the cast blocks) ----
  const int n0 = 3 * HID * HID / 4;
  const int n1 = HID * HID / 4;
  const int n2 = MLPP * HID / 4;
  const int n3 = HID * MLPP / 4;
  const int total = n0 + n1 + n2 + n3;
  int nb = gridDim.x - SEQ;
  int stride = nb * blockDim.x;
  for (int i = (blockIdx.x - SEQ) * blockDim.x + threadIdx.x; i < total; i += stride) {
    if (i < n0) {
      float4 u = ((const float4*)wqkv)[i];
      ((uint2*)wqkv_o)[i] = make_uint2(cvt_pk2(u.x, u.y), cvt_pk2(u.z, u.w));
    } else if (i < n0 + n1) {
      int k = i - n0;
      float4 u = ((const float4*)wo)[k];
      ((uint2*)wo_o)[k] = make_uint2(cvt_pk2(u.x, u.y), cvt_pk2(u.z, u.w));
    } else if (i < n0 + n1 + n2) {
      int k = i - n0 - n1;
      int r = k / (HID / 4);
      uint2 w = make_uint2(0u, 0u);
      if (r < MLPD) {
        float4 u = ((const float4*)w0)[k];
        w = make_uint2(cvt_pk2(u.x, u.y), cvt_pk2(u.z, u.w));
      }
      ((uint2*)fc0_o)[k] = w;
    } else {
      int k = i - n0 - n1 - n2;
      int r = k / (MLPP / 4), c4 = k - r * (MLPP / 4);
      uint2 w = make_uint2(0u, 0u);
      if (c4 < MLPD / 4) {
        float4 u = ((const float4*)w1)[r * (MLPD / 4) + c4];
        w = make_uint2(cvt_pk2(u.x, u.y), cvt_pk2(u.z, u.w));
      }
      ((uint2*)fc1_o)[k] = w;
    }
  }
}

// ---------------- layernorm (fp32 in -> bf16 out) ----------------
__global__ __launch_bounds__(256) void ln_k(const float* __restrict__ x,
                                            const float* __restrict__ g,
                                            const float* __restrict__ b,
                                            bf16* __restrict__ o) {
  int row = blockIdx.x;
  const float4* xr = (const float4*)(x + (size_t)row * HID);
  float sum = 0.f, sq = 0.f;
  for (int c = threadIdx.x; c < HID / 4; c += 256) {
    float4 u = xr[c];
    sum += u.x + u.y + u.z + u.w;
    sq += u.x * u.x + u.y * u.y + u.z * u.z + u.w * u.w;
  }
#pragma unroll
  for (int off = 32; off > 0; off >>= 1) {
    sum += __shfl_down(sum, off, 64);
    sq += __shfl_down(sq, off, 64);
  }
  __shared__ float red[8];
  int wv = threadIdx.x >> 6;
  if ((threadIdx.x & 63) == 0) { red[wv] = sum; red[4 + wv] = sq; }
  __syncthreads();
  if (threadIdx.x == 0) {
    red[0] = red[0] + red[1] + red[2] + red[3];
    red[4] = red[4] + red[5] + red[6] + red[7];
  }
  __syncthreads();
  float mu = red[0] * (1.f / HID);
  float var = red[4] * (1.f / HID) - mu * mu;
  float inv = rsqrtf(var + 1e-5f);
  uint2* o4 = (uint2*)(o + (size_t)row * HID);
  const float4* g4 = (const float4*)g;
  const float4* b4 = (const float4*)b;
  for (int c = threadIdx.x; c < HID / 4; c += 256) {
    float4 u = xr[c], gg = g4[c], bb = b4[c];
    uint2 w = make_uint2(cvt_pk2((u.x - mu) * inv * gg.x + bb.x, (u.y - mu) * inv * gg.y + bb.y),
                         cvt_pk2((u.z - mu) * inv * gg.z + bb.z, (u.w - mu) * inv * gg.w + bb.w));
    o4[c] = w;
  }
}

// ---------------- GEMM: C[M][N] = A[M][K] @ Bt[N][K]^T  (+ epilogue) ----------------
// 3 LDS buffers, depth-2 prefetch, counted vmcnt, bijective XCD swizzle,
// LDS chunk XOR-swizzle (linear dst + inverse-swz source + swz read).
// BN=128: 4 waves 2x2, wave tile 64x64 (acc 4x4). BN=64: wave tile 64x32.
// EPI 0: +bias -> bf16   1: +bias+res -> fp32   2: +bias, gelu -> bf16
template <int EPI, int BN>
__global__ __launch_bounds__(256) void gemm_bf16(const bf16* __restrict__ A,
                                                 const bf16* __restrict__ Bt,
                                                 const float* __restrict__ bias, int nbias,
                                                 const float* __restrict__ res,
                                                 float* __restrict__ outf,
                                                 bf16* __restrict__ outb,
                                                 int M, int N, int K) {
  constexpr int NFR = (BN == 128) ? 4 : 2;  // B frags per wave
  __shared__ bf16 As[3][128 * 32];
  __shared__ bf16 Bs[3][BN * 32];
  const int t = threadIdx.x;
  const int l = t & 63;
  const int w = t >> 6;
  const int wr = w >> 1, wc = w & 1;
  const int lrow = l & 15;
  // swizzled read chunk: g ^ xs, xs = (lrow>>1)&3
  const int lks = (((l >> 4) ^ ((lrow >> 1) & 3)) & 3) * 8;
  const int wg = (blockIdx.x & 7) * (gridDim.x >> 3) + (blockIdx.x >> 3);
  const int gyt = M >> 7;
  const int xt = wg / gyt;
  const int yt = wg - xt * gyt;
  const int m0 = yt * 128;
  const int n0 = xt * BN;
  const int arow = t >> 2;
  // swizzled source chunk: (t&3) ^ ((t>>3)&3)
  const int ach = (((t & 3) ^ ((t >> 3) & 3)) & 3) * 8;

  const bf16* pa0 = &A[(size_t)(m0 + arow) * K + ach];
  const bf16* pa1 = &A[(size_t)(m0 + arow + 64) * K + ach];
  const bf16* pb0 = &Bt[(size_t)(n0 + arow) * K + ach];
  const bf16* pb1 = (BN == 128) ? &Bt[(size_t)(n0 + arow + 64) * K + ach] : pb0;
  auto STAGE = [&](int buf, int kt) {
    size_t off = (size_t)kt * 32;
    async_lds16(&As[buf][t * 8], pa0 + off);
    async_lds16(&As[buf][(256 + t) * 8], pa1 + off);
    async_lds16(&Bs[buf][t * 8], pb0 + off);
    if constexpr (BN == 128) async_lds16(&Bs[buf][(256 + t) * 8], pb1 + off);
  };

  f32x4 acc[4][NFR] = {};
  const int nkt = K >> 5;
  STAGE(0, 0);
  STAGE(1, 1);
  int bcur = 0;
  for (int kt = 0; kt < nkt; ++kt) {
    if (kt + 1 < nkt) {
      if constexpr (BN == 128)
        asm volatile("s_waitcnt vmcnt(4)" ::: "memory");  // stage kt landed; kt+1 in flight
      else
        asm volatile("s_waitcnt vmcnt(3)" ::: "memory");
    } else {
      asm volatile("s_waitcnt vmcnt(0)" ::: "memory");
    }
    __builtin_amdgcn_s_barrier();
    int bn2 = bcur + 2;
    if (bn2 >= 3) bn2 -= 3;
    if (kt + 2 < nkt) STAGE(bn2, kt + 2);

    short8 af[4], bfr[NFR];
#pragma unroll
    for (int i = 0; i < 4; ++i)
      af[i] = *(const short8*)&As[bcur][(wr * 64 + i * 16 + lrow) * 32 + lks];
#pragma unroll
    for (int j = 0; j < NFR; ++j)
      bfr[j] = *(const short8*)&Bs[bcur][(wc * (BN >> 1) + j * 16 + lrow) * 32 + lks];
    __builtin_amdgcn_s_setprio(1);
#pragma unroll
    for (int i = 0; i < 4; ++i)
#pragma unroll
      for (int j = 0; j < NFR; ++j)
        acc[i][j] = __builtin_amdgcn_mfma_f32_16x16x32_bf16(af[i], bfr[j], acc[i][j], 0, 0, 0);
    __builtin_amdgcn_s_setprio(0);
    ++bcur;
    if (bcur == 3) bcur = 0;
  }

#pragma unroll
  for (int i = 0; i < 4; ++i) {
    int rowb = m0 + wr * 64 + i * 16 + (l >> 4) * 4;
#pragma unroll
    for (int j = 0; j < NFR; ++j) {
      int col = n0 + wc * (BN >> 1) + j * 16 + lrow;
      float bv = (col < nbias) ? bias[col] : 0.f;
#pragma unroll
      for (int r2 = 0; r2 < 4; ++r2) {
        size_t idx = (size_t)(rowb + r2) * N + col;
        float v = acc[i][j][r2] + bv;
        if (EPI == 0) {
          outb[idx] = __float2bfloat16(v);
        } else if (EPI == 1) {
          outf[idx] = v + res[idx];
        } else {
          float u = 0.7978845608028654f * (v + 0.044715f * v * v * v);
          u = fminf(fmaxf(u, -15.f), 15.f);
          float tt = __expf(2.f * u);
          outb[idx] = __float2bfloat16(v * tt / (tt + 1.f));
        }
      }
    }
  }
}

// ---------------- rope + qkv split (xqkv bf16) ----------------
// q scale folds log2(e) so flash softmax runs in exp2 domain.
// vt row d=72 is set to 1.0: PV's MFMA then computes the softmax denominator l
// for free in the d=72 accumulator slot (flash "ones-row" trick).
__global__ __launch_bounds__(256) void rope_split(const bf16* __restrict__ xqkv,
                                                  const float* __restrict__ cosb,
                                                  const float* __restrict__ sinb,
                                                  bf16* __restrict__ qp,
                                                  bf16* __restrict__ kp,
                                                  bf16* __restrict__ vt) {
  __shared__ bf16 vl[64][72];
  const int t = threadIdx.x;
  const int h = blockIdx.y;
  const int s0 = blockIdx.x * 64;
  const float scale = 0.17002445f;  // (1/sqrt(72)) * log2(e)
  for (int idx = t; idx < 64 * 48; idx += 256) {
    int sl = idx / 48, pi = idx - sl * 48;
    int srow = s0 + sl;
    size_t obase = ((size_t)h * SEQ + srow) * HDP + 2 * pi;
    if (pi < 36) {
      const bf16* xr = xqkv + (size_t)srow * (3 * HID) + h * HD + 2 * pi;
      unsigned qw = *(const unsigned*)xr;
      unsigned kw = *(const unsigned*)(xr + HID);
      float qr = bflo(qw), qi = bfhi(qw);
      float kr = bflo(kw), ki = bfhi(kw);
      float c = cosb[srow * 36 + pi], sn = sinb[srow * 36 + pi];
      *(unsigned*)&qp[obase] = cvt_pk2((qr * c - qi * sn) * scale, (qr * sn + qi * c) * scale);
      *(unsigned*)&kp[obase] = cvt_pk2(kr * c - ki * sn, kr * sn + ki * c);
    } else {
      *(unsigned*)&qp[obase] = 0u;
      *(unsigned*)&kp[obase] = 0u;
    }
  }
  for (int idx = t; idx < 64 * 72; idx += 256) {
    int sl = idx / 72, d = idx - sl * 72;
    vl[sl][d] = xqkv[(size_t)(s0 + sl) * (3 * HID) + 2 * HID + h * HD + d];
  }
  __syncthreads();
  bf16 z = __float2bfloat16(0.f);
  bf16 one = __float2bfloat16(1.f);
  for (int idx = t; idx < HDP * 64; idx += 256) {
    int d = idx / 64, sl = idx - d * 64;
    vt[((size_t)h * HDP + d) * SEQ + s0 + sl] = (d < 72) ? vl[sl][d] : ((d == 72) ? one : z);
  }
}

// ---------------- flash attention (KVBLK=32, 4 waves, 40KB) ----------------
// Triple-buffered KV, QK(t+1)-ahead, swapped operands (lane-local softmax),
// exp2-domain, defer-max THR=8*log2(e)=11.54. Softmax denominator l comes from
// the V ones-row (d=72) accumulator — no per-tile l accumulation needed; the
// defer-max rescale of oa[] rescales l automatically. Grid 768 = 3 blocks/CU.
// NOTE: must drain vmcnt(0) before exit (wrapped tail stages; R13 race).
__global__ __launch_bounds__(256) void flash_attn(const bf16* __restrict__ q,
                                                  const bf16* __restrict__ kk,
                                                  const bf16* __restrict__ vT,
                                                  bf16* __restrict__ o) {
  __shared__ alignas(16) bf16 KV3[3 * 6144];
  __shared__ alignas(16) bf16 Pl[4][512];
  const int t = threadIdx.x;
  const int l = t & 63;
  const int w = t >> 6;
  const int g = l >> 4;
  const int lrow = l & 15;
  const int bid = blockIdx.x;
  const int kq = bid >> 3;
  const int h = (bid & 7) * 2 + (kq & 1);
  const int q0 = (kq >> 1) * 64 + w * 16;
  const int NT = SEQ / 32;

  const bf16* sbase[3];
  int smul[3];
#pragma unroll
  for (int i = 0; i < 3; ++i) {
    int s = t + i * 256;
    if (s < 384) {
      int cb = s >> 5, kv = s & 31;
      sbase[i] = kk + ((size_t)h * SEQ + kv) * HDP + cb * 8;
      smul[i] = 32 * HDP;
    } else {
      int vs = s - 384;
      int cb = vs / 96, d = vs - cb * 96;
      sbase[i] = vT + ((size_t)h * HDP + d) * SEQ + cb * 8;
      smul[i] = 32;
    }
  }
  auto STAGE = [&](int tile, int bufOff) {
#pragma unroll
    for (int i = 0; i < 3; ++i)
      async_lds16(&KV3[bufOff + (t + i * 256) * 8], sbase[i] + (size_t)tile * smul[i]);
  };

  short8 qf[3];
#pragma unroll
  for (int f = 0; f < 3; ++f)
    qf[f] = *(const short8*)&q[((size_t)h * SEQ + q0 + lrow) * HDP + f * 32 + g * 8];

  float m_r = -1e30f;
  f32x4 oa[5] = {};

  STAGE(0, 0);
  STAGE(1, 6144);
  STAGE(2, 12288);
  asm volatile("s_waitcnt vmcnt(6)" ::: "memory");
  __builtin_amdgcn_s_barrier();

  f32x4 stA[2] = {}, stB[2];
  int b0 = 0;
#pragma unroll
  for (int nf = 0; nf < 2; ++nf)
#pragma unroll
    for (int f = 0; f < 3; ++f) {
      short8 kfrag = *(const short8*)&KV3[0 + (f * 4 + g) * 256 + (nf * 16 + lrow) * 8];
      stA[nf] = __builtin_amdgcn_mfma_f32_16x16x32_bf16(kfrag, qf[f], stA[nf], 0, 0, 0);
    }

#pragma unroll 3
  for (int kt = 0; kt < NT - 1; ++kt) {
    int b1 = b0 + 6144;
    if (b1 == 18432) b1 = 0;
    asm volatile("s_waitcnt vmcnt(3)" ::: "memory");
    __builtin_amdgcn_s_barrier();

    // QK(kt+1) from b1 (independent of softmax(kt) below)
    stB[0] = (f32x4){0.f, 0.f, 0.f, 0.f};
    stB[1] = (f32x4){0.f, 0.f, 0.f, 0.f};
    __builtin_amdgcn_s_setprio(1);
#pragma unroll
    for (int nf = 0; nf < 2; ++nf)
#pragma unroll
      for (int f = 0; f < 3; ++f) {
        short8 kfrag = *(const short8*)&KV3[b1 + (f * 4 + g) * 256 + (nf * 16 + lrow) * 8];
        stB[nf] = __builtin_amdgcn_mfma_f32_16x16x32_bf16(kfrag, qf[f], stB[nf], 0, 0, 0);
      }
    __builtin_amdgcn_s_setprio(0);

    // softmax(kt): defer-max (exp2 domain); l comes from PV ones-row
    float pmax = fmaxf(fmaxf(fmaxf(stA[0][0], stA[0][1]), fmaxf(stA[0][2], stA[0][3])),
                       fmaxf(fmaxf(stA[1][0], stA[1][1]), fmaxf(stA[1][2], stA[1][3])));
    if (!__all(pmax - m_r <= 11.54f)) {
      float rm = pmax;
      rm = fmaxf(rm, __shfl_xor(rm, 16, 64));
      rm = fmaxf(rm, __shfl_xor(rm, 32, 64));
      float mn = fmaxf(m_r, rm);
      float alpha = exp2a(m_r - mn);
#pragma unroll
      for (int nf = 0; nf < 5; ++nf)
#pragma unroll
        for (int r = 0; r < 4; ++r) oa[nf][r] *= alpha;
      m_r = mn;
    }
#pragma unroll
    for (int nf = 0; nf < 2; ++nf)
#pragma unroll
      for (int r = 0; r < 4; ++r) stA[nf][r] = exp2a(stA[nf][r] - m_r);

    // P write: kv = nf*16+g*4+r, q=lrow -> elem = (2nf+(g>>1))*128 + lrow*8 + (g&1)*4
#pragma unroll
    for (int nf = 0; nf < 2; ++nf) {
      uint2* dst = (uint2*)&Pl[w][(2 * nf + (g >> 1)) * 128 + lrow * 8 + (g & 1) * 4];
      *dst = make_uint2(cvt_pk2(stA[nf][0], stA[nf][1]), cvt_pk2(stA[nf][2], stA[nf][3]));
    }

    // PV(kt) from b0: O^T += V' x P'  (d=72 row of V is ones -> accumulates l)
    {
      short8 pa = *(const short8*)&Pl[w][g * 128 + lrow * 8];
      __builtin_amdgcn_s_setprio(1);
#pragma unroll
      for (int nf = 0; nf < 5; ++nf) {
        short8 bv = *(const short8*)&KV3[b0 + 3072 + g * 768 + (nf * 16 + lrow) * 8];
        oa[nf] = __builtin_amdgcn_mfma_f32_16x16x32_bf16(bv, pa, oa[nf], 0, 0, 0);
      }
      __builtin_amdgcn_s_setprio(0);
    }

    asm volatile("s_waitcnt lgkmcnt(0)" ::: "memory");
    __builtin_amdgcn_s_barrier();
    int s = kt + 3;
    if (s >= NT) s -= NT;
    STAGE(s, b0);
    stA[0] = stB[0];
    stA[1] = stB[1];
    b0 = b1;
  }

  // epilogue tile NT-1
  {
    float pmax = fmaxf(fmaxf(fmaxf(stA[0][0], stA[0][1]), fmaxf(stA[0][2], stA[0][3])),
                       fmaxf(fmaxf(stA[1][0], stA[1][1]), fmaxf(stA[1][2], stA[1][3])));
    if (!__all(pmax - m_r <= 11.54f)) {
      float rm = pmax;
      rm = fmaxf(rm, __shfl_xor(rm, 16, 64));
      rm = fmaxf(rm, __shfl_xor(rm, 32, 64));
      float mn = fmaxf(m_r, rm);
      float alpha = exp2a(m_r - mn);
#pragma unroll
      for (int nf = 0; nf < 5; ++nf)
#pragma unroll
        for (int r = 0; r < 4; ++r) oa[nf][r] *= alpha;
      m_r = mn;
    }
#pragma unroll
    for (int nf = 0; nf < 2; ++nf)
#pragma unroll
      for (int r = 0; r < 4; ++r) stA[nf][r] = exp2a(stA[nf][r] - m_r);
#pragma unroll
    for (int nf = 0; nf < 2; ++nf) {
      uint2* dst = (uint2*)&Pl[w][(2 * nf + (g >> 1)) * 128 + lrow * 8 + (g & 1) * 4];
      *dst = make_uint2(cvt_pk2(stA[nf][0], stA[nf][1]), cvt_pk2(stA[nf][2], stA[nf][3]));
    }
    short8 pa = *(const short8*)&Pl[w][g * 128 + lrow * 8];
#pragma unroll
    for (int nf = 0; nf < 5; ++nf) {
      short8 bv = *(const short8*)&KV3[b0 + 3072 + g * 768 + (nf * 16 + lrow) * 8];
      oa[nf] = __builtin_amdgcn_mfma_f32_16x16x32_bf16(bv, pa, oa[nf], 0, 0, 0);
    }
  }

  // drain stale wrapped stages BEFORE exit (see kernel comment)
  asm volatile("s_waitcnt vmcnt(0)" ::: "memory");

  // l lives in oa[4][0] of lane group g=2 (d=72): broadcast from lane 32+lrow
  float lt = __shfl(oa[4][0], 32 + lrow, 64);
  float rcp = 1.f / lt;
  size_t obase = (size_t)(q0 + lrow) * HID + h * HD;
#pragma unroll
  for (int nf = 0; nf < 5; ++nf) {
    int d = nf * 16 + g * 4;
    if (d + 3 < HD) {
      uint2 pk = make_uint2(cvt_pk2(oa[nf][0] * rcp, oa[nf][1] * rcp),
                            cvt_pk2(oa[nf][2] * rcp, oa[nf][3] * rcp));
      *(uint2*)&o[obase + d] = pk;
    }
  }
}

// ---------------- launch ----------------
extern "C" void kernel_launch(void* const* d_in, const int* in_sizes, int n_in,
                              void* d_out, int out_size, void* d_ws, size_t ws_size,
                              hipStream_t stream) {
  (void)in_sizes; (void)n_in; (void)out_size;
  const float* hidden = (const float*)d_in[0];
  const float* cosb = (const float*)d_in[1];
  const float* sinb = (const float*)d_in[2];
  const float* ln0g = (const float*)d_in[3];
  const float* ln0b = (const float*)d_in[4];
  const float* ln1g = (const float*)d_in[5];
  const float* ln1b = (const float*)d_in[6];
  const float* wqkv = (const float*)d_in[7];
  const float* bqkv = (const float*)d_in[8];
  const float* wo = (const float*)d_in[9];
  const float* bo = (const float*)d_in[10];
  const float* w0 = (const float*)d_in[11];
  const float* b0 = (const float*)d_in[12];
  const float* w1 = (const float*)d_in[13];
  const float* b1 = (const float*)d_in[14];

  char* p = (char*)d_ws;
  auto alloc = [&](size_t n) {
    char* r = p;
    p += (n + 255) & ~(size_t)255;
    return r;
  };
  bf16* wqkv_bf = (bf16*)alloc((size_t)3 * HID * HID * 2);
  bf16* wo_bf = (bf16*)alloc((size_t)HID * HID * 2);
  bf16* fc0_bf = (bf16*)alloc((size_t)MLPP * HID * 2);
  bf16* fc1_bf = (bf16*)alloc((size_t)HID * MLPP * 2);
  bf16* ln0_bf = (bf16*)alloc((size_t)SEQ * HID * 2);
  bf16* xqkv = (bf16*)alloc((size_t)SEQ * 3 * HID * 2);
  bf16* qp = (bf16*)alloc((size_t)NHEAD * SEQ * HDP * 2);
  bf16* kp = (bf16*)alloc((size_t)NHEAD * SEQ * HDP * 2);
  bf16* vt = (bf16*)alloc((size_t)NHEAD * HDP * SEQ * 2);
  bf16* attn_bf = (bf16*)alloc((size_t)SEQ * HID * 2);
  float* h1 = (float*)alloc((size_t)SEQ * HID * 4);
  bf16* ln1_bf = (bf16*)alloc((size_t)SEQ * HID * 2);
  bf16* gelu_bf = (bf16*)alloc((size_t)SEQ * MLPP * 2);
  if ((size_t)(p - (char*)d_ws) > ws_size) return;

  dim3 blk(256);
  prep_k<<<SEQ + 1024, blk, 0, stream>>>(hidden, ln0g, ln0b, wqkv, wo, w0, w1, ln0_bf,
                                         (unsigned*)wqkv_bf, (unsigned*)wo_bf,
                                         (unsigned*)fc0_bf, (unsigned*)fc1_bf);
  gemm_bf16<0, 128><<<dim3((3 * HID / 128) * (SEQ / 128)), blk, 0, stream>>>(
      ln0_bf, wqkv_bf, bqkv, 3 * HID, nullptr, nullptr, xqkv, SEQ, 3 * HID, HID);
  rope_split<<<dim3(SEQ / 64, NHEAD), blk, 0, stream>>>(xqkv, cosb, sinb, qp, kp, vt);
  flash_attn<<<dim3(768), blk, 0, stream>>>(qp, kp, vt, attn_bf);
  gemm_bf16<1, 64><<<dim3((HID / 64) * (SEQ / 128)), blk, 0, stream>>>(
      attn_bf, wo_bf, bo, HID, hidden, h1, nullptr, SEQ, HID, HID);
  ln_k<<<SEQ, blk, 0, stream>>>(h1, ln1g, ln1b, ln1_bf);
  gemm_bf16<2, 128><<<dim3((MLPP / 128) * (SEQ / 128)), blk, 0, stream>>>(
      ln1_bf, fc0_bf, b0, MLPD, nullptr, nullptr, gelu_bf, SEQ, MLPP, HID);
  gemm_bf16<1, 64><<<dim3((HID / 64) * (SEQ / 128)), blk, 0, stream>>>(
      gelu_bf, fc1_bf, b1, HID, h1, (float*)d_out, nullptr, SEQ, HID, MLPP);
}

// Round 17
// 339.253 us; speedup vs baseline: 1.2511x; 1.0117x over previous
//
#include <hip/hip_runtime.h>
#include <hip/hip_bf16.h>
#include <math.h>

typedef __hip_bfloat16 bf16;
typedef __attribute__((ext_vector_type(8))) short short8;
typedef __attribute__((ext_vector_type(4))) short short4v;
typedef __attribute__((ext_vector_type(4))) float f32x4;

#define SEQ 3072
#define HID 1152
#define NHEAD 16
#define HD 72
#define HDP 96
#define MLPD 4304
#define MLPP 4352

__device__ __forceinline__ void async_lds16(void* lds, const void* g) {
  __builtin_amdgcn_global_load_lds((const __attribute__((address_space(1))) void*)g,
                                   (__attribute__((address_space(3))) void*)lds,
                                   16, 0, 0);
}

// one v_cvt_pk_bf16_f32: a -> low16, b -> high16 (RNE)
__device__ __forceinline__ unsigned cvt_pk2(float a, float b) {
  unsigned r;
  asm("v_cvt_pk_bf16_f32 %0, %1, %2" : "=v"(r) : "v"(a), "v"(b));
  return r;
}

// raw v_exp_f32: 2^x
__device__ __forceinline__ float exp2a(float x) {
  float r;
  asm("v_exp_f32 %0, %1" : "=v"(r) : "v"(x));
  return r;
}

// bf16 pair (packed in u32) -> two floats, bit-ops only
__device__ __forceinline__ float bflo(unsigned u) { return __uint_as_float(u << 16); }
__device__ __forceinline__ float bfhi(unsigned u) { return __uint_as_float(u & 0xffff0000u); }

// ---------------- prep: LN0 (blocks < SEQ) + all weight casts (rest) ----------------
__global__ __launch_bounds__(256) void prep_k(const float* __restrict__ hidden,
                                              const float* __restrict__ ln0g,
                                              const float* __restrict__ ln0b,
                                              const float* __restrict__ wqkv,
                                              const float* __restrict__ wo,
                                              const float* __restrict__ w0,
                                              const float* __restrict__ w1,
                                              bf16* __restrict__ ln0_o,
                                              unsigned* __restrict__ wqkv_o,
                                              unsigned* __restrict__ wo_o,
                                              unsigned* __restrict__ fc0_o,
                                              unsigned* __restrict__ fc1_o) {
  if (blockIdx.x < SEQ) {
    // ---- LN0 row ----
    int row = blockIdx.x;
    const float4* xr = (const float4*)(hidden + (size_t)row * HID);
    float sum = 0.f, sq = 0.f;
    for (int c = threadIdx.x; c < HID / 4; c += 256) {
      float4 u = xr[c];
      sum += u.x + u.y + u.z + u.w;
      sq += u.x * u.x + u.y * u.y + u.z * u.z + u.w * u.w;
    }
#pragma unroll
    for (int off = 32; off > 0; off >>= 1) {
      sum += __shfl_down(sum, off, 64);
      sq += __shfl_down(sq, off, 64);
    }
    __shared__ float red[8];
    int wv = threadIdx.x >> 6;
    if ((threadIdx.x & 63) == 0) { red[wv] = sum; red[4 + wv] = sq; }
    __syncthreads();
    if (threadIdx.x == 0) {
      red[0] = red[0] + red[1] + red[2] + red[3];
      red[4] = red[4] + red[5] + red[6] + red[7];
    }
    __syncthreads();
    float mu = red[0] * (1.f / HID);
    float var = red[4] * (1.f / HID) - mu * mu;
    float inv = rsqrtf(var + 1e-5f);
    uint2* o4 = (uint2*)(ln0_o + (size_t)row * HID);
    const float4* g4 = (const float4*)ln0g;
    const float4* b4 = (const float4*)ln0b;
    for (int c = threadIdx.x; c < HID / 4; c += 256) {
      float4 u = xr[c], gg = g4[c], bb = b4[c];
      o4[c] = make_uint2(cvt_pk2((u.x - mu) * inv * gg.x + bb.x, (u.y - mu) * inv * gg.y + bb.y),
                         cvt_pk2((u.z - mu) * inv * gg.z + bb.z, (u.w - mu) * inv * gg.w + bb.w));
    }
    return;
  }
  // ---- weight casts (grid-stride over the cast blocks) ----
  const int n0 = 3 * HID * HID / 4;
  const int n1 = HID * HID / 4;
  const int n2 = MLPP * HID / 4;
  const int n3 = HID * MLPP / 4;
  const int total = n0 + n1 + n2 + n3;
  int nb = gridDim.x - SEQ;
  int stride = nb * blockDim.x;
  for (int i = (blockIdx.x - SEQ) * blockDim.x + threadIdx.x; i < total; i += stride) {
    if (i < n0) {
      float4 u = ((const float4*)wqkv)[i];
      ((uint2*)wqkv_o)[i] = make_uint2(cvt_pk2(u.x, u.y), cvt_pk2(u.z, u.w));
    } else if (i < n0 + n1) {
      int k = i - n0;
      float4 u = ((const float4*)wo)[k];
      ((uint2*)wo_o)[k] = make_uint2(cvt_pk2(u.x, u.y), cvt_pk2(u.z, u.w));
    } else if (i < n0 + n1 + n2) {
      int k = i - n0 - n1;
      int r = k / (HID / 4);
      uint2 w = make_uint2(0u, 0u);
      if (r < MLPD) {
        float4 u = ((const float4*)w0)[k];
        w = make_uint2(cvt_pk2(u.x, u.y), cvt_pk2(u.z, u.w));
      }
      ((uint2*)fc0_o)[k] = w;
    } else {
      int k = i - n0 - n1 - n2;
      int r = k / (MLPP / 4), c4 = k - r * (MLPP / 4);
      uint2 w = make_uint2(0u, 0u);
      if (c4 < MLPD / 4) {
        float4 u = ((const float4*)w1)[r * (MLPD / 4) + c4];
        w = make_uint2(cvt_pk2(u.x, u.y), cvt_pk2(u.z, u.w));
      }
      ((uint2*)fc1_o)[k] = w;
    }
  }
}

// ---------------- layernorm (fp32 in -> bf16 out) ----------------
__global__ __launch_bounds__(256) void ln_k(const float* __restrict__ x,
                                            const float* __restrict__ g,
                                            const float* __restrict__ b,
                                            bf16* __restrict__ o) {
  int row = blockIdx.x;
  const float4* xr = (const float4*)(x + (size_t)row * HID);
  float sum = 0.f, sq = 0.f;
  for (int c = threadIdx.x; c < HID / 4; c += 256) {
    float4 u = xr[c];
    sum += u.x + u.y + u.z + u.w;
    sq += u.x * u.x + u.y * u.y + u.z * u.z + u.w * u.w;
  }
#pragma unroll
  for (int off = 32; off > 0; off >>= 1) {
    sum += __shfl_down(sum, off, 64);
    sq += __shfl_down(sq, off, 64);
  }
  __shared__ float red[8];
  int wv = threadIdx.x >> 6;
  if ((threadIdx.x & 63) == 0) { red[wv] = sum; red[4 + wv] = sq; }
  __syncthreads();
  if (threadIdx.x == 0) {
    red[0] = red[0] + red[1] + red[2] + red[3];
    red[4] = red[4] + red[5] + red[6] + red[7];
  }
  __syncthreads();
  float mu = red[0] * (1.f / HID);
  float var = red[4] * (1.f / HID) - mu * mu;
  float inv = rsqrtf(var + 1e-5f);
  uint2* o4 = (uint2*)(o + (size_t)row * HID);
  const float4* g4 = (const float4*)g;
  const float4* b4 = (const float4*)b;
  for (int c = threadIdx.x; c < HID / 4; c += 256) {
    float4 u = xr[c], gg = g4[c], bb = b4[c];
    uint2 w = make_uint2(cvt_pk2((u.x - mu) * inv * gg.x + bb.x, (u.y - mu) * inv * gg.y + bb.y),
                         cvt_pk2((u.z - mu) * inv * gg.z + bb.z, (u.w - mu) * inv * gg.w + bb.w));
    o4[c] = w;
  }
}

// ---------------- GEMM: C[M][N] = A[M][K] @ Bt[N][K]^T  (+ epilogue) ----------------
// 3 LDS buffers, depth-2 prefetch, counted vmcnt, bijective XCD swizzle,
// LDS chunk XOR-swizzle (linear dst + inverse-swz source + swz read).
// BN=128: 4 waves 2x2, wave tile 64x64 (acc 4x4). BN=64: wave tile 64x32.
// EPI 0: +bias -> bf16   1: +bias+res -> fp32   2: +bias, gelu -> bf16
template <int EPI, int BN>
__global__ __launch_bounds__(256) void gemm_bf16(const bf16* __restrict__ A,
                                                 const bf16* __restrict__ Bt,
                                                 const float* __restrict__ bias, int nbias,
                                                 const float* __restrict__ res,
                                                 float* __restrict__ outf,
                                                 bf16* __restrict__ outb,
                                                 int M, int N, int K) {
  constexpr int NFR = (BN == 128) ? 4 : 2;  // B frags per wave
  __shared__ bf16 As[3][128 * 32];
  __shared__ bf16 Bs[3][BN * 32];
  const int t = threadIdx.x;
  const int l = t & 63;
  const int w = t >> 6;
  const int wr = w >> 1, wc = w & 1;
  const int lrow = l & 15;
  // swizzled read chunk: g ^ xs, xs = (lrow>>1)&3
  const int lks = (((l >> 4) ^ ((lrow >> 1) & 3)) & 3) * 8;
  const int wg = (blockIdx.x & 7) * (gridDim.x >> 3) + (blockIdx.x >> 3);
  const int gyt = M >> 7;
  const int xt = wg / gyt;
  const int yt = wg - xt * gyt;
  const int m0 = yt * 128;
  const int n0 = xt * BN;
  const int arow = t >> 2;
  // swizzled source chunk: (t&3) ^ ((t>>3)&3)
  const int ach = (((t & 3) ^ ((t >> 3) & 3)) & 3) * 8;

  const bf16* pa0 = &A[(size_t)(m0 + arow) * K + ach];
  const bf16* pa1 = &A[(size_t)(m0 + arow + 64) * K + ach];
  const bf16* pb0 = &Bt[(size_t)(n0 + arow) * K + ach];
  const bf16* pb1 = (BN == 128) ? &Bt[(size_t)(n0 + arow + 64) * K + ach] : pb0;
  auto STAGE = [&](int buf, int kt) {
    size_t off = (size_t)kt * 32;
    async_lds16(&As[buf][t * 8], pa0 + off);
    async_lds16(&As[buf][(256 + t) * 8], pa1 + off);
    async_lds16(&Bs[buf][t * 8], pb0 + off);
    if constexpr (BN == 128) async_lds16(&Bs[buf][(256 + t) * 8], pb1 + off);
  };

  f32x4 acc[4][NFR] = {};
  const int nkt = K >> 5;
  STAGE(0, 0);
  STAGE(1, 1);
  int bcur = 0;
  for (int kt = 0; kt < nkt; ++kt) {
    if (kt + 1 < nkt) {
      if constexpr (BN == 128)
        asm volatile("s_waitcnt vmcnt(4)" ::: "memory");  // stage kt landed; kt+1 in flight
      else
        asm volatile("s_waitcnt vmcnt(3)" ::: "memory");
    } else {
      asm volatile("s_waitcnt vmcnt(0)" ::: "memory");
    }
    __builtin_amdgcn_s_barrier();
    int bn2 = bcur + 2;
    if (bn2 >= 3) bn2 -= 3;
    if (kt + 2 < nkt) STAGE(bn2, kt + 2);

    short8 af[4], bfr[NFR];
#pragma unroll
    for (int i = 0; i < 4; ++i)
      af[i] = *(const short8*)&As[bcur][(wr * 64 + i * 16 + lrow) * 32 + lks];
#pragma unroll
    for (int j = 0; j < NFR; ++j)
      bfr[j] = *(const short8*)&Bs[bcur][(wc * (BN >> 1) + j * 16 + lrow) * 32 + lks];
    __builtin_amdgcn_s_setprio(1);
#pragma unroll
    for (int i = 0; i < 4; ++i)
#pragma unroll
      for (int j = 0; j < NFR; ++j)
        acc[i][j] = __builtin_amdgcn_mfma_f32_16x16x32_bf16(af[i], bfr[j], acc[i][j], 0, 0, 0);
    __builtin_amdgcn_s_setprio(0);
    ++bcur;
    if (bcur == 3) bcur = 0;
  }

#pragma unroll
  for (int i = 0; i < 4; ++i) {
    int rowb = m0 + wr * 64 + i * 16 + (l >> 4) * 4;
#pragma unroll
    for (int j = 0; j < NFR; ++j) {
      int col = n0 + wc * (BN >> 1) + j * 16 + lrow;
      float bv = (col < nbias) ? bias[col] : 0.f;
#pragma unroll
      for (int r2 = 0; r2 < 4; ++r2) {
        size_t idx = (size_t)(rowb + r2) * N + col;
        float v = acc[i][j][r2] + bv;
        if (EPI == 0) {
          outb[idx] = __float2bfloat16(v);
        } else if (EPI == 1) {
          outf[idx] = v + res[idx];
        } else {
          float u = 0.7978845608028654f * (v + 0.044715f * v * v * v);
          u = fminf(fmaxf(u, -15.f), 15.f);
          float tt = __expf(2.f * u);
          outb[idx] = __float2bfloat16(v * tt / (tt + 1.f));
        }
      }
    }
  }
}

// ---------------- rope + qkv split (xqkv bf16) ----------------
// q scale folds log2(e) so flash softmax runs in exp2 domain.
// vt row d=72 is set to 1.0: PV's MFMA then computes the softmax denominator l
// for free in the d=72 accumulator slot (flash "ones-row" trick).
__global__ __launch_bounds__(256) void rope_split(const bf16* __restrict__ xqkv,
                                                  const float* __restrict__ cosb,
                                                  const float* __restrict__ sinb,
                                                  bf16* __restrict__ qp,
                                                  bf16* __restrict__ kp,
                                                  bf16* __restrict__ vt) {
  __shared__ bf16 vl[64][72];
  const int t = threadIdx.x;
  const int h = blockIdx.y;
  const int s0 = blockIdx.x * 64;
  const float scale = 0.17002445f;  // (1/sqrt(72)) * log2(e)
  for (int idx = t; idx < 64 * 48; idx += 256) {
    int sl = idx / 48, pi = idx - sl * 48;
    int srow = s0 + sl;
    size_t obase = ((size_t)h * SEQ + srow) * HDP + 2 * pi;
    if (pi < 36) {
      const bf16* xr = xqkv + (size_t)srow * (3 * HID) + h * HD + 2 * pi;
      unsigned qw = *(const unsigned*)xr;
      unsigned kw = *(const unsigned*)(xr + HID);
      float qr = bflo(qw), qi = bfhi(qw);
      float kr = bflo(kw), ki = bfhi(kw);
      float c = cosb[srow * 36 + pi], sn = sinb[srow * 36 + pi];
      *(unsigned*)&qp[obase] = cvt_pk2((qr * c - qi * sn) * scale, (qr * sn + qi * c) * scale);
      *(unsigned*)&kp[obase] = cvt_pk2(kr * c - ki * sn, kr * sn + ki * c);
    } else {
      *(unsigned*)&qp[obase] = 0u;
      *(unsigned*)&kp[obase] = 0u;
    }
  }
  for (int idx = t; idx < 64 * 72; idx += 256) {
    int sl = idx / 72, d = idx - sl * 72;
    vl[sl][d] = xqkv[(size_t)(s0 + sl) * (3 * HID) + 2 * HID + h * HD + d];
  }
  __syncthreads();
  bf16 z = __float2bfloat16(0.f);
  bf16 one = __float2bfloat16(1.f);
  for (int idx = t; idx < HDP * 64; idx += 256) {
    int d = idx / 64, sl = idx - d * 64;
    vt[((size_t)h * HDP + d) * SEQ + s0 + sl] = (d < 72) ? vl[sl][d] : ((d == 72) ? one : z);
  }
}

// ---------------- flash attention (KVBLK=32, 4 waves, 40KB) ----------------
// Triple-buffered KV, QK(t+1)-ahead, swapped operands (lane-local softmax),
// exp2-domain, defer-max THR=8*log2(e)=11.54. Softmax denominator l comes from
// the V ones-row (d=72) accumulator — no per-tile l accumulation; defer-max's
// oa rescale covers l automatically. NO manual unroll (R16 lesson: unrolling
// across barriers defeats the compiler's interleave; VGPR 56->64, -16% perf).
// Grid 768 = 3 blocks/CU. Must drain vmcnt(0) before exit (R13 race).
__global__ __launch_bounds__(256) void flash_attn(const bf16* __restrict__ q,
                                                  const bf16* __restrict__ kk,
                                                  const bf16* __restrict__ vT,
                                                  bf16* __restrict__ o) {
  __shared__ alignas(16) bf16 KV3[3 * 6144];
  __shared__ alignas(16) bf16 Pl[4][512];
  const int t = threadIdx.x;
  const int l = t & 63;
  const int w = t >> 6;
  const int g = l >> 4;
  const int lrow = l & 15;
  const int bid = blockIdx.x;
  const int kq = bid >> 3;
  const int h = (bid & 7) * 2 + (kq & 1);
  const int q0 = (kq >> 1) * 64 + w * 16;
  const int NT = SEQ / 32;

  const bf16* sbase[3];
  int smul[3];
#pragma unroll
  for (int i = 0; i < 3; ++i) {
    int s = t + i * 256;
    if (s < 384) {
      int cb = s >> 5, kv = s & 31;
      sbase[i] = kk + ((size_t)h * SEQ + kv) * HDP + cb * 8;
      smul[i] = 32 * HDP;
    } else {
      int vs = s - 384;
      int cb = vs / 96, d = vs - cb * 96;
      sbase[i] = vT + ((size_t)h * HDP + d) * SEQ + cb * 8;
      smul[i] = 32;
    }
  }
  auto STAGE = [&](int tile, int bufOff) {
#pragma unroll
    for (int i = 0; i < 3; ++i)
      async_lds16(&KV3[bufOff + (t + i * 256) * 8], sbase[i] + (size_t)tile * smul[i]);
  };

  short8 qf[3];
#pragma unroll
  for (int f = 0; f < 3; ++f)
    qf[f] = *(const short8*)&q[((size_t)h * SEQ + q0 + lrow) * HDP + f * 32 + g * 8];

  float m_r = -1e30f;
  f32x4 oa[5] = {};

  STAGE(0, 0);
  STAGE(1, 6144);
  STAGE(2, 12288);
  asm volatile("s_waitcnt vmcnt(6)" ::: "memory");
  __builtin_amdgcn_s_barrier();

  f32x4 stA[2] = {}, stB[2];
  int b0 = 0;
#pragma unroll
  for (int nf = 0; nf < 2; ++nf)
#pragma unroll
    for (int f = 0; f < 3; ++f) {
      short8 kfrag = *(const short8*)&KV3[0 + (f * 4 + g) * 256 + (nf * 16 + lrow) * 8];
      stA[nf] = __builtin_amdgcn_mfma_f32_16x16x32_bf16(kfrag, qf[f], stA[nf], 0, 0, 0);
    }

  for (int kt = 0; kt < NT - 1; ++kt) {
    int b1 = b0 + 6144;
    if (b1 == 18432) b1 = 0;
    asm volatile("s_waitcnt vmcnt(3)" ::: "memory");
    __builtin_amdgcn_s_barrier();

    // QK(kt+1) from b1 (independent of softmax(kt) below)
    stB[0] = (f32x4){0.f, 0.f, 0.f, 0.f};
    stB[1] = (f32x4){0.f, 0.f, 0.f, 0.f};
    __builtin_amdgcn_s_setprio(1);
#pragma unroll
    for (int nf = 0; nf < 2; ++nf)
#pragma unroll
      for (int f = 0; f < 3; ++f) {
        short8 kfrag = *(const short8*)&KV3[b1 + (f * 4 + g) * 256 + (nf * 16 + lrow) * 8];
        stB[nf] = __builtin_amdgcn_mfma_f32_16x16x32_bf16(kfrag, qf[f], stB[nf], 0, 0, 0);
      }
    __builtin_amdgcn_s_setprio(0);

    // softmax(kt): defer-max (exp2 domain); l comes from PV ones-row
    float pmax = fmaxf(fmaxf(fmaxf(stA[0][0], stA[0][1]), fmaxf(stA[0][2], stA[0][3])),
                       fmaxf(fmaxf(stA[1][0], stA[1][1]), fmaxf(stA[1][2], stA[1][3])));
    if (!__all(pmax - m_r <= 11.54f)) {
      float rm = pmax;
      rm = fmaxf(rm, __shfl_xor(rm, 16, 64));
      rm = fmaxf(rm, __shfl_xor(rm, 32, 64));
      float mn = fmaxf(m_r, rm);
      float alpha = exp2a(m_r - mn);
#pragma unroll
      for (int nf = 0; nf < 5; ++nf)
#pragma unroll
        for (int r = 0; r < 4; ++r) oa[nf][r] *= alpha;
      m_r = mn;
    }
#pragma unroll
    for (int nf = 0; nf < 2; ++nf)
#pragma unroll
      for (int r = 0; r < 4; ++r) stA[nf][r] = exp2a(stA[nf][r] - m_r);

    // P write: kv = nf*16+g*4+r, q=lrow -> elem = (2nf+(g>>1))*128 + lrow*8 + (g&1)*4
#pragma unroll
    for (int nf = 0; nf < 2; ++nf) {
      uint2* dst = (uint2*)&Pl[w][(2 * nf + (g >> 1)) * 128 + lrow * 8 + (g & 1) * 4];
      *dst = make_uint2(cvt_pk2(stA[nf][0], stA[nf][1]), cvt_pk2(stA[nf][2], stA[nf][3]));
    }

    // PV(kt) from b0: O^T += V' x P'  (d=72 row of V is ones -> accumulates l)
    {
      short8 pa = *(const short8*)&Pl[w][g * 128 + lrow * 8];
      __builtin_amdgcn_s_setprio(1);
#pragma unroll
      for (int nf = 0; nf < 5; ++nf) {
        short8 bv = *(const short8*)&KV3[b0 + 3072 + g * 768 + (nf * 16 + lrow) * 8];
        oa[nf] = __builtin_amdgcn_mfma_f32_16x16x32_bf16(bv, pa, oa[nf], 0, 0, 0);
      }
      __builtin_amdgcn_s_setprio(0);
    }

    asm volatile("s_waitcnt lgkmcnt(0)" ::: "memory");
    __builtin_amdgcn_s_barrier();
    int s = kt + 3;
    if (s >= NT) s -= NT;
    STAGE(s, b0);
    stA[0] = stB[0];
    stA[1] = stB[1];
    b0 = b1;
  }

  // epilogue tile NT-1
  {
    float pmax = fmaxf(fmaxf(fmaxf(stA[0][0], stA[0][1]), fmaxf(stA[0][2], stA[0][3])),
                       fmaxf(fmaxf(stA[1][0], stA[1][1]), fmaxf(stA[1][2], stA[1][3])));
    if (!__all(pmax - m_r <= 11.54f)) {
      float rm = pmax;
      rm = fmaxf(rm, __shfl_xor(rm, 16, 64));
      rm = fmaxf(rm, __shfl_xor(rm, 32, 64));
      float mn = fmaxf(m_r, rm);
      float alpha = exp2a(m_r - mn);
#pragma unroll
      for (int nf = 0; nf < 5; ++nf)
#pragma unroll
        for (int r = 0; r < 4; ++r) oa[nf][r] *= alpha;
      m_r = mn;
    }
#pragma unroll
    for (int nf = 0; nf < 2; ++nf)
#pragma unroll
      for (int r = 0; r < 4; ++r) stA[nf][r] = exp2a(stA[nf][r] - m_r);
#pragma unroll
    for (int nf = 0; nf < 2; ++nf) {
      uint2* dst = (uint2*)&Pl[w][(2 * nf + (g >> 1)) * 128 + lrow * 8 + (g & 1) * 4];
      *dst = make_uint2(cvt_pk2(stA[nf][0], stA[nf][1]), cvt_pk2(stA[nf][2], stA[nf][3]));
    }
    short8 pa = *(const short8*)&Pl[w][g * 128 + lrow * 8];
#pragma unroll
    for (int nf = 0; nf < 5; ++nf) {
      short8 bv = *(const short8*)&KV3[b0 + 3072 + g * 768 + (nf * 16 + lrow) * 8];
      oa[nf] = __builtin_amdgcn_mfma_f32_16x16x32_bf16(bv, pa, oa[nf], 0, 0, 0);
    }
  }

  // drain stale wrapped stages BEFORE exit (see kernel comment)
  asm volatile("s_waitcnt vmcnt(0)" ::: "memory");

  // l lives in oa[4][0] of lane group g=2 (d=72): broadcast from lane 32+lrow
  float lt = __shfl(oa[4][0], 32 + lrow, 64);
  float rcp = 1.f / lt;
  size_t obase = (size_t)(q0 + lrow) * HID + h * HD;
#pragma unroll
  for (int nf = 0; nf < 5; ++nf) {
    int d = nf * 16 + g * 4;
    if (d + 3 < HD) {
      uint2 pk = make_uint2(cvt_pk2(oa[nf][0] * rcp, oa[nf][1] * rcp),
                            cvt_pk2(oa[nf][2] * rcp, oa[nf][3] * rcp));
      *(uint2*)&o[obase + d] = pk;
    }
  }
}

// ---------------- launch ----------------
extern "C" void kernel_launch(void* const* d_in, const int* in_sizes, int n_in,
                              void* d_out, int out_size, void* d_ws, size_t ws_size,
                              hipStream_t stream) {
  (void)in_sizes; (void)n_in; (void)out_size;
  const float* hidden = (const float*)d_in[0];
  const float* cosb = (const float*)d_in[1];
  const float* sinb = (const float*)d_in[2];
  const float* ln0g = (const float*)d_in[3];
  const float* ln0b = (const float*)d_in[4];
  const float* ln1g = (const float*)d_in[5];
  const float* ln1b = (const float*)d_in[6];
  const float* wqkv = (const float*)d_in[7];
  const float* bqkv = (const float*)d_in[8];
  const float* wo = (const float*)d_in[9];
  const float* bo = (const float*)d_in[10];
  const float* w0 = (const float*)d_in[11];
  const float* b0 = (const float*)d_in[12];
  const float* w1 = (const float*)d_in[13];
  const float* b1 = (const float*)d_in[14];

  char* p = (char*)d_ws;
  auto alloc = [&](size_t n) {
    char* r = p;
    p += (n + 255) & ~(size_t)255;
    return r;
  };
  bf16* wqkv_bf = (bf16*)alloc((size_t)3 * HID * HID * 2);
  bf16* wo_bf = (bf16*)alloc((size_t)HID * HID * 2);
  bf16* fc0_bf = (bf16*)alloc((size_t)MLPP * HID * 2);
  bf16* fc1_bf = (bf16*)alloc((size_t)HID * MLPP * 2);
  bf16* ln0_bf = (bf16*)alloc((size_t)SEQ * HID * 2);
  bf16* xqkv = (bf16*)alloc((size_t)SEQ * 3 * HID * 2);
  bf16* qp = (bf16*)alloc((size_t)NHEAD * SEQ * HDP * 2);
  bf16* kp = (bf16*)alloc((size_t)NHEAD * SEQ * HDP * 2);
  bf16* vt = (bf16*)alloc((size_t)NHEAD * HDP * SEQ * 2);
  bf16* attn_bf = (bf16*)alloc((size_t)SEQ * HID * 2);
  float* h1 = (float*)alloc((size_t)SEQ * HID * 4);
  bf16* ln1_bf = (bf16*)alloc((size_t)SEQ * HID * 2);
  bf16* gelu_bf = (bf16*)alloc((size_t)SEQ * MLPP * 2);
  if ((size_t)(p - (char*)d_ws) > ws_size) return;

  dim3 blk(256);
  prep_k<<<SEQ + 1024, blk, 0, stream>>>(hidden, ln0g, ln0b, wqkv, wo, w0, w1, ln0_bf,
                                         (unsigned*)wqkv_bf, (unsigned*)wo_bf,
                                         (unsigned*)fc0_bf, (unsigned*)fc1_bf);
  gemm_bf16<0, 128><<<dim3((3 * HID / 128) * (SEQ / 128)), blk, 0, stream>>>(
      ln0_bf, wqkv_bf, bqkv, 3 * HID, nullptr, nullptr, xqkv, SEQ, 3 * HID, HID);
  rope_split<<<dim3(SEQ / 64, NHEAD), blk, 0, stream>>>(xqkv, cosb, sinb, qp, kp, vt);
  flash_attn<<<dim3(768), blk, 0, stream>>>(qp, kp, vt, attn_bf);
  gemm_bf16<1, 64><<<dim3((HID / 64) * (SEQ / 128)), blk, 0, stream>>>(
      attn_bf, wo_bf, bo, HID, hidden, h1, nullptr, SEQ, HID, HID);
  ln_k<<<SEQ, blk, 0, stream>>>(h1, ln1g, ln1b, ln1_bf);
  gemm_bf16<2, 128><<<dim3((MLPP / 128) * (SEQ / 128)), blk, 0, stream>>>(
      ln1_bf, fc0_bf, b0, MLPD, nullptr, nullptr, gelu_bf, SEQ, MLPP, HID);
  gemm_bf16<1, 64><<<dim3((HID / 64) * (SEQ / 128)), blk, 0, stream>>>(
      gelu_bf, fc1_bf, b1, HID, h1, (float*)d_out, nullptr, SEQ, HID, MLPP);
}